// Round 1
// 1233.296 us; speedup vs baseline: 1.0503x; 1.0503x over previous
//
#include <hip/hip_runtime.h>
#include <hip/hip_bf16.h>
#include <cstdio>

// ---------------------------------------------------------------------------
// RWKV6 TimeMix: B=4, T=2048, C=2048, H=32, N=64, DMIX=32, DDEC=64
// ---------------------------------------------------------------------------

typedef __attribute__((ext_vector_type(8))) short bf16x8;    // 8 bf16 = 4 VGPRs
typedef __attribute__((ext_vector_type(4))) float floatx4;

#define T_DIM 2048
#define C_DIM 2048
#define B_DIM 4
#define M_ROWS (B_DIM * T_DIM)   // 8192

// ---------------- global_load_lds helper (16B per lane) --------------------
typedef const unsigned int __attribute__((address_space(1)))* gas1_t;
typedef unsigned int __attribute__((address_space(3)))* las3_t;
__device__ __forceinline__ void gl_lds16(const void* g, void* l) {
    __builtin_amdgcn_global_load_lds((gas1_t)g, (las3_t)l, 16, 0, 0);
}

// ---------------- transpose + cast + zero-pad ------------------------------
__global__ __launch_bounds__(256) void k_transpose(
    const float* __restrict__ in, void* __restrict__ out,
    int R, int Cin, int to_bf16)
{
    __shared__ float tile[32][33];
    const int tx = threadIdx.x & 31, ty = threadIdx.x >> 5;
    const int cbase = blockIdx.x * 32, rbase = blockIdx.y * 32;
#pragma unroll
    for (int i = 0; i < 4; i++) {
        int r = rbase + ty + i * 8;
        int c = cbase + tx;
        tile[ty + i * 8][tx] = (c < Cin) ? in[(size_t)r * Cin + c] : 0.0f;
    }
    __syncthreads();
    if (to_bf16) {
        __hip_bfloat16* ob = (__hip_bfloat16*)out;
#pragma unroll
        for (int i = 0; i < 4; i++) {
            int c = cbase + ty + i * 8;
            ob[(size_t)c * R + rbase + tx] = __float2bfloat16(tile[tx][ty + i * 8]);
        }
    } else {
        float* of = (float*)out;
#pragma unroll
        for (int i = 0; i < 4; i++) {
            int c = cbase + ty + i * 8;
            of[(size_t)c * R + rbase + tx] = tile[tx][ty + i * 8];
        }
    }
}

// ---------------- XX = bf16(x + (prev-x)*tmx); also x_last ------------------
__global__ __launch_bounds__(256) void k_xx(
    const float* __restrict__ x, const float* __restrict__ shift,
    const float* __restrict__ tmx,
    __hip_bfloat16* __restrict__ XX, float* __restrict__ xlast)
{
    const int row = blockIdx.x;
    const int b = row >> 11, t = row & 2047;
    const int c0 = threadIdx.x * 8;
    const float* xrow = x + (size_t)row * C_DIM;
    const float* prow = (t == 0) ? (shift + (size_t)b * C_DIM) : (xrow - C_DIM);
    float4 xa = ((const float4*)(xrow + c0))[0];
    float4 xb = ((const float4*)(xrow + c0))[1];
    float4 pa = ((const float4*)(prow + c0))[0];
    float4 pb = ((const float4*)(prow + c0))[1];
    float xv8[8] = {xa.x, xa.y, xa.z, xa.w, xb.x, xb.y, xb.z, xb.w};
    float pv8[8] = {pa.x, pa.y, pa.z, pa.w, pb.x, pb.y, pb.z, pb.w};
    union { bf16x8 v8; __hip_bfloat16 e[8]; } u;
#pragma unroll
    for (int j = 0; j < 8; j++)
        u.e[j] = __float2bfloat16(fmaf(pv8[j] - xv8[j], tmx[c0 + j], xv8[j]));
    *(bf16x8*)(XX + (size_t)row * C_DIM + c0) = u.v8;
    if (t == T_DIM - 1) {
        ((float4*)(xlast + (size_t)b * C_DIM + c0))[0] = xa;
        ((float4*)(xlast + (size_t)b * C_DIM + c0))[1] = xb;
    }
}

// ---------------- H = tanh(XX @ w1) : M=8192, N=256(padded), K=2048 ---------
__global__ __launch_bounds__(256) void k_gemm_h(
    const __hip_bfloat16* __restrict__ A,
    const __hip_bfloat16* __restrict__ Bt,
    float* __restrict__ Hout)
{
    __shared__ __hip_bfloat16 As[64 * 32];
    __shared__ __hip_bfloat16 Bs[256 * 32];
    const int tid = threadIdx.x;
    const int m0 = blockIdx.x * 64;
    const int wave = tid >> 6, lane = tid & 63;
    const int fcol = lane & 15, quad = lane >> 4;
    floatx4 acc[16];
#pragma unroll
    for (int i = 0; i < 16; i++) acc[i] = (floatx4){0.f, 0.f, 0.f, 0.f};

    const int rA = tid >> 2, kcA = (tid & 3) * 8;
    const __hip_bfloat16* gA = A + (size_t)(m0 + rA) * 2048 + kcA;
    __hip_bfloat16* lA = As + tid * 8;
    const __hip_bfloat16* gB[4];
    __hip_bfloat16* lB[4];
#pragma unroll
    for (int s = 0; s < 4; s++) {
        int q = tid + 256 * s;
        gB[s] = Bt + (size_t)(q >> 2) * 2048 + (q & 3) * 8;
        lB[s] = Bs + q * 8;
    }
    for (int kk = 0; kk < 2048; kk += 32) {
        gl_lds16(gA + kk, lA);
#pragma unroll
        for (int s = 0; s < 4; s++) gl_lds16(gB[s] + kk, lB[s]);
        __syncthreads();
        bf16x8 aF = *(const bf16x8*)(As + (wave * 16 + fcol) * 32 + quad * 8);
#pragma unroll
        for (int ni = 0; ni < 16; ni++) {
            bf16x8 bF = *(const bf16x8*)(Bs + (ni * 16 + fcol) * 32 + quad * 8);
            acc[ni] = __builtin_amdgcn_mfma_f32_16x16x32_bf16(aF, bF, acc[ni], 0, 0, 0);
        }
        __syncthreads();
    }
#pragma unroll
    for (int ni = 0; ni < 16; ni++) {
        int col = ni * 16 + fcol;
#pragma unroll
        for (int g = 0; g < 4; g++) {
            int row = m0 + wave * 16 + quad * 4 + g;
            Hout[(size_t)row * 256 + col] = tanhf(acc[ni][g]);
        }
    }
}

// ---------------- G = tanh(A @ Bt^T) : N=64, K=2048 -------------------------
__global__ __launch_bounds__(256) void k_gemm_n64(
    const __hip_bfloat16* __restrict__ A,
    const __hip_bfloat16* __restrict__ Bt,
    __hip_bfloat16* __restrict__ G)
{
    __shared__ __hip_bfloat16 As[64 * 32];
    __shared__ __hip_bfloat16 Bs[64 * 32];
    const int tid = threadIdx.x;
    const int m0 = blockIdx.x * 64;
    const int wave = tid >> 6, lane = tid & 63;
    const int fcol = lane & 15, quad = lane >> 4;
    floatx4 acc[4];
#pragma unroll
    for (int i = 0; i < 4; i++) acc[i] = (floatx4){0.f, 0.f, 0.f, 0.f};

    const int r = tid >> 2, kc = (tid & 3) * 8;
    const __hip_bfloat16* gA = A + (size_t)(m0 + r) * 2048 + kc;
    const __hip_bfloat16* gB = Bt + (size_t)r * 2048 + kc;
    __hip_bfloat16* lA = As + tid * 8;
    __hip_bfloat16* lB = Bs + tid * 8;
    for (int kk = 0; kk < 2048; kk += 32) {
        gl_lds16(gA + kk, lA);
        gl_lds16(gB + kk, lB);
        __syncthreads();
        bf16x8 aF = *(const bf16x8*)(As + (wave * 16 + fcol) * 32 + quad * 8);
#pragma unroll
        for (int ni = 0; ni < 4; ni++) {
            bf16x8 bF = *(const bf16x8*)(Bs + (ni * 16 + fcol) * 32 + quad * 8);
            acc[ni] = __builtin_amdgcn_mfma_f32_16x16x32_bf16(aF, bF, acc[ni], 0, 0, 0);
        }
        __syncthreads();
    }
#pragma unroll
    for (int ni = 0; ni < 4; ni++) {
        int col = ni * 16 + fcol;
#pragma unroll
        for (int g = 0; g < 4; g++) {
            int row = m0 + wave * 16 + quad * 4 + g;
            G[(size_t)row * 64 + col] = __float2bfloat16(tanhf(acc[ni][g]));
        }
    }
}

// ---------------- mix-apply: xout_f = x + dx*(maa_f + H_f @ w2_f) -----------
__global__ __launch_bounds__(256) void k_mixapply(
    const float* __restrict__ x, const float* __restrict__ shift,
    const float* __restrict__ H, const float* __restrict__ w2,
    const float* __restrict__ tmr, const float* __restrict__ tmk,
    const float* __restrict__ tmv, const float* __restrict__ tmw,
    const float* __restrict__ tmv2,
    __hip_bfloat16* __restrict__ xr, __hip_bfloat16* __restrict__ xk,
    __hip_bfloat16* __restrict__ xv, __hip_bfloat16* __restrict__ xw,
    __hip_bfloat16* __restrict__ xv2)
{
    __shared__ float hsm[16][160];
    const int row0 = blockIdx.x * 16;
    const int b = row0 >> 11;
    const int tid = threadIdx.x;
    for (int idx = tid; idx < 16 * 160; idx += 256)
        hsm[idx / 160][idx % 160] = H[(size_t)(row0 + idx / 160) * 256 + idx % 160];
    __syncthreads();
    const int c0 = tid * 8;
    const float* maas[5] = {tmr, tmk, tmv, tmw, tmv2};
    __hip_bfloat16* outs[5] = {xr, xk, xv, xw, xv2};
    for (int rc = 0; rc < 16; rc += 8) {
#pragma unroll
        for (int f = 0; f < 5; f++) {
            float acc[8][8];
#pragma unroll
            for (int r = 0; r < 8; r++)
#pragma unroll
                for (int j = 0; j < 8; j++) acc[r][j] = 0.f;
#pragma unroll 4
            for (int d = 0; d < 32; d++) {
                const float4* wp = (const float4*)(w2 + (size_t)(f * 32 + d) * 2048 + c0);
                float4 p0 = wp[0], p1 = wp[1];
                float wv[8] = {p0.x, p0.y, p0.z, p0.w, p1.x, p1.y, p1.z, p1.w};
#pragma unroll
                for (int r = 0; r < 8; r++) {
                    float h = hsm[rc + r][f * 32 + d];
#pragma unroll
                    for (int j = 0; j < 8; j++) acc[r][j] = fmaf(h, wv[j], acc[r][j]);
                }
            }
            const float* maa = maas[f];
            float m8[8];
#pragma unroll
            for (int j = 0; j < 8; j++) m8[j] = maa[c0 + j];
#pragma unroll
            for (int r = 0; r < 8; r++) {
                int row = row0 + rc + r;
                int t = row & 2047;
                const float* xrow = x + (size_t)row * C_DIM;
                const float* prow = (t == 0) ? (shift + (size_t)b * C_DIM) : (xrow - C_DIM);
                float4 xa = ((const float4*)(xrow + c0))[0];
                float4 xb = ((const float4*)(xrow + c0))[1];
                float4 pa = ((const float4*)(prow + c0))[0];
                float4 pb = ((const float4*)(prow + c0))[1];
                float xv8[8] = {xa.x, xa.y, xa.z, xa.w, xb.x, xb.y, xb.z, xb.w};
                float pv8[8] = {pa.x, pa.y, pa.z, pa.w, pb.x, pb.y, pb.z, pb.w};
                union { bf16x8 v8; __hip_bfloat16 e[8]; } u;
#pragma unroll
                for (int j = 0; j < 8; j++) {
                    float dx = pv8[j] - xv8[j];
                    u.e[j] = __float2bfloat16(fmaf(dx, m8[j] + acc[r][j], xv8[j]));
                }
                *(bf16x8*)(outs[f] + (size_t)row * C_DIM + c0) = u.v8;
            }
        }
    }
}

// ---------------- big MFMA GEMM: M=8192, N=2048, K=2048 ---------------------
// 256x256 tile, BK=32, 512 threads (8 waves as 2m x 4n), 4-slot LDS ring
// (128 KiB). Deep pipeline: while computing tile t, tile t+3 is staged into
// the slot whose reads finished at tile t-1 (race-free: per-tile barrier
// bounds wave skew <1 tile). Counted s_waitcnt vmcnt(8) -- never 0 in the
// main loop -- so 2-3 tiles of global_load_lds stay in flight across the
// barrier (T3+T4). Grid 256 = 1 block/CU; bid&7 = XCD = n-tile, so each
// XCD's 32 CUs share one 1 MB B-panel in its private L2.
// mode 0: outF = val     mode 1: outB = bf16(val)
__global__ __launch_bounds__(512, 2) void k_gemm256(
    const __hip_bfloat16* __restrict__ A,
    const __hip_bfloat16* __restrict__ Bt,
    int mode,
    float* __restrict__ outF, __hip_bfloat16* __restrict__ outB)
{
    constexpr int K = 2048;
    constexpr int NT = K / 32;          // 64 k-tiles
    __shared__ __hip_bfloat16 LA[4][256 * 32];   // 64 KiB
    __shared__ __hip_bfloat16 LB[4][256 * 32];   // 64 KiB
    const int tid = threadIdx.x;
    const int bid = blockIdx.x;
    const int n0 = (bid & 7) * 256;     // XCD == n-tile
    const int m0 = (bid >> 3) * 256;
    const int wave = tid >> 6, lane = tid & 63;
    const int wm = (wave >> 2) * 128, wn = (wave & 3) * 64;
    const int fcol = lane & 15, quad = lane >> 4;

    floatx4 acc[8][4];
#pragma unroll
    for (int mi = 0; mi < 8; mi++)
#pragma unroll
        for (int ni = 0; ni < 4; ni++)
            acc[mi][ni] = (floatx4){0.f, 0.f, 0.f, 0.f};

    // staging: per k-tile each thread moves 2x16B of A and 2x16B of B.
    // wave w, call c covers rows [ (2w+c)*16 , +16 ), 64B (=32 bf16) per row.
    const int ch0 = wave * 2, ch1 = wave * 2 + 1;
    const int rr = lane >> 2, kc = (lane & 3) * 8;
    const __hip_bfloat16* pA0 = A  + (size_t)(m0 + ch0 * 16 + rr) * K + kc;
    const __hip_bfloat16* pA1 = A  + (size_t)(m0 + ch1 * 16 + rr) * K + kc;
    const __hip_bfloat16* pB0 = Bt + (size_t)(n0 + ch0 * 16 + rr) * K + kc;
    const __hip_bfloat16* pB1 = Bt + (size_t)(n0 + ch1 * 16 + rr) * K + kc;
    const int lo0 = ch0 * 512 + lane * 8;   // == (row*32 + col) for this lane
    const int lo1 = ch1 * 512 + lane * 8;

    int ns = 0;
    // prologue: stage tiles 0..2 (12 loads/wave in flight)
    for (; ns < 3; ++ns) {
        gl_lds16(pA0 + ns * 32, &LA[ns][lo0]);
        gl_lds16(pA1 + ns * 32, &LA[ns][lo1]);
        gl_lds16(pB0 + ns * 32, &LB[ns][lo0]);
        gl_lds16(pB1 + ns * 32, &LB[ns][lo1]);
    }
    for (int t = 0; t < NT; ++t) {
        // wait for tile t only: keep tiles t+1,t+2 (8 loads) in flight
        if (t < NT - 2)       asm volatile("s_waitcnt vmcnt(8)" ::: "memory");
        else if (t == NT - 2) asm volatile("s_waitcnt vmcnt(4)" ::: "memory");
        else                  asm volatile("s_waitcnt vmcnt(0)" ::: "memory");
        asm volatile("s_barrier" ::: "memory");
        if (ns < NT) {
            const int sl = ns & 3;   // == (t-1)&3 : reads done at end of t-1
            gl_lds16(pA0 + ns * 32, &LA[sl][lo0]);
            gl_lds16(pA1 + ns * 32, &LA[sl][lo1]);
            gl_lds16(pB0 + ns * 32, &LB[sl][lo0]);
            gl_lds16(pB1 + ns * 32, &LB[sl][lo1]);
            ++ns;
        }
        const int st = t & 3;
        const __hip_bfloat16* ab = &LA[st][(wm + fcol) * 32 + quad * 8];
        const __hip_bfloat16* bb = &LB[st][(wn + fcol) * 32 + quad * 8];
        bf16x8 bF[4];
#pragma unroll
        for (int ni = 0; ni < 4; ni++)
            bF[ni] = *(const bf16x8*)(bb + ni * 512);
#pragma unroll
        for (int mi = 0; mi < 8; mi++) {
            bf16x8 aF = *(const bf16x8*)(ab + mi * 512);
#pragma unroll
            for (int ni = 0; ni < 4; ni++)
                acc[mi][ni] = __builtin_amdgcn_mfma_f32_16x16x32_bf16(
                    aF, bF[ni], acc[mi][ni], 0, 0, 0);
        }
    }
#pragma unroll
    for (int mi = 0; mi < 8; mi++) {
#pragma unroll
        for (int ni = 0; ni < 4; ni++) {
            int rbase = m0 + wm + mi * 16 + quad * 4;
            int ccol = n0 + wn + ni * 16 + fcol;
#pragma unroll
            for (int g = 0; g < 4; g++) {
                size_t idx = (size_t)(rbase + g) * 2048 + ccol;
                float val = acc[mi][ni][g];
                if (mode == 0) outF[idx] = val;
                else           outB[idx] = __float2bfloat16(val);
            }
        }
    }
}

// ---------------- merged K=64 epilogue GEMMs --------------------------------
// grid 2048: op = id>>10. op0: decay = exp(-exp(Gd@dw2t + tdec)) (fp32)
//                         op1: v2  += Gv@vw2t (bf16 rmw)
__global__ __launch_bounds__(256) void k_gemm64(
    const __hip_bfloat16* __restrict__ A0, const __hip_bfloat16* __restrict__ B0,
    const __hip_bfloat16* __restrict__ A1, const __hip_bfloat16* __restrict__ B1,
    float* __restrict__ decayOut, const float* __restrict__ tdec,
    __hip_bfloat16* __restrict__ v2Out)
{
    constexpr int K = 64;
    __shared__ __hip_bfloat16 As[128 * 32];
    __shared__ __hip_bfloat16 Bs[128 * 32];
    const int tid = threadIdx.x;
    const int op = blockIdx.x >> 10;
    const int id = blockIdx.x & 1023;
    const int xcd = id & 7, jj = id >> 3;
    const int m0 = (((xcd << 3) | (jj & 7))) * 128;
    const int n0 = (jj >> 3) * 128;
    const __hip_bfloat16* A = op ? A1 : A0;
    const __hip_bfloat16* Bt = op ? B1 : B0;
    const int wave = tid >> 6, lane = tid & 63;
    const int wm = (wave >> 1) * 64, wn = (wave & 1) * 64;
    const int fcol = lane & 15, quad = lane >> 4;

    floatx4 acc[4][4];
#pragma unroll
    for (int mi = 0; mi < 4; mi++)
#pragma unroll
        for (int ni = 0; ni < 4; ni++)
            acc[mi][ni] = (floatx4){0.f, 0.f, 0.f, 0.f};

    const int q0 = tid, q1 = tid + 256;
    const int r0 = q0 >> 2, kc0 = (q0 & 3) * 8;
    const int r1 = q1 >> 2, kc1 = (q1 & 3) * 8;
    const __hip_bfloat16* gA0 = A + (size_t)(m0 + r0) * K + kc0;
    const __hip_bfloat16* gA1 = A + (size_t)(m0 + r1) * K + kc1;
    const __hip_bfloat16* gB0 = Bt + (size_t)(n0 + r0) * K + kc0;
    const __hip_bfloat16* gB1 = Bt + (size_t)(n0 + r1) * K + kc1;
    __hip_bfloat16* lA0 = As + q0 * 8; __hip_bfloat16* lA1 = As + q1 * 8;
    __hip_bfloat16* lB0 = Bs + q0 * 8; __hip_bfloat16* lB1 = Bs + q1 * 8;

    for (int kk = 0; kk < K; kk += 32) {
        gl_lds16(gA0 + kk, lA0);
        gl_lds16(gA1 + kk, lA1);
        gl_lds16(gB0 + kk, lB0);
        gl_lds16(gB1 + kk, lB1);
        __syncthreads();
        bf16x8 aF[4], bF[4];
#pragma unroll
        for (int mi = 0; mi < 4; mi++)
            aF[mi] = *(const bf16x8*)(As + (wm + mi * 16 + fcol) * 32 + quad * 8);
#pragma unroll
        for (int ni = 0; ni < 4; ni++)
            bF[ni] = *(const bf16x8*)(Bs + (wn + ni * 16 + fcol) * 32 + quad * 8);
#pragma unroll
        for (int mi = 0; mi < 4; mi++)
#pragma unroll
            for (int ni = 0; ni < 4; ni++)
                acc[mi][ni] = __builtin_amdgcn_mfma_f32_16x16x32_bf16(
                    aF[mi], bF[ni], acc[mi][ni], 0, 0, 0);
        __syncthreads();
    }
#pragma unroll
    for (int mi = 0; mi < 4; mi++) {
#pragma unroll
        for (int ni = 0; ni < 4; ni++) {
            int rbase = m0 + wm + mi * 16 + quad * 4;
            int ccol = n0 + wn + ni * 16 + fcol;
#pragma unroll
            for (int g = 0; g < 4; g++) {
                size_t idx = (size_t)(rbase + g) * 2048 + ccol;
                float val = acc[mi][ni][g];
                if (op == 0) {
                    decayOut[idx] = expf(-expf(val + tdec[ccol]));
                } else {
                    v2Out[idx] = __float2bfloat16(__bfloat162float(v2Out[idx]) + val);
                }
            }
        }
    }
}

// ---------------- chunked WKV scan (flash-linear-attention form) ------------
// One block per (b,h); 4 waves; 32 chunks of L=64, sequential.
// k~ = k*(1-d) computed inline from raw k + dec.
__global__ __launch_bounds__(256) void k_scan_chunked(
    const __hip_bfloat16* __restrict__ r, const __hip_bfloat16* __restrict__ k,
    const __hip_bfloat16* __restrict__ v, const float* __restrict__ dec,
    const float* __restrict__ state_in,
    __hip_bfloat16* __restrict__ y, float* __restrict__ state_out)
{
    __shared__ __hip_bfloat16 Rs[64 * 64];
    __shared__ __hip_bfloat16 Ks[64 * 64];
    __shared__ __hip_bfloat16 Vs[64 * 64];
    __shared__ float Ds[64 * 64];
    __shared__ __hip_bfloat16 Am[64 * 72];   // a[t][i] = r*Eexc
    __shared__ __hip_bfloat16 Bm[64 * 72];   // b[s][i] = k~/Einc
    __shared__ __hip_bfloat16 VT[64 * 72];   // V^T [j][s]
    __shared__ __hip_bfloat16 CT[64 * 72];   // C^T [i][s]
    __shared__ __hip_bfloat16 ST[64 * 72];   // S^T [j][i]
    __shared__ __hip_bfloat16 Pm[64 * 72];   // masked P [t][s]
    __shared__ float part[4][64];
    __shared__ float efin[64];

    const int tid = threadIdx.x;
    const int bh = blockIdx.x, b = bh >> 5, h = bh & 31;
    const int wave = tid >> 6, lane = tid & 63;
    const int fcol = lane & 15, quad = lane >> 4;
    const int ci = tid & 63, seg = tid >> 6;

    floatx4 sfr[4];
    {
        const float* sp = state_in + (size_t)bh * 4096;
#pragma unroll
        for (int n = 0; n < 4; n++)
#pragma unroll
            for (int g = 0; g < 4; g++)
                sfr[n][g] = sp[(size_t)(16 * wave + quad * 4 + g) * 64 + 16 * n + fcol];
    }

    const size_t cbase0 = (size_t)b * T_DIM * C_DIM + (size_t)h * 64;
    for (int c = 0; c < 32; c++) {
        const size_t cb = cbase0 + (size_t)c * 64 * C_DIM;
        {
            const int q0 = tid, q1 = tid + 256;
            gl_lds16(r + cb + (size_t)(q0 >> 3) * C_DIM + (q0 & 7) * 8, Rs + q0 * 8);
            gl_lds16(r + cb + (size_t)(q1 >> 3) * C_DIM + (q1 & 7) * 8, Rs + q1 * 8);
            gl_lds16(k + cb + (size_t)(q0 >> 3) * C_DIM + (q0 & 7) * 8, Ks + q0 * 8);
            gl_lds16(k + cb + (size_t)(q1 >> 3) * C_DIM + (q1 & 7) * 8, Ks + q1 * 8);
            gl_lds16(v + cb + (size_t)(q0 >> 3) * C_DIM + (q0 & 7) * 8, Vs + q0 * 8);
            gl_lds16(v + cb + (size_t)(q1 >> 3) * C_DIM + (q1 & 7) * 8, Vs + q1 * 8);
#pragma unroll
            for (int s = 0; s < 4; s++) {
                int q = tid + 256 * s;
                gl_lds16(dec + cb + (size_t)(q >> 4) * C_DIM + (q & 15) * 4, Ds + q * 4);
            }
        }
        __syncthreads();   // B1

        {
#pragma unroll
            for (int n = 0; n < 4; n++)
#pragma unroll
                for (int g = 0; g < 4; g++)
                    ST[(size_t)(16 * n + fcol) * 72 + 16 * wave + quad * 4 + g] =
                        __float2bfloat16(sfr[n][g]);
            float p = 1.0f;
#pragma unroll
            for (int u = 0; u < 16; u++) p *= Ds[(seg * 16 + u) * 64 + ci];
            part[seg][ci] = p;
        }
        __syncthreads();   // B2

        {
            float p0 = part[0][ci], p1 = part[1][ci], p2 = part[2][ci], p3 = part[3][ci];
            float pre = 1.0f;
            if (seg > 0) pre *= p0;
            if (seg > 1) pre *= p1;
            if (seg > 2) pre *= p2;
            float tot = p0 * p1 * p2 * p3;
            if (seg == 0) efin[ci] = tot;
            float e = pre;
#pragma unroll
            for (int u = 0; u < 16; u++) {
                int t = seg * 16 + u;
                float d = Ds[t * 64 + ci];
                float rv = __bfloat162float(Rs[t * 64 + ci]);
                float kv = __bfloat162float(Ks[t * 64 + ci]) * (1.0f - d);  // k~
                Am[t * 72 + ci] = __float2bfloat16(rv * e);
                e *= d;
                float bb = kv * __builtin_amdgcn_rcpf(e);
                Bm[t * 72 + ci] = __float2bfloat16(bb);
                CT[ci * 72 + t] = __float2bfloat16(bb * tot);
            }
#pragma unroll
            for (int u = 0; u < 16; u++) {
                int t = seg * 16 + ((u + (ci & 15)) & 15);
                VT[ci * 72 + t] = Vs[t * 64 + ci];
            }
        }
        __syncthreads();   // B3

        {
            bf16x8 af[2];
#pragma unroll
            for (int kk = 0; kk < 2; kk++)
                af[kk] = *(const bf16x8*)(Am + (16 * wave + fcol) * 72 + kk * 32 + quad * 8);
            floatx4 pfr[4], yfr[4];
#pragma unroll
            for (int n = 0; n < 4; n++) {
                pfr[n] = (floatx4){0.f, 0.f, 0.f, 0.f};
                yfr[n] = (floatx4){0.f, 0.f, 0.f, 0.f};
#pragma unroll
                for (int kk = 0; kk < 2; kk++) {
                    bf16x8 bF = *(const bf16x8*)(Bm + (16 * n + fcol) * 72 + kk * 32 + quad * 8);
                    bf16x8 sF = *(const bf16x8*)(ST + (16 * n + fcol) * 72 + kk * 32 + quad * 8);
                    pfr[n] = __builtin_amdgcn_mfma_f32_16x16x32_bf16(af[kk], bF, pfr[n], 0, 0, 0);
                    yfr[n] = __builtin_amdgcn_mfma_f32_16x16x32_bf16(af[kk], sF, yfr[n], 0, 0, 0);
                }
            }
#pragma unroll
            for (int n = 0; n < 4; n++)
#pragma unroll
                for (int g = 0; g < 4; g++) {
                    int t = 16 * wave + quad * 4 + g;
                    int s = 16 * n + fcol;
                    Pm[t * 72 + s] = (s < t) ? __float2bfloat16(pfr[n][g])
                                             : __float2bfloat16(0.0f);
                }
            float eg[4];
#pragma unroll
            for (int g = 0; g < 4; g++) eg[g] = efin[16 * wave + quad * 4 + g];
#pragma unroll
            for (int n = 0; n < 4; n++)
#pragma unroll
                for (int g = 0; g < 4; g++) sfr[n][g] *= eg[g];
            bf16x8 pf[2], cf[2];
#pragma unroll
            for (int kk = 0; kk < 2; kk++) {
                pf[kk] = *(const bf16x8*)(Pm + (16 * wave + fcol) * 72 + kk * 32 + quad * 8);
                cf[kk] = *(const bf16x8*)(CT + (16 * wave + fcol) * 72 + kk * 32 + quad * 8);
            }
#pragma unroll
            for (int n = 0; n < 4; n++) {
#pragma unroll
                for (int kk = 0; kk < 2; kk++) {
                    bf16x8 vF = *(const bf16x8*)(VT + (16 * n + fcol) * 72 + kk * 32 + quad * 8);
                    yfr[n] = __builtin_amdgcn_mfma_f32_16x16x32_bf16(pf[kk], vF, yfr[n], 0, 0, 0);
                    sfr[n] = __builtin_amdgcn_mfma_f32_16x16x32_bf16(cf[kk], vF, sfr[n], 0, 0, 0);
                }
            }
#pragma unroll
            for (int n = 0; n < 4; n++)
#pragma unroll
                for (int g = 0; g < 4; g++) {
                    size_t addr = cb + (size_t)(16 * wave + quad * 4 + g) * C_DIM + 16 * n + fcol;
                    float yv = __bfloat162float(y[addr]) + yfr[n][g];
                    y[addr] = __float2bfloat16(yv);
                }
        }
    }
    {
        float* so = state_out + (size_t)bh * 4096;
#pragma unroll
        for (int n = 0; n < 4; n++)
#pragma unroll
            for (int g = 0; g < 4; g++)
                so[(size_t)(16 * wave + quad * 4 + g) * 64 + 16 * n + fcol] = sfr[n][g];
    }
}

// ---------------- in-place LayerNorm on bf16 rows ---------------------------
__global__ __launch_bounds__(256) void k_addln(
    __hip_bfloat16* __restrict__ y,
    const float* __restrict__ lnw, const float* __restrict__ lnb)
{
    __shared__ float ls[4], ls2[4];
    const int row = blockIdx.x;
    const size_t base = (size_t)row * C_DIM;
    const int tid = threadIdx.x;
    const int c0 = tid * 8;
    union { bf16x8 v8; __hip_bfloat16 e[8]; } uin;
    uin.v8 = *(const bf16x8*)(y + base + c0);
    float vbuf[8];
#pragma unroll
    for (int j = 0; j < 8; j++) vbuf[j] = __bfloat162float(uin.e[j]);
    float s = 0.f, s2 = 0.f;
#pragma unroll
    for (int j = 0; j < 8; j++) { s += vbuf[j]; s2 += vbuf[j] * vbuf[j]; }
#pragma unroll
    for (int off = 32; off > 0; off >>= 1) {
        s += __shfl_down(s, off, 64);
        s2 += __shfl_down(s2, off, 64);
    }
    const int w = tid >> 6;
    if ((tid & 63) == 0) { ls[w] = s; ls2[w] = s2; }
    __syncthreads();
    float S = ls[0] + ls[1] + ls[2] + ls[3];
    float S2 = ls2[0] + ls2[1] + ls2[2] + ls2[3];
    float mu = S * (1.0f / C_DIM);
    float var = S2 * (1.0f / C_DIM) - mu * mu;
    float rs = rsqrtf(var + 1e-5f);
    union { bf16x8 v8; __hip_bfloat16 e[8]; } u;
#pragma unroll
    for (int j = 0; j < 8; j++) {
        int ccc = c0 + j;
        u.e[j] = __float2bfloat16((vbuf[j] - mu) * rs * lnw[ccc] + lnb[ccc]);
    }
    *(bf16x8*)(y + base + c0) = u.v8;
}

// ---------------------------------------------------------------------------
extern "C" void kernel_launch(void* const* d_in, const int* in_sizes, int n_in,
                              void* d_out, int out_size, void* d_ws, size_t ws_size,
                              hipStream_t stream)
{
    const float* x     = (const float*)d_in[0];
    const float* shift = (const float*)d_in[1];
    const float* wkvin = (const float*)d_in[2];
    const float* tmx   = (const float*)d_in[3];
    const float* tmr   = (const float*)d_in[4];
    const float* tmk   = (const float*)d_in[5];
    const float* tmv   = (const float*)d_in[6];
    const float* tmw   = (const float*)d_in[7];
    const float* tmv2  = (const float*)d_in[8];
    const float* w1    = (const float*)d_in[9];
    const float* w2    = (const float*)d_in[10];
    const float* tdec  = (const float*)d_in[11];
    const float* dw1   = (const float*)d_in[12];
    const float* dw2   = (const float*)d_in[13];
    const float* vw1   = (const float*)d_in[14];
    const float* vw2   = (const float*)d_in[15];
    const float* Wr    = (const float*)d_in[16];
    const float* Wk    = (const float*)d_in[17];
    const float* Wv    = (const float*)d_in[18];
    const float* Wo    = (const float*)d_in[19];
    const float* lnw   = (const float*)d_in[20];
    const float* lnb   = (const float*)d_in[21];

    const size_t SZ_XBF = (size_t)M_ROWS * C_DIM * 2;
    const size_t SZ_WBF = (size_t)C_DIM * C_DIM * 2;
    char* ws = (char*)d_ws;
    size_t off = 0;
    __hip_bfloat16* S0 = (__hip_bfloat16*)(ws + off); off += SZ_XBF; // xr -> v
    __hip_bfloat16* S1 = (__hip_bfloat16*)(ws + off); off += SZ_XBF; // xk -> r
    __hip_bfloat16* S2 = (__hip_bfloat16*)(ws + off); off += SZ_XBF; // xv -> v2/y
    __hip_bfloat16* S3 = (__hip_bfloat16*)(ws + off); off += SZ_XBF; // xw -> k
    __hip_bfloat16* S4 = (__hip_bfloat16*)(ws + off); off += SZ_XBF; // xv2
    char* D = ws + off; off += (size_t)M_ROWS * C_DIM * 4;  // XX||H, then decay
    __hip_bfloat16* XX    = (__hip_bfloat16*)D;
    float*          Hbuf  = (float*)(D + SZ_XBF);
    float*          decay = (float*)D;
    __hip_bfloat16* WrT = (__hip_bfloat16*)(ws + off); off += SZ_WBF;
    __hip_bfloat16* WkT = (__hip_bfloat16*)(ws + off); off += SZ_WBF;
    __hip_bfloat16* WvT = (__hip_bfloat16*)(ws + off); off += SZ_WBF;
    __hip_bfloat16* WoT = (__hip_bfloat16*)(ws + off); off += SZ_WBF;
    __hip_bfloat16* w1tb  = (__hip_bfloat16*)(ws + off); off += (size_t)256 * 2048 * 2;
    __hip_bfloat16* dw1t  = (__hip_bfloat16*)(ws + off); off += (size_t)64 * 2048 * 2;
    __hip_bfloat16* vw1t  = (__hip_bfloat16*)(ws + off); off += (size_t)64 * 2048 * 2;
    __hip_bfloat16* dw2t  = (__hip_bfloat16*)(ws + off); off += (size_t)2048 * 64 * 2;
    __hip_bfloat16* vw2t  = (__hip_bfloat16*)(ws + off); off += (size_t)2048 * 64 * 2;
    __hip_bfloat16* Gd    = (__hip_bfloat16*)(ws + off); off += (size_t)M_ROWS * 64 * 2;
    __hip_bfloat16* Gv    = (__hip_bfloat16*)(ws + off); off += (size_t)M_ROWS * 64 * 2;
    if (ws_size < off) {
        fprintf(stderr, "kernel_launch: ws too small (%zu < %zu)\n", ws_size, off);
        return;
    }

    float* out_y     = (float*)d_out;
    float* out_xlast = out_y + (size_t)M_ROWS * C_DIM;
    float* out_state = out_xlast + (size_t)B_DIM * C_DIM;

    // ---- weight prep ----
    k_transpose<<<dim3(8, 64),  256, 0, stream>>>(w1,  w1tb, 2048, 160, 1);
    k_transpose<<<dim3(2, 64),  256, 0, stream>>>(dw1, dw1t, 2048, 64, 1);
    k_transpose<<<dim3(2, 64),  256, 0, stream>>>(vw1, vw1t, 2048, 64, 1);
    k_transpose<<<dim3(64, 2),  256, 0, stream>>>(dw2, dw2t, 64, 2048, 1);
    k_transpose<<<dim3(64, 2),  256, 0, stream>>>(vw2, vw2t, 64, 2048, 1);
    k_transpose<<<dim3(64, 64), 256, 0, stream>>>(Wr, WrT, 2048, 2048, 1);
    k_transpose<<<dim3(64, 64), 256, 0, stream>>>(Wk, WkT, 2048, 2048, 1);
    k_transpose<<<dim3(64, 64), 256, 0, stream>>>(Wv, WvT, 2048, 2048, 1);
    k_transpose<<<dim3(64, 64), 256, 0, stream>>>(Wo, WoT, 2048, 2048, 1);

    // ---- mixer ----
    k_xx<<<M_ROWS, 256, 0, stream>>>(x, shift, tmx, XX, out_xlast);
    k_gemm_h<<<128, 256, 0, stream>>>(XX, w1tb, Hbuf);
    k_mixapply<<<512, 256, 0, stream>>>(x, shift, Hbuf, w2,
                                        tmr, tmk, tmv, tmw, tmv2,
                                        S0, S1, S2, S3, S4);
    // ---- LoRA hidden layers ----
    k_gemm_n64<<<128, 256, 0, stream>>>(S3, dw1t, Gd);   // from xw (frees S3)
    k_gemm_n64<<<128, 256, 0, stream>>>(S4, vw1t, Gv);   // from xv2
    // ---- big GEMMs (outputs recycle freed x-slots; raw k now) ----
    k_gemm256<<<256, 512, 0, stream>>>(S1, WkT, 1, nullptr, S3);   // k  (xk->S3)
    k_gemm256<<<256, 512, 0, stream>>>(S0, WrT, 1, nullptr, S1);   // r  (xr->S1)
    k_gemm256<<<256, 512, 0, stream>>>(S2, WvT, 1, nullptr, S0);   // v  (xv->S0)
    k_gemm256<<<256, 512, 0, stream>>>(S4, WvT, 1, nullptr, S2);   // v2 (xv2->S2)
    // ---- merged K=64 epilogues: decay (fp32 into D) + v2 += lora ----
    k_gemm64<<<2048, 256, 0, stream>>>(Gd, dw2t, Gv, vw2t, decay, tdec, S2);
    // ---- chunked WKV scan (k~ = k*(1-d) inline; adds v2 in-place in S2) ----
    k_scan_chunked<<<128, 256, 0, stream>>>(S1, S3, S0, decay, wkvin, S2, out_state);
    // ---- LayerNorm (in-place) + output projection ----
    k_addln<<<M_ROWS, 256, 0, stream>>>(S2, lnw, lnb);
    k_gemm256<<<256, 512, 0, stream>>>(S2, WoT, 0, out_y, nullptr);

    (void)in_sizes; (void)n_in; (void)out_size;
}

// Round 2
// 1205.137 us; speedup vs baseline: 1.0749x; 1.0234x over previous
//
#include <hip/hip_runtime.h>
#include <hip/hip_bf16.h>
#include <cstdio>

// ---------------------------------------------------------------------------
// RWKV6 TimeMix: B=4, T=2048, C=2048, H=32, N=64, DMIX=32, DDEC=64
// ---------------------------------------------------------------------------

typedef __attribute__((ext_vector_type(8))) short bf16x8;    // 8 bf16 = 4 VGPRs
typedef __attribute__((ext_vector_type(4))) float floatx4;

#define T_DIM 2048
#define C_DIM 2048
#define B_DIM 4
#define M_ROWS (B_DIM * T_DIM)   // 8192

// ---------------- global_load_lds helper (16B per lane) --------------------
typedef const unsigned int __attribute__((address_space(1)))* gas1_t;
typedef unsigned int __attribute__((address_space(3)))* las3_t;
__device__ __forceinline__ void gl_lds16(const void* g, void* l) {
    __builtin_amdgcn_global_load_lds((gas1_t)g, (las3_t)l, 16, 0, 0);
}

// ---------------- transpose + cast + zero-pad ------------------------------
__global__ __launch_bounds__(256) void k_transpose(
    const float* __restrict__ in, void* __restrict__ out,
    int R, int Cin, int to_bf16)
{
    __shared__ float tile[32][33];
    const int tx = threadIdx.x & 31, ty = threadIdx.x >> 5;
    const int cbase = blockIdx.x * 32, rbase = blockIdx.y * 32;
#pragma unroll
    for (int i = 0; i < 4; i++) {
        int r = rbase + ty + i * 8;
        int c = cbase + tx;
        tile[ty + i * 8][tx] = (c < Cin) ? in[(size_t)r * Cin + c] : 0.0f;
    }
    __syncthreads();
    if (to_bf16) {
        __hip_bfloat16* ob = (__hip_bfloat16*)out;
#pragma unroll
        for (int i = 0; i < 4; i++) {
            int c = cbase + ty + i * 8;
            ob[(size_t)c * R + rbase + tx] = __float2bfloat16(tile[tx][ty + i * 8]);
        }
    } else {
        float* of = (float*)out;
#pragma unroll
        for (int i = 0; i < 4; i++) {
            int c = cbase + ty + i * 8;
            of[(size_t)c * R + rbase + tx] = tile[tx][ty + i * 8];
        }
    }
}

// ---------------- XX = bf16(x + (prev-x)*tmx); also x_last ------------------
__global__ __launch_bounds__(256) void k_xx(
    const float* __restrict__ x, const float* __restrict__ shift,
    const float* __restrict__ tmx,
    __hip_bfloat16* __restrict__ XX, float* __restrict__ xlast)
{
    const int row = blockIdx.x;
    const int b = row >> 11, t = row & 2047;
    const int c0 = threadIdx.x * 8;
    const float* xrow = x + (size_t)row * C_DIM;
    const float* prow = (t == 0) ? (shift + (size_t)b * C_DIM) : (xrow - C_DIM);
    float4 xa = ((const float4*)(xrow + c0))[0];
    float4 xb = ((const float4*)(xrow + c0))[1];
    float4 pa = ((const float4*)(prow + c0))[0];
    float4 pb = ((const float4*)(prow + c0))[1];
    float xv8[8] = {xa.x, xa.y, xa.z, xa.w, xb.x, xb.y, xb.z, xb.w};
    float pv8[8] = {pa.x, pa.y, pa.z, pa.w, pb.x, pb.y, pb.z, pb.w};
    union { bf16x8 v8; __hip_bfloat16 e[8]; } u;
#pragma unroll
    for (int j = 0; j < 8; j++)
        u.e[j] = __float2bfloat16(fmaf(pv8[j] - xv8[j], tmx[c0 + j], xv8[j]));
    *(bf16x8*)(XX + (size_t)row * C_DIM + c0) = u.v8;
    if (t == T_DIM - 1) {
        ((float4*)(xlast + (size_t)b * C_DIM + c0))[0] = xa;
        ((float4*)(xlast + (size_t)b * C_DIM + c0))[1] = xb;
    }
}

// ---------------- H = tanh(XX @ w1) : M=8192, N=256(padded), K=2048 ---------
__global__ __launch_bounds__(256) void k_gemm_h(
    const __hip_bfloat16* __restrict__ A,
    const __hip_bfloat16* __restrict__ Bt,
    float* __restrict__ Hout)
{
    __shared__ __hip_bfloat16 As[64 * 32];
    __shared__ __hip_bfloat16 Bs[256 * 32];
    const int tid = threadIdx.x;
    const int m0 = blockIdx.x * 64;
    const int wave = tid >> 6, lane = tid & 63;
    const int fcol = lane & 15, quad = lane >> 4;
    floatx4 acc[16];
#pragma unroll
    for (int i = 0; i < 16; i++) acc[i] = (floatx4){0.f, 0.f, 0.f, 0.f};

    const int rA = tid >> 2, kcA = (tid & 3) * 8;
    const __hip_bfloat16* gA = A + (size_t)(m0 + rA) * 2048 + kcA;
    __hip_bfloat16* lA = As + tid * 8;
    const __hip_bfloat16* gB[4];
    __hip_bfloat16* lB[4];
#pragma unroll
    for (int s = 0; s < 4; s++) {
        int q = tid + 256 * s;
        gB[s] = Bt + (size_t)(q >> 2) * 2048 + (q & 3) * 8;
        lB[s] = Bs + q * 8;
    }
    for (int kk = 0; kk < 2048; kk += 32) {
        gl_lds16(gA + kk, lA);
#pragma unroll
        for (int s = 0; s < 4; s++) gl_lds16(gB[s] + kk, lB[s]);
        __syncthreads();
        bf16x8 aF = *(const bf16x8*)(As + (wave * 16 + fcol) * 32 + quad * 8);
#pragma unroll
        for (int ni = 0; ni < 16; ni++) {
            bf16x8 bF = *(const bf16x8*)(Bs + (ni * 16 + fcol) * 32 + quad * 8);
            acc[ni] = __builtin_amdgcn_mfma_f32_16x16x32_bf16(aF, bF, acc[ni], 0, 0, 0);
        }
        __syncthreads();
    }
#pragma unroll
    for (int ni = 0; ni < 16; ni++) {
        int col = ni * 16 + fcol;
#pragma unroll
        for (int g = 0; g < 4; g++) {
            int row = m0 + wave * 16 + quad * 4 + g;
            Hout[(size_t)row * 256 + col] = tanhf(acc[ni][g]);
        }
    }
}

// ---------------- G = tanh(A @ Bt^T) : N=64, K=2048 -------------------------
__global__ __launch_bounds__(256) void k_gemm_n64(
    const __hip_bfloat16* __restrict__ A,
    const __hip_bfloat16* __restrict__ Bt,
    __hip_bfloat16* __restrict__ G)
{
    __shared__ __hip_bfloat16 As[64 * 32];
    __shared__ __hip_bfloat16 Bs[64 * 32];
    const int tid = threadIdx.x;
    const int m0 = blockIdx.x * 64;
    const int wave = tid >> 6, lane = tid & 63;
    const int fcol = lane & 15, quad = lane >> 4;
    floatx4 acc[4];
#pragma unroll
    for (int i = 0; i < 4; i++) acc[i] = (floatx4){0.f, 0.f, 0.f, 0.f};

    const int r = tid >> 2, kc = (tid & 3) * 8;
    const __hip_bfloat16* gA = A + (size_t)(m0 + r) * 2048 + kc;
    const __hip_bfloat16* gB = Bt + (size_t)r * 2048 + kc;
    __hip_bfloat16* lA = As + tid * 8;
    __hip_bfloat16* lB = Bs + tid * 8;
    for (int kk = 0; kk < 2048; kk += 32) {
        gl_lds16(gA + kk, lA);
        gl_lds16(gB + kk, lB);
        __syncthreads();
        bf16x8 aF = *(const bf16x8*)(As + (wave * 16 + fcol) * 32 + quad * 8);
#pragma unroll
        for (int ni = 0; ni < 4; ni++) {
            bf16x8 bF = *(const bf16x8*)(Bs + (ni * 16 + fcol) * 32 + quad * 8);
            acc[ni] = __builtin_amdgcn_mfma_f32_16x16x32_bf16(aF, bF, acc[ni], 0, 0, 0);
        }
        __syncthreads();
    }
#pragma unroll
    for (int ni = 0; ni < 4; ni++) {
        int col = ni * 16 + fcol;
#pragma unroll
        for (int g = 0; g < 4; g++) {
            int row = m0 + wave * 16 + quad * 4 + g;
            G[(size_t)row * 64 + col] = __float2bfloat16(tanhf(acc[ni][g]));
        }
    }
}

// ---------------- mix-apply: xout_f = x + dx*(maa_f + H_f @ w2_f) -----------
__global__ __launch_bounds__(256) void k_mixapply(
    const float* __restrict__ x, const float* __restrict__ shift,
    const float* __restrict__ H, const float* __restrict__ w2,
    const float* __restrict__ tmr, const float* __restrict__ tmk,
    const float* __restrict__ tmv, const float* __restrict__ tmw,
    const float* __restrict__ tmv2,
    __hip_bfloat16* __restrict__ xr, __hip_bfloat16* __restrict__ xk,
    __hip_bfloat16* __restrict__ xv, __hip_bfloat16* __restrict__ xw,
    __hip_bfloat16* __restrict__ xv2)
{
    __shared__ float hsm[16][160];
    const int row0 = blockIdx.x * 16;
    const int b = row0 >> 11;
    const int tid = threadIdx.x;
    for (int idx = tid; idx < 16 * 160; idx += 256)
        hsm[idx / 160][idx % 160] = H[(size_t)(row0 + idx / 160) * 256 + idx % 160];
    __syncthreads();
    const int c0 = tid * 8;
    const float* maas[5] = {tmr, tmk, tmv, tmw, tmv2};
    __hip_bfloat16* outs[5] = {xr, xk, xv, xw, xv2};
    for (int rc = 0; rc < 16; rc += 8) {
#pragma unroll
        for (int f = 0; f < 5; f++) {
            float acc[8][8];
#pragma unroll
            for (int r = 0; r < 8; r++)
#pragma unroll
                for (int j = 0; j < 8; j++) acc[r][j] = 0.f;
#pragma unroll 4
            for (int d = 0; d < 32; d++) {
                const float4* wp = (const float4*)(w2 + (size_t)(f * 32 + d) * 2048 + c0);
                float4 p0 = wp[0], p1 = wp[1];
                float wv[8] = {p0.x, p0.y, p0.z, p0.w, p1.x, p1.y, p1.z, p1.w};
#pragma unroll
                for (int r = 0; r < 8; r++) {
                    float h = hsm[rc + r][f * 32 + d];
#pragma unroll
                    for (int j = 0; j < 8; j++) acc[r][j] = fmaf(h, wv[j], acc[r][j]);
                }
            }
            const float* maa = maas[f];
            float m8[8];
#pragma unroll
            for (int j = 0; j < 8; j++) m8[j] = maa[c0 + j];
#pragma unroll
            for (int r = 0; r < 8; r++) {
                int row = row0 + rc + r;
                int t = row & 2047;
                const float* xrow = x + (size_t)row * C_DIM;
                const float* prow = (t == 0) ? (shift + (size_t)b * C_DIM) : (xrow - C_DIM);
                float4 xa = ((const float4*)(xrow + c0))[0];
                float4 xb = ((const float4*)(xrow + c0))[1];
                float4 pa = ((const float4*)(prow + c0))[0];
                float4 pb = ((const float4*)(prow + c0))[1];
                float xv8[8] = {xa.x, xa.y, xa.z, xa.w, xb.x, xb.y, xb.z, xb.w};
                float pv8[8] = {pa.x, pa.y, pa.z, pa.w, pb.x, pb.y, pb.z, pb.w};
                union { bf16x8 v8; __hip_bfloat16 e[8]; } u;
#pragma unroll
                for (int j = 0; j < 8; j++) {
                    float dx = pv8[j] - xv8[j];
                    u.e[j] = __float2bfloat16(fmaf(dx, m8[j] + acc[r][j], xv8[j]));
                }
                *(bf16x8*)(outs[f] + (size_t)row * C_DIM + c0) = u.v8;
            }
        }
    }
}

// ---------------- big MFMA GEMM: M=8192, N=2048, K=2048 ---------------------
// 256x256 tile, BK=32, 512 threads (8 waves as 2m x 4n), 4-slot LDS ring
// (128 KiB). Deep pipeline: while computing tile t, tile t+3 is staged into
// the slot whose reads finished at tile t-1 (race-free: per-tile barrier
// bounds wave skew <1 tile). Counted s_waitcnt vmcnt(8) -- never 0 in the
// main loop -- so 2-3 tiles of global_load_lds stay in flight across the
// barrier (T3+T4). Grid 256 = 1 block/CU; bid&7 = XCD = n-tile, so each
// XCD's 32 CUs share one 1 MB B-panel in its private L2.
// mode 0: outF = val     mode 1: outB = bf16(val)
__global__ __launch_bounds__(512, 2) void k_gemm256(
    const __hip_bfloat16* __restrict__ A,
    const __hip_bfloat16* __restrict__ Bt,
    int mode,
    float* __restrict__ outF, __hip_bfloat16* __restrict__ outB)
{
    constexpr int K = 2048;
    constexpr int NT = K / 32;          // 64 k-tiles
    __shared__ __hip_bfloat16 LA[4][256 * 32];   // 64 KiB
    __shared__ __hip_bfloat16 LB[4][256 * 32];   // 64 KiB
    const int tid = threadIdx.x;
    const int bid = blockIdx.x;
    const int n0 = (bid & 7) * 256;     // XCD == n-tile
    const int m0 = (bid >> 3) * 256;
    const int wave = tid >> 6, lane = tid & 63;
    const int wm = (wave >> 2) * 128, wn = (wave & 3) * 64;
    const int fcol = lane & 15, quad = lane >> 4;

    floatx4 acc[8][4];
#pragma unroll
    for (int mi = 0; mi < 8; mi++)
#pragma unroll
        for (int ni = 0; ni < 4; ni++)
            acc[mi][ni] = (floatx4){0.f, 0.f, 0.f, 0.f};

    // staging: per k-tile each thread moves 2x16B of A and 2x16B of B.
    // wave w, call c covers rows [ (2w+c)*16 , +16 ), 64B (=32 bf16) per row.
    const int ch0 = wave * 2, ch1 = wave * 2 + 1;
    const int rr = lane >> 2, kc = (lane & 3) * 8;
    const __hip_bfloat16* pA0 = A  + (size_t)(m0 + ch0 * 16 + rr) * K + kc;
    const __hip_bfloat16* pA1 = A  + (size_t)(m0 + ch1 * 16 + rr) * K + kc;
    const __hip_bfloat16* pB0 = Bt + (size_t)(n0 + ch0 * 16 + rr) * K + kc;
    const __hip_bfloat16* pB1 = Bt + (size_t)(n0 + ch1 * 16 + rr) * K + kc;
    const int lo0 = ch0 * 512 + lane * 8;   // == (row*32 + col) for this lane
    const int lo1 = ch1 * 512 + lane * 8;

    int ns = 0;
    // prologue: stage tiles 0..2 (12 loads/wave in flight)
    for (; ns < 3; ++ns) {
        gl_lds16(pA0 + ns * 32, &LA[ns][lo0]);
        gl_lds16(pA1 + ns * 32, &LA[ns][lo1]);
        gl_lds16(pB0 + ns * 32, &LB[ns][lo0]);
        gl_lds16(pB1 + ns * 32, &LB[ns][lo1]);
    }
    for (int t = 0; t < NT; ++t) {
        // wait for tile t only: keep tiles t+1,t+2 (8 loads) in flight
        if (t < NT - 2)       asm volatile("s_waitcnt vmcnt(8)" ::: "memory");
        else if (t == NT - 2) asm volatile("s_waitcnt vmcnt(4)" ::: "memory");
        else                  asm volatile("s_waitcnt vmcnt(0)" ::: "memory");
        asm volatile("s_barrier" ::: "memory");
        if (ns < NT) {
            const int sl = ns & 3;   // == (t-1)&3 : reads done at end of t-1
            gl_lds16(pA0 + ns * 32, &LA[sl][lo0]);
            gl_lds16(pA1 + ns * 32, &LA[sl][lo1]);
            gl_lds16(pB0 + ns * 32, &LB[sl][lo0]);
            gl_lds16(pB1 + ns * 32, &LB[sl][lo1]);
            ++ns;
        }
        const int st = t & 3;
        const __hip_bfloat16* ab = &LA[st][(wm + fcol) * 32 + quad * 8];
        const __hip_bfloat16* bb = &LB[st][(wn + fcol) * 32 + quad * 8];
        bf16x8 bF[4];
#pragma unroll
        for (int ni = 0; ni < 4; ni++)
            bF[ni] = *(const bf16x8*)(bb + ni * 512);
#pragma unroll
        for (int mi = 0; mi < 8; mi++) {
            bf16x8 aF = *(const bf16x8*)(ab + mi * 512);
#pragma unroll
            for (int ni = 0; ni < 4; ni++)
                acc[mi][ni] = __builtin_amdgcn_mfma_f32_16x16x32_bf16(
                    aF, bF[ni], acc[mi][ni], 0, 0, 0);
        }
    }
#pragma unroll
    for (int mi = 0; mi < 8; mi++) {
#pragma unroll
        for (int ni = 0; ni < 4; ni++) {
            int rbase = m0 + wm + mi * 16 + quad * 4;
            int ccol = n0 + wn + ni * 16 + fcol;
#pragma unroll
            for (int g = 0; g < 4; g++) {
                size_t idx = (size_t)(rbase + g) * 2048 + ccol;
                float val = acc[mi][ni][g];
                if (mode == 0) outF[idx] = val;
                else           outB[idx] = __float2bfloat16(val);
            }
        }
    }
}

// ---------------- merged K=64 epilogue GEMMs --------------------------------
// grid 2048: op = id>>10. op0: decay = exp(-exp(Gd@dw2t + tdec)) (fp32)
//                         op1: v2  += Gv@vw2t (bf16 rmw)
__global__ __launch_bounds__(256) void k_gemm64(
    const __hip_bfloat16* __restrict__ A0, const __hip_bfloat16* __restrict__ B0,
    const __hip_bfloat16* __restrict__ A1, const __hip_bfloat16* __restrict__ B1,
    float* __restrict__ decayOut, const float* __restrict__ tdec,
    __hip_bfloat16* __restrict__ v2Out)
{
    constexpr int K = 64;
    __shared__ __hip_bfloat16 As[128 * 32];
    __shared__ __hip_bfloat16 Bs[128 * 32];
    const int tid = threadIdx.x;
    const int op = blockIdx.x >> 10;
    const int id = blockIdx.x & 1023;
    const int xcd = id & 7, jj = id >> 3;
    const int m0 = (((xcd << 3) | (jj & 7))) * 128;
    const int n0 = (jj >> 3) * 128;
    const __hip_bfloat16* A = op ? A1 : A0;
    const __hip_bfloat16* Bt = op ? B1 : B0;
    const int wave = tid >> 6, lane = tid & 63;
    const int wm = (wave >> 1) * 64, wn = (wave & 1) * 64;
    const int fcol = lane & 15, quad = lane >> 4;

    floatx4 acc[4][4];
#pragma unroll
    for (int mi = 0; mi < 4; mi++)
#pragma unroll
        for (int ni = 0; ni < 4; ni++)
            acc[mi][ni] = (floatx4){0.f, 0.f, 0.f, 0.f};

    const int q0 = tid, q1 = tid + 256;
    const int r0 = q0 >> 2, kc0 = (q0 & 3) * 8;
    const int r1 = q1 >> 2, kc1 = (q1 & 3) * 8;
    const __hip_bfloat16* gA0 = A + (size_t)(m0 + r0) * K + kc0;
    const __hip_bfloat16* gA1 = A + (size_t)(m0 + r1) * K + kc1;
    const __hip_bfloat16* gB0 = Bt + (size_t)(n0 + r0) * K + kc0;
    const __hip_bfloat16* gB1 = Bt + (size_t)(n0 + r1) * K + kc1;
    __hip_bfloat16* lA0 = As + q0 * 8; __hip_bfloat16* lA1 = As + q1 * 8;
    __hip_bfloat16* lB0 = Bs + q0 * 8; __hip_bfloat16* lB1 = Bs + q1 * 8;

    for (int kk = 0; kk < K; kk += 32) {
        gl_lds16(gA0 + kk, lA0);
        gl_lds16(gA1 + kk, lA1);
        gl_lds16(gB0 + kk, lB0);
        gl_lds16(gB1 + kk, lB1);
        __syncthreads();
        bf16x8 aF[4], bF[4];
#pragma unroll
        for (int mi = 0; mi < 4; mi++)
            aF[mi] = *(const bf16x8*)(As + (wm + mi * 16 + fcol) * 32 + quad * 8);
#pragma unroll
        for (int ni = 0; ni < 4; ni++)
            bF[ni] = *(const bf16x8*)(Bs + (wn + ni * 16 + fcol) * 32 + quad * 8);
#pragma unroll
        for (int mi = 0; mi < 4; mi++)
#pragma unroll
            for (int ni = 0; ni < 4; ni++)
                acc[mi][ni] = __builtin_amdgcn_mfma_f32_16x16x32_bf16(
                    aF[mi], bF[ni], acc[mi][ni], 0, 0, 0);
        __syncthreads();
    }
#pragma unroll
    for (int mi = 0; mi < 4; mi++) {
#pragma unroll
        for (int ni = 0; ni < 4; ni++) {
            int rbase = m0 + wm + mi * 16 + quad * 4;
            int ccol = n0 + wn + ni * 16 + fcol;
#pragma unroll
            for (int g = 0; g < 4; g++) {
                size_t idx = (size_t)(rbase + g) * 2048 + ccol;
                float val = acc[mi][ni][g];
                if (op == 0) {
                    decayOut[idx] = expf(-expf(val + tdec[ccol]));
                } else {
                    v2Out[idx] = __float2bfloat16(__bfloat162float(v2Out[idx]) + val);
                }
            }
        }
    }
}

// ---------------- chunked WKV scan (flash-linear-attention form) ------------
// One block per (b,h); 4 waves; 32 chunks of L=64, sequential.
// k~ = k*(1-d) computed inline from raw k + dec.
// v2: double-buffered input staging (Rs/Ks/Vs/Ds/Ys x2): chunk c+1's 12
// global_load_lds issue right after chunk c's top barrier and land during
// chunk c's compute. Raw s_barrier + lgkmcnt-only publishes at B2/B3 (no
// vmcnt(0) drain -- hipcc's __syncthreads drain was the latency bottleneck:
// MfmaUtil 2%, VALUBusy 7%, all pipes idle). Single counted wait per chunk:
// vmcnt(16) lets the previous chunk's 16 y-stores stay in flight while
// draining exactly the prefetched stage (T3+T4 applied to the scan).
// The y RMW read is replaced by the staged Ys tile (v2 rows), so no scalar
// global-load latency sits on the critical path.
__global__ __launch_bounds__(256) void k_scan_chunked(
    const __hip_bfloat16* __restrict__ r, const __hip_bfloat16* __restrict__ k,
    const __hip_bfloat16* __restrict__ v, const float* __restrict__ dec,
    const float* __restrict__ state_in,
    __hip_bfloat16* __restrict__ y, float* __restrict__ state_out)
{
    __shared__ __hip_bfloat16 Rs[2][64 * 64];   // 16 KiB
    __shared__ __hip_bfloat16 Ks[2][64 * 64];   // 16 KiB
    __shared__ __hip_bfloat16 Vs[2][64 * 64];   // 16 KiB
    __shared__ float          Dsb[2][64 * 64];  // 32 KiB
    __shared__ __hip_bfloat16 Ys[2][64 * 64];   // 16 KiB (v2 rows of chunk)
    __shared__ __hip_bfloat16 Am[64 * 72];   // a[t][i] = r*Eexc
    __shared__ __hip_bfloat16 Bm[64 * 72];   // b[s][i] = k~/Einc
    __shared__ __hip_bfloat16 VT[64 * 72];   // V^T [j][s]
    __shared__ __hip_bfloat16 CT[64 * 72];   // C^T [i][s]
    __shared__ __hip_bfloat16 ST[64 * 72];   // S^T [j][i]
    __shared__ __hip_bfloat16 Pm[64 * 72];   // masked P [t][s]
    __shared__ float part[4][64];
    __shared__ float efin[64];

    const int tid = threadIdx.x;
    const int bh = blockIdx.x, b = bh >> 5, h = bh & 31;
    const int wave = tid >> 6, lane = tid & 63;
    const int fcol = lane & 15, quad = lane >> 4;
    const int ci = tid & 63, seg = tid >> 6;

    floatx4 sfr[4];
    {
        const float* sp = state_in + (size_t)bh * 4096;
#pragma unroll
        for (int n = 0; n < 4; n++)
#pragma unroll
            for (int g = 0; g < 4; g++)
                sfr[n][g] = sp[(size_t)(16 * wave + quad * 4 + g) * 64 + 16 * n + fcol];
    }

    const size_t cbase0 = (size_t)b * T_DIM * C_DIM + (size_t)h * 64;

    // 12 global_load_lds per thread per chunk
    auto stage = [&](int cc, int buf) {
        const size_t cb = cbase0 + (size_t)cc * 64 * C_DIM;
        const int q0 = tid, q1 = tid + 256;
        const size_t o0 = (size_t)(q0 >> 3) * C_DIM + (q0 & 7) * 8;
        const size_t o1 = (size_t)(q1 >> 3) * C_DIM + (q1 & 7) * 8;
        gl_lds16(r + cb + o0, &Rs[buf][q0 * 8]);
        gl_lds16(r + cb + o1, &Rs[buf][q1 * 8]);
        gl_lds16(k + cb + o0, &Ks[buf][q0 * 8]);
        gl_lds16(k + cb + o1, &Ks[buf][q1 * 8]);
        gl_lds16(v + cb + o0, &Vs[buf][q0 * 8]);
        gl_lds16(v + cb + o1, &Vs[buf][q1 * 8]);
        gl_lds16(y + cb + o0, &Ys[buf][q0 * 8]);
        gl_lds16(y + cb + o1, &Ys[buf][q1 * 8]);
#pragma unroll
        for (int s = 0; s < 4; s++) {
            int q = tid + 256 * s;
            gl_lds16(dec + cb + (size_t)(q >> 4) * C_DIM + (q & 15) * 4,
                     &Dsb[buf][q * 4]);
        }
    };

    stage(0, 0);

    for (int c = 0; c < 32; c++) {
        const int cur = c & 1, nxt = cur ^ 1;
        const size_t cb = cbase0 + (size_t)c * 64 * C_DIM;

        // top barrier: chunk c's stage complete; prev chunk's 16 y-stores may
        // remain in flight (distinct addresses, never re-read by this kernel).
        if (c == 0) asm volatile("s_waitcnt vmcnt(0)" ::: "memory");
        else        asm volatile("s_waitcnt vmcnt(16)" ::: "memory");
        asm volatile("s_waitcnt lgkmcnt(0)" ::: "memory");
        __builtin_amdgcn_s_barrier();
        __builtin_amdgcn_sched_barrier(0);

        // prefetch next chunk into the buffer whose readers all passed the
        // barrier above (they finished with it during chunk c-1).
        if (c + 1 < 32) stage(c + 1, nxt);

        {
#pragma unroll
            for (int n = 0; n < 4; n++)
#pragma unroll
                for (int g = 0; g < 4; g++)
                    ST[(size_t)(16 * n + fcol) * 72 + 16 * wave + quad * 4 + g] =
                        __float2bfloat16(sfr[n][g]);
            float p = 1.0f;
#pragma unroll
            for (int u = 0; u < 16; u++) p *= Dsb[cur][(seg * 16 + u) * 64 + ci];
            part[seg][ci] = p;
        }
        asm volatile("s_waitcnt lgkmcnt(0)" ::: "memory");
        __builtin_amdgcn_s_barrier();   // B2 (publishes ST, part; no vm drain)
        __builtin_amdgcn_sched_barrier(0);

        {
            float p0 = part[0][ci], p1 = part[1][ci], p2 = part[2][ci], p3 = part[3][ci];
            float pre = 1.0f;
            if (seg > 0) pre *= p0;
            if (seg > 1) pre *= p1;
            if (seg > 2) pre *= p2;
            float tot = p0 * p1 * p2 * p3;
            if (seg == 0) efin[ci] = tot;
            float e = pre;
#pragma unroll
            for (int u = 0; u < 16; u++) {
                int t = seg * 16 + u;
                float d = Dsb[cur][t * 64 + ci];
                float rv = __bfloat162float(Rs[cur][t * 64 + ci]);
                float kv = __bfloat162float(Ks[cur][t * 64 + ci]) * (1.0f - d);  // k~
                Am[t * 72 + ci] = __float2bfloat16(rv * e);
                e *= d;
                float bb = kv * __builtin_amdgcn_rcpf(e);
                Bm[t * 72 + ci] = __float2bfloat16(bb);
                CT[ci * 72 + t] = __float2bfloat16(bb * tot);
            }
#pragma unroll
            for (int u = 0; u < 16; u++) {
                int t = seg * 16 + ((u + (ci & 15)) & 15);
                VT[ci * 72 + t] = Vs[cur][t * 64 + ci];
            }
        }
        asm volatile("s_waitcnt lgkmcnt(0)" ::: "memory");
        __builtin_amdgcn_s_barrier();   // B3 (publishes Am,Bm,CT,VT,efin)
        __builtin_amdgcn_sched_barrier(0);

        {
            bf16x8 af[2];
#pragma unroll
            for (int kk = 0; kk < 2; kk++)
                af[kk] = *(const bf16x8*)(Am + (16 * wave + fcol) * 72 + kk * 32 + quad * 8);
            floatx4 pfr[4], yfr[4];
#pragma unroll
            for (int n = 0; n < 4; n++) {
                pfr[n] = (floatx4){0.f, 0.f, 0.f, 0.f};
                yfr[n] = (floatx4){0.f, 0.f, 0.f, 0.f};
#pragma unroll
                for (int kk = 0; kk < 2; kk++) {
                    bf16x8 bF = *(const bf16x8*)(Bm + (16 * n + fcol) * 72 + kk * 32 + quad * 8);
                    bf16x8 sF = *(const bf16x8*)(ST + (16 * n + fcol) * 72 + kk * 32 + quad * 8);
                    pfr[n] = __builtin_amdgcn_mfma_f32_16x16x32_bf16(af[kk], bF, pfr[n], 0, 0, 0);
                    yfr[n] = __builtin_amdgcn_mfma_f32_16x16x32_bf16(af[kk], sF, yfr[n], 0, 0, 0);
                }
            }
#pragma unroll
            for (int n = 0; n < 4; n++)
#pragma unroll
                for (int g = 0; g < 4; g++) {
                    int t = 16 * wave + quad * 4 + g;
                    int s = 16 * n + fcol;
                    Pm[t * 72 + s] = (s < t) ? __float2bfloat16(pfr[n][g])
                                             : __float2bfloat16(0.0f);
                }
            float eg[4];
#pragma unroll
            for (int g = 0; g < 4; g++) eg[g] = efin[16 * wave + quad * 4 + g];
#pragma unroll
            for (int n = 0; n < 4; n++)
#pragma unroll
                for (int g = 0; g < 4; g++) sfr[n][g] *= eg[g];
            bf16x8 pf[2], cf[2];
#pragma unroll
            for (int kk = 0; kk < 2; kk++) {
                pf[kk] = *(const bf16x8*)(Pm + (16 * wave + fcol) * 72 + kk * 32 + quad * 8);
                cf[kk] = *(const bf16x8*)(CT + (16 * wave + fcol) * 72 + kk * 32 + quad * 8);
            }
#pragma unroll
            for (int n = 0; n < 4; n++) {
#pragma unroll
                for (int kk = 0; kk < 2; kk++) {
                    bf16x8 vF = *(const bf16x8*)(VT + (16 * n + fcol) * 72 + kk * 32 + quad * 8);
                    yfr[n] = __builtin_amdgcn_mfma_f32_16x16x32_bf16(pf[kk], vF, yfr[n], 0, 0, 0);
                    sfr[n] = __builtin_amdgcn_mfma_f32_16x16x32_bf16(cf[kk], vF, sfr[n], 0, 0, 0);
                }
            }
#pragma unroll
            for (int n = 0; n < 4; n++)
#pragma unroll
                for (int g = 0; g < 4; g++) {
                    int t = 16 * wave + quad * 4 + g;
                    int s = 16 * n + fcol;
                    size_t addr = cb + (size_t)t * C_DIM + s;
                    float yv = __bfloat162float(Ys[cur][t * 64 + s]) + yfr[n][g];
                    y[addr] = __float2bfloat16(yv);
                }
        }
    }
    {
        float* so = state_out + (size_t)bh * 4096;
#pragma unroll
        for (int n = 0; n < 4; n++)
#pragma unroll
            for (int g = 0; g < 4; g++)
                so[(size_t)(16 * wave + quad * 4 + g) * 64 + 16 * n + fcol] = sfr[n][g];
    }
}

// ---------------- in-place LayerNorm on bf16 rows ---------------------------
__global__ __launch_bounds__(256) void k_addln(
    __hip_bfloat16* __restrict__ y,
    const float* __restrict__ lnw, const float* __restrict__ lnb)
{
    __shared__ float ls[4], ls2[4];
    const int row = blockIdx.x;
    const size_t base = (size_t)row * C_DIM;
    const int tid = threadIdx.x;
    const int c0 = tid * 8;
    union { bf16x8 v8; __hip_bfloat16 e[8]; } uin;
    uin.v8 = *(const bf16x8*)(y + base + c0);
    float vbuf[8];
#pragma unroll
    for (int j = 0; j < 8; j++) vbuf[j] = __bfloat162float(uin.e[j]);
    float s = 0.f, s2 = 0.f;
#pragma unroll
    for (int j = 0; j < 8; j++) { s += vbuf[j]; s2 += vbuf[j] * vbuf[j]; }
#pragma unroll
    for (int off = 32; off > 0; off >>= 1) {
        s += __shfl_down(s, off, 64);
        s2 += __shfl_down(s2, off, 64);
    }
    const int w = tid >> 6;
    if ((tid & 63) == 0) { ls[w] = s; ls2[w] = s2; }
    __syncthreads();
    float S = ls[0] + ls[1] + ls[2] + ls[3];
    float S2 = ls2[0] + ls2[1] + ls2[2] + ls2[3];
    float mu = S * (1.0f / C_DIM);
    float var = S2 * (1.0f / C_DIM) - mu * mu;
    float rs = rsqrtf(var + 1e-5f);
    union { bf16x8 v8; __hip_bfloat16 e[8]; } u;
#pragma unroll
    for (int j = 0; j < 8; j++) {
        int ccc = c0 + j;
        u.e[j] = __float2bfloat16((vbuf[j] - mu) * rs * lnw[ccc] + lnb[ccc]);
    }
    *(bf16x8*)(y + base + c0) = u.v8;
}

// ---------------------------------------------------------------------------
extern "C" void kernel_launch(void* const* d_in, const int* in_sizes, int n_in,
                              void* d_out, int out_size, void* d_ws, size_t ws_size,
                              hipStream_t stream)
{
    const float* x     = (const float*)d_in[0];
    const float* shift = (const float*)d_in[1];
    const float* wkvin = (const float*)d_in[2];
    const float* tmx   = (const float*)d_in[3];
    const float* tmr   = (const float*)d_in[4];
    const float* tmk   = (const float*)d_in[5];
    const float* tmv   = (const float*)d_in[6];
    const float* tmw   = (const float*)d_in[7];
    const float* tmv2  = (const float*)d_in[8];
    const float* w1    = (const float*)d_in[9];
    const float* w2    = (const float*)d_in[10];
    const float* tdec  = (const float*)d_in[11];
    const float* dw1   = (const float*)d_in[12];
    const float* dw2   = (const float*)d_in[13];
    const float* vw1   = (const float*)d_in[14];
    const float* vw2   = (const float*)d_in[15];
    const float* Wr    = (const float*)d_in[16];
    const float* Wk    = (const float*)d_in[17];
    const float* Wv    = (const float*)d_in[18];
    const float* Wo    = (const float*)d_in[19];
    const float* lnw   = (const float*)d_in[20];
    const float* lnb   = (const float*)d_in[21];

    const size_t SZ_XBF = (size_t)M_ROWS * C_DIM * 2;
    const size_t SZ_WBF = (size_t)C_DIM * C_DIM * 2;
    char* ws = (char*)d_ws;
    size_t off = 0;
    __hip_bfloat16* S0 = (__hip_bfloat16*)(ws + off); off += SZ_XBF; // xr -> v
    __hip_bfloat16* S1 = (__hip_bfloat16*)(ws + off); off += SZ_XBF; // xk -> r
    __hip_bfloat16* S2 = (__hip_bfloat16*)(ws + off); off += SZ_XBF; // xv -> v2/y
    __hip_bfloat16* S3 = (__hip_bfloat16*)(ws + off); off += SZ_XBF; // xw -> k
    __hip_bfloat16* S4 = (__hip_bfloat16*)(ws + off); off += SZ_XBF; // xv2
    char* D = ws + off; off += (size_t)M_ROWS * C_DIM * 4;  // XX||H, then decay
    __hip_bfloat16* XX    = (__hip_bfloat16*)D;
    float*          Hbuf  = (float*)(D + SZ_XBF);
    float*          decay = (float*)D;
    __hip_bfloat16* WrT = (__hip_bfloat16*)(ws + off); off += SZ_WBF;
    __hip_bfloat16* WkT = (__hip_bfloat16*)(ws + off); off += SZ_WBF;
    __hip_bfloat16* WvT = (__hip_bfloat16*)(ws + off); off += SZ_WBF;
    __hip_bfloat16* WoT = (__hip_bfloat16*)(ws + off); off += SZ_WBF;
    __hip_bfloat16* w1tb  = (__hip_bfloat16*)(ws + off); off += (size_t)256 * 2048 * 2;
    __hip_bfloat16* dw1t  = (__hip_bfloat16*)(ws + off); off += (size_t)64 * 2048 * 2;
    __hip_bfloat16* vw1t  = (__hip_bfloat16*)(ws + off); off += (size_t)64 * 2048 * 2;
    __hip_bfloat16* dw2t  = (__hip_bfloat16*)(ws + off); off += (size_t)2048 * 64 * 2;
    __hip_bfloat16* vw2t  = (__hip_bfloat16*)(ws + off); off += (size_t)2048 * 64 * 2;
    __hip_bfloat16* Gd    = (__hip_bfloat16*)(ws + off); off += (size_t)M_ROWS * 64 * 2;
    __hip_bfloat16* Gv    = (__hip_bfloat16*)(ws + off); off += (size_t)M_ROWS * 64 * 2;
    if (ws_size < off) {
        fprintf(stderr, "kernel_launch: ws too small (%zu < %zu)\n", ws_size, off);
        return;
    }

    float* out_y     = (float*)d_out;
    float* out_xlast = out_y + (size_t)M_ROWS * C_DIM;
    float* out_state = out_xlast + (size_t)B_DIM * C_DIM;

    // ---- weight prep ----
    k_transpose<<<dim3(8, 64),  256, 0, stream>>>(w1,  w1tb, 2048, 160, 1);
    k_transpose<<<dim3(2, 64),  256, 0, stream>>>(dw1, dw1t, 2048, 64, 1);
    k_transpose<<<dim3(2, 64),  256, 0, stream>>>(vw1, vw1t, 2048, 64, 1);
    k_transpose<<<dim3(64, 2),  256, 0, stream>>>(dw2, dw2t, 64, 2048, 1);
    k_transpose<<<dim3(64, 2),  256, 0, stream>>>(vw2, vw2t, 64, 2048, 1);
    k_transpose<<<dim3(64, 64), 256, 0, stream>>>(Wr, WrT, 2048, 2048, 1);
    k_transpose<<<dim3(64, 64), 256, 0, stream>>>(Wk, WkT, 2048, 2048, 1);
    k_transpose<<<dim3(64, 64), 256, 0, stream>>>(Wv, WvT, 2048, 2048, 1);
    k_transpose<<<dim3(64, 64), 256, 0, stream>>>(Wo, WoT, 2048, 2048, 1);

    // ---- mixer ----
    k_xx<<<M_ROWS, 256, 0, stream>>>(x, shift, tmx, XX, out_xlast);
    k_gemm_h<<<128, 256, 0, stream>>>(XX, w1tb, Hbuf);
    k_mixapply<<<512, 256, 0, stream>>>(x, shift, Hbuf, w2,
                                        tmr, tmk, tmv, tmw, tmv2,
                                        S0, S1, S2, S3, S4);
    // ---- LoRA hidden layers ----
    k_gemm_n64<<<128, 256, 0, stream>>>(S3, dw1t, Gd);   // from xw (frees S3)
    k_gemm_n64<<<128, 256, 0, stream>>>(S4, vw1t, Gv);   // from xv2
    // ---- big GEMMs (outputs recycle freed x-slots; raw k now) ----
    k_gemm256<<<256, 512, 0, stream>>>(S1, WkT, 1, nullptr, S3);   // k  (xk->S3)
    k_gemm256<<<256, 512, 0, stream>>>(S0, WrT, 1, nullptr, S1);   // r  (xr->S1)
    k_gemm256<<<256, 512, 0, stream>>>(S2, WvT, 1, nullptr, S0);   // v  (xv->S0)
    k_gemm256<<<256, 512, 0, stream>>>(S4, WvT, 1, nullptr, S2);   // v2 (xv2->S2)
    // ---- merged K=64 epilogues: decay (fp32 into D) + v2 += lora ----
    k_gemm64<<<2048, 256, 0, stream>>>(Gd, dw2t, Gv, vw2t, decay, tdec, S2);
    // ---- chunked WKV scan (k~ = k*(1-d) inline; adds v2 in-place in S2) ----
    k_scan_chunked<<<128, 256, 0, stream>>>(S1, S3, S0, decay, wkvin, S2, out_state);
    // ---- LayerNorm (in-place) + output projection ----
    k_addln<<<M_ROWS, 256, 0, stream>>>(S2, lnw, lnb);
    k_gemm256<<<256, 512, 0, stream>>>(S2, WoT, 0, out_y, nullptr);

    (void)in_sizes; (void)n_in; (void)out_size;
}

// Round 4
// 1137.367 us; speedup vs baseline: 1.1389x; 1.0596x over previous
//
#include <hip/hip_runtime.h>
#include <hip/hip_bf16.h>
#include <cstdio>

// ---------------------------------------------------------------------------
// RWKV6 TimeMix: B=4, T=2048, C=2048, H=32, N=64, DMIX=32, DDEC=64
// ---------------------------------------------------------------------------

typedef __attribute__((ext_vector_type(8))) short bf16x8;    // 8 bf16 = 4 VGPRs
typedef __attribute__((ext_vector_type(4))) float floatx4;

#define T_DIM 2048
#define C_DIM 2048
#define B_DIM 4
#define M_ROWS (B_DIM * T_DIM)   // 8192

// ---------------- global_load_lds helper (16B per lane) --------------------
typedef const unsigned int __attribute__((address_space(1)))* gas1_t;
typedef unsigned int __attribute__((address_space(3)))* las3_t;
__device__ __forceinline__ void gl_lds16(const void* g, void* l) {
    __builtin_amdgcn_global_load_lds((gas1_t)g, (las3_t)l, 16, 0, 0);
}

// ---------------- transpose + cast + zero-pad ------------------------------
__global__ __launch_bounds__(256) void k_transpose(
    const float* __restrict__ in, void* __restrict__ out,
    int R, int Cin, int to_bf16)
{
    __shared__ float tile[32][33];
    const int tx = threadIdx.x & 31, ty = threadIdx.x >> 5;
    const int cbase = blockIdx.x * 32, rbase = blockIdx.y * 32;
#pragma unroll
    for (int i = 0; i < 4; i++) {
        int r = rbase + ty + i * 8;
        int c = cbase + tx;
        tile[ty + i * 8][tx] = (c < Cin) ? in[(size_t)r * Cin + c] : 0.0f;
    }
    __syncthreads();
    if (to_bf16) {
        __hip_bfloat16* ob = (__hip_bfloat16*)out;
#pragma unroll
        for (int i = 0; i < 4; i++) {
            int c = cbase + ty + i * 8;
            ob[(size_t)c * R + rbase + tx] = __float2bfloat16(tile[tx][ty + i * 8]);
        }
    } else {
        float* of = (float*)out;
#pragma unroll
        for (int i = 0; i < 4; i++) {
            int c = cbase + ty + i * 8;
            of[(size_t)c * R + rbase + tx] = tile[tx][ty + i * 8];
        }
    }
}

// ---------------- XX = bf16(x + (prev-x)*tmx); also x_last ------------------
__global__ __launch_bounds__(256) void k_xx(
    const float* __restrict__ x, const float* __restrict__ shift,
    const float* __restrict__ tmx,
    __hip_bfloat16* __restrict__ XX, float* __restrict__ xlast)
{
    const int row = blockIdx.x;
    const int b = row >> 11, t = row & 2047;
    const int c0 = threadIdx.x * 8;
    const float* xrow = x + (size_t)row * C_DIM;
    const float* prow = (t == 0) ? (shift + (size_t)b * C_DIM) : (xrow - C_DIM);
    float4 xa = ((const float4*)(xrow + c0))[0];
    float4 xb = ((const float4*)(xrow + c0))[1];
    float4 pa = ((const float4*)(prow + c0))[0];
    float4 pb = ((const float4*)(prow + c0))[1];
    float xv8[8] = {xa.x, xa.y, xa.z, xa.w, xb.x, xb.y, xb.z, xb.w};
    float pv8[8] = {pa.x, pa.y, pa.z, pa.w, pb.x, pb.y, pb.z, pb.w};
    union { bf16x8 v8; __hip_bfloat16 e[8]; } u;
#pragma unroll
    for (int j = 0; j < 8; j++)
        u.e[j] = __float2bfloat16(fmaf(pv8[j] - xv8[j], tmx[c0 + j], xv8[j]));
    *(bf16x8*)(XX + (size_t)row * C_DIM + c0) = u.v8;
    if (t == T_DIM - 1) {
        ((float4*)(xlast + (size_t)b * C_DIM + c0))[0] = xa;
        ((float4*)(xlast + (size_t)b * C_DIM + c0))[1] = xb;
    }
}

// ---------------- H = bf16(tanh(XX @ w1)) : M=8192, N=256(pad), K=2048 ------
__global__ __launch_bounds__(256) void k_gemm_h(
    const __hip_bfloat16* __restrict__ A,
    const __hip_bfloat16* __restrict__ Bt,
    __hip_bfloat16* __restrict__ Hout)
{
    __shared__ __hip_bfloat16 As[64 * 32];
    __shared__ __hip_bfloat16 Bs[256 * 32];
    const int tid = threadIdx.x;
    const int m0 = blockIdx.x * 64;
    const int wave = tid >> 6, lane = tid & 63;
    const int fcol = lane & 15, quad = lane >> 4;
    floatx4 acc[16];
#pragma unroll
    for (int i = 0; i < 16; i++) acc[i] = (floatx4){0.f, 0.f, 0.f, 0.f};

    const int rA = tid >> 2, kcA = (tid & 3) * 8;
    const __hip_bfloat16* gA = A + (size_t)(m0 + rA) * 2048 + kcA;
    __hip_bfloat16* lA = As + tid * 8;
    const __hip_bfloat16* gB[4];
    __hip_bfloat16* lB[4];
#pragma unroll
    for (int s = 0; s < 4; s++) {
        int q = tid + 256 * s;
        gB[s] = Bt + (size_t)(q >> 2) * 2048 + (q & 3) * 8;
        lB[s] = Bs + q * 8;
    }
    for (int kk = 0; kk < 2048; kk += 32) {
        gl_lds16(gA + kk, lA);
#pragma unroll
        for (int s = 0; s < 4; s++) gl_lds16(gB[s] + kk, lB[s]);
        __syncthreads();
        bf16x8 aF = *(const bf16x8*)(As + (wave * 16 + fcol) * 32 + quad * 8);
#pragma unroll
        for (int ni = 0; ni < 16; ni++) {
            bf16x8 bF = *(const bf16x8*)(Bs + (ni * 16 + fcol) * 32 + quad * 8);
            acc[ni] = __builtin_amdgcn_mfma_f32_16x16x32_bf16(aF, bF, acc[ni], 0, 0, 0);
        }
        __syncthreads();
    }
#pragma unroll
    for (int ni = 0; ni < 16; ni++) {
        int col = ni * 16 + fcol;
#pragma unroll
        for (int g = 0; g < 4; g++) {
            int row = m0 + wave * 16 + quad * 4 + g;
            Hout[(size_t)row * 256 + col] = __float2bfloat16(tanhf(acc[ni][g]));
        }
    }
}

// ---------------- G = tanh(A @ Bt^T) : N=64, K=2048 -------------------------
__global__ __launch_bounds__(256) void k_gemm_n64(
    const __hip_bfloat16* __restrict__ A,
    const __hip_bfloat16* __restrict__ Bt,
    __hip_bfloat16* __restrict__ G)
{
    __shared__ __hip_bfloat16 As[64 * 32];
    __shared__ __hip_bfloat16 Bs[64 * 32];
    const int tid = threadIdx.x;
    const int m0 = blockIdx.x * 64;
    const int wave = tid >> 6, lane = tid & 63;
    const int fcol = lane & 15, quad = lane >> 4;
    floatx4 acc[4];
#pragma unroll
    for (int i = 0; i < 4; i++) acc[i] = (floatx4){0.f, 0.f, 0.f, 0.f};

    const int r = tid >> 2, kc = (tid & 3) * 8;
    const __hip_bfloat16* gA = A + (size_t)(m0 + r) * 2048 + kc;
    const __hip_bfloat16* gB = Bt + (size_t)r * 2048 + kc;
    __hip_bfloat16* lA = As + tid * 8;
    __hip_bfloat16* lB = Bs + tid * 8;
    for (int kk = 0; kk < 2048; kk += 32) {
        gl_lds16(gA + kk, lA);
        gl_lds16(gB + kk, lB);
        __syncthreads();
        bf16x8 aF = *(const bf16x8*)(As + (wave * 16 + fcol) * 32 + quad * 8);
#pragma unroll
        for (int ni = 0; ni < 4; ni++) {
            bf16x8 bF = *(const bf16x8*)(Bs + (ni * 16 + fcol) * 32 + quad * 8);
            acc[ni] = __builtin_amdgcn_mfma_f32_16x16x32_bf16(aF, bF, acc[ni], 0, 0, 0);
        }
        __syncthreads();
    }
#pragma unroll
    for (int ni = 0; ni < 4; ni++) {
        int col = ni * 16 + fcol;
#pragma unroll
        for (int g = 0; g < 4; g++) {
            int row = m0 + wave * 16 + quad * 4 + g;
            G[(size_t)row * 64 + col] = __float2bfloat16(tanhf(acc[ni][g]));
        }
    }
}

// ---------------- fused mix: xout_f = x + dx*(maa_f + H_f @ w2_f) -----------
// MFMA rewrite of the old VALU mixapply (was 143us: 5x global x re-read,
// 20K scalar FMA/thread, MfmaUtil 0). Tile 32 rows x 256 cols, 2048 blocks
// (bid&7 = n-tile = XCD -> per-XCD 80KB w2T col-slab L2-hot). Stage x-slab
// (+boundary/shift row) and H-slab to LDS once; per f: single-k-step MFMA
// (K=32, B-frags straight from L2-resident w2T), mix tile -> LDS, epilogue
// reads x/prev from LDS (5x re-read now at LDS BW, not HBM) and streams
// bf16x8 stores. LDS 65KB -> 2 blocks/CU.
__global__ __launch_bounds__(256) void k_mixfused(
    const float* __restrict__ x, const float* __restrict__ shift,
    const __hip_bfloat16* __restrict__ Hb,
    const __hip_bfloat16* __restrict__ w2T,
    const float* __restrict__ tmr, const float* __restrict__ tmk,
    const float* __restrict__ tmv, const float* __restrict__ tmw,
    const float* __restrict__ tmv2,
    __hip_bfloat16* __restrict__ xr, __hip_bfloat16* __restrict__ xk,
    __hip_bfloat16* __restrict__ xv, __hip_bfloat16* __restrict__ xw,
    __hip_bfloat16* __restrict__ xv2)
{
    __shared__ float          xp[33 * 256];     // [0]=prev/shift, [1..32]=x rows
    __shared__ __hip_bfloat16 Hs[32 * 256];     // H-slab (cols 160..255 unused)
    __shared__ __hip_bfloat16 mixS[32 * 256];   // one f's mix tile

    const int tid = threadIdx.x;
    const int bid = blockIdx.x;
    const int n0 = (bid & 7) * 256;
    const int m0 = (bid >> 3) * 32;
    const int wave = tid >> 6, lane = tid & 63;
    const int fcol = lane & 15, quad = lane >> 4;
    const int wm = (wave >> 1) * 16, wn = (wave & 1) * 128;

    // ---- stage x-slab + boundary row + H-slab ----
#pragma unroll
    for (int i = 0; i < 8; i++) {
        int row = i * 4 + wave;
        gl_lds16(x + (size_t)(m0 + row) * C_DIM + n0 + lane * 4,
                 xp + (row + 1) * 256 + lane * 4);
    }
    if (wave == 0) {
        const float* src = (m0 & 2047)
            ? (x + (size_t)(m0 - 1) * C_DIM + n0)
            : (shift + (size_t)(m0 >> 11) * C_DIM + n0);
        gl_lds16(src + lane * 4, xp + lane * 4);
    }
#pragma unroll
    for (int i = 0; i < 4; i++) {
        int q = tid + 256 * i;
        gl_lds16(Hb + (size_t)(m0 + (q >> 5)) * 256 + (q & 31) * 8,
                 Hs + (q >> 5) * 256 + (q & 31) * 8);
    }
    asm volatile("s_waitcnt vmcnt(0) lgkmcnt(0)" ::: "memory");
    __builtin_amdgcn_s_barrier();
    __builtin_amdgcn_sched_barrier(0);

    const float* maas[5] = {tmr, tmk, tmv, tmw, tmv2};
    __hip_bfloat16* outs[5] = {xr, xk, xv, xw, xv2};
    const int cc = tid & 31, c0 = cc * 8, rb = tid >> 5;

#pragma unroll
    for (int f = 0; f < 5; f++) {
        // ---- phase B: mix_f tile via MFMA (one K=32 step) ----
        {
            bf16x8 aF = *(const bf16x8*)(Hs + (wm + fcol) * 256 + f * 32 + quad * 8);
            floatx4 acc[8];
#pragma unroll
            for (int nf = 0; nf < 8; nf++) {
                bf16x8 bF = *(const bf16x8*)(
                    w2T + (size_t)(n0 + wn + nf * 16 + fcol) * 160 + f * 32 + quad * 8);
                acc[nf] = __builtin_amdgcn_mfma_f32_16x16x32_bf16(
                    aF, bF, (floatx4){0.f, 0.f, 0.f, 0.f}, 0, 0, 0);
            }
#pragma unroll
            for (int nf = 0; nf < 8; nf++)
#pragma unroll
                for (int g = 0; g < 4; g++)
                    mixS[(wm + quad * 4 + g) * 256 + wn + nf * 16 + fcol] =
                        __float2bfloat16(acc[nf][g]);
        }
        asm volatile("s_waitcnt lgkmcnt(0)" ::: "memory");
        __builtin_amdgcn_s_barrier();
        __builtin_amdgcn_sched_barrier(0);

        // ---- phase C: xout_f = x + (prev-x)*(maa_f + mix) ----
        {
            float4 ma = ((const float4*)(maas[f] + n0 + c0))[0];
            float4 mb = ((const float4*)(maas[f] + n0 + c0))[1];
            float m8[8] = {ma.x, ma.y, ma.z, ma.w, mb.x, mb.y, mb.z, mb.w};
#pragma unroll
            for (int i = 0; i < 4; i++) {
                int row = rb + 8 * i;
                float4 xa = ((const float4*)(xp + (row + 1) * 256 + c0))[0];
                float4 xb = ((const float4*)(xp + (row + 1) * 256 + c0))[1];
                float4 pa = ((const float4*)(xp + row * 256 + c0))[0];
                float4 pb = ((const float4*)(xp + row * 256 + c0))[1];
                float xv8[8] = {xa.x, xa.y, xa.z, xa.w, xb.x, xb.y, xb.z, xb.w};
                float pv8[8] = {pa.x, pa.y, pa.z, pa.w, pb.x, pb.y, pb.z, pb.w};
                union { bf16x8 v8; __hip_bfloat16 e[8]; } mu;
                mu.v8 = *(const bf16x8*)(mixS + row * 256 + c0);
                union { bf16x8 v8; __hip_bfloat16 e[8]; } u;
#pragma unroll
                for (int j = 0; j < 8; j++) {
                    float dx = pv8[j] - xv8[j];
                    float mixv = __bfloat162float(mu.e[j]);
                    u.e[j] = __float2bfloat16(fmaf(dx, m8[j] + mixv, xv8[j]));
                }
                *(bf16x8*)(outs[f] + (size_t)(m0 + row) * C_DIM + n0 + c0) = u.v8;
            }
        }
        if (f < 4) {
            asm volatile("s_waitcnt lgkmcnt(0)" ::: "memory");
            __builtin_amdgcn_s_barrier();
            __builtin_amdgcn_sched_barrier(0);
        }
    }
}

// ---------------- big MFMA GEMM: M=8192, N=2048, K=2048 ---------------------
// 256x256 tile, BK=32, 512 threads (8 waves as 2m x 4n), 4-slot LDS ring
// (128 KiB). Deep pipeline: while computing tile t, tile t+3 is staged into
// the slot whose reads finished at tile t-1 (race-free: per-tile barrier
// bounds wave skew <1 tile). Counted s_waitcnt vmcnt(8) -- never 0 in the
// main loop -- so 2-3 tiles of global_load_lds stay in flight across the
// barrier (T3+T4). Grid 256 = 1 block/CU; bid&7 = XCD = n-tile, so each
// XCD's 32 CUs share one 1 MB B-panel in its private L2.
// mode 0: outF = val     mode 1: outB = bf16(val)
__global__ __launch_bounds__(512, 2) void k_gemm256(
    const __hip_bfloat16* __restrict__ A,
    const __hip_bfloat16* __restrict__ Bt,
    int mode,
    float* __restrict__ outF, __hip_bfloat16* __restrict__ outB)
{
    constexpr int K = 2048;
    constexpr int NT = K / 32;          // 64 k-tiles
    __shared__ __hip_bfloat16 LA[4][256 * 32];   // 64 KiB
    __shared__ __hip_bfloat16 LB[4][256 * 32];   // 64 KiB
    const int tid = threadIdx.x;
    const int bid = blockIdx.x;
    const int n0 = (bid & 7) * 256;     // XCD == n-tile
    const int m0 = (bid >> 3) * 256;
    const int wave = tid >> 6, lane = tid & 63;
    const int wm = (wave >> 2) * 128, wn = (wave & 3) * 64;
    const int fcol = lane & 15, quad = lane >> 4;

    floatx4 acc[8][4];
#pragma unroll
    for (int mi = 0; mi < 8; mi++)
#pragma unroll
        for (int ni = 0; ni < 4; ni++)
            acc[mi][ni] = (floatx4){0.f, 0.f, 0.f, 0.f};

    // staging: per k-tile each thread moves 2x16B of A and 2x16B of B.
    // wave w, call c covers rows [ (2w+c)*16 , +16 ), 64B (=32 bf16) per row.
    const int ch0 = wave * 2, ch1 = wave * 2 + 1;
    const int rr = lane >> 2, kc = (lane & 3) * 8;
    const __hip_bfloat16* pA0 = A  + (size_t)(m0 + ch0 * 16 + rr) * K + kc;
    const __hip_bfloat16* pA1 = A  + (size_t)(m0 + ch1 * 16 + rr) * K + kc;
    const __hip_bfloat16* pB0 = Bt + (size_t)(n0 + ch0 * 16 + rr) * K + kc;
    const __hip_bfloat16* pB1 = Bt + (size_t)(n0 + ch1 * 16 + rr) * K + kc;
    const int lo0 = ch0 * 512 + lane * 8;   // == (row*32 + col) for this lane
    const int lo1 = ch1 * 512 + lane * 8;

    int ns = 0;
    // prologue: stage tiles 0..2 (12 loads/wave in flight)
    for (; ns < 3; ++ns) {
        gl_lds16(pA0 + ns * 32, &LA[ns][lo0]);
        gl_lds16(pA1 + ns * 32, &LA[ns][lo1]);
        gl_lds16(pB0 + ns * 32, &LB[ns][lo0]);
        gl_lds16(pB1 + ns * 32, &LB[ns][lo1]);
    }
    for (int t = 0; t < NT; ++t) {
        // wait for tile t only: keep tiles t+1,t+2 (8 loads) in flight
        if (t < NT - 2)       asm volatile("s_waitcnt vmcnt(8)" ::: "memory");
        else if (t == NT - 2) asm volatile("s_waitcnt vmcnt(4)" ::: "memory");
        else                  asm volatile("s_waitcnt vmcnt(0)" ::: "memory");
        asm volatile("s_barrier" ::: "memory");
        if (ns < NT) {
            const int sl = ns & 3;   // == (t-1)&3 : reads done at end of t-1
            gl_lds16(pA0 + ns * 32, &LA[sl][lo0]);
            gl_lds16(pA1 + ns * 32, &LA[sl][lo1]);
            gl_lds16(pB0 + ns * 32, &LB[sl][lo0]);
            gl_lds16(pB1 + ns * 32, &LB[sl][lo1]);
            ++ns;
        }
        const int st = t & 3;
        const __hip_bfloat16* ab = &LA[st][(wm + fcol) * 32 + quad * 8];
        const __hip_bfloat16* bb = &LB[st][(wn + fcol) * 32 + quad * 8];
        bf16x8 bF[4];
#pragma unroll
        for (int ni = 0; ni < 4; ni++)
            bF[ni] = *(const bf16x8*)(bb + ni * 512);
#pragma unroll
        for (int mi = 0; mi < 8; mi++) {
            bf16x8 aF = *(const bf16x8*)(ab + mi * 512);
#pragma unroll
            for (int ni = 0; ni < 4; ni++)
                acc[mi][ni] = __builtin_amdgcn_mfma_f32_16x16x32_bf16(
                    aF, bF[ni], acc[mi][ni], 0, 0, 0);
        }
    }
#pragma unroll
    for (int mi = 0; mi < 8; mi++) {
#pragma unroll
        for (int ni = 0; ni < 4; ni++) {
            int rbase = m0 + wm + mi * 16 + quad * 4;
            int ccol = n0 + wn + ni * 16 + fcol;
#pragma unroll
            for (int g = 0; g < 4; g++) {
                size_t idx = (size_t)(rbase + g) * 2048 + ccol;
                float val = acc[mi][ni][g];
                if (mode == 0) outF[idx] = val;
                else           outB[idx] = __float2bfloat16(val);
            }
        }
    }
}

// ---------------- merged K=64 epilogue GEMMs --------------------------------
// grid 2048: op = id>>10. op0: decay = exp(-exp(Gd@dw2t + tdec)) (fp32)
//                         op1: v2  += Gv@vw2t (bf16 rmw)
__global__ __launch_bounds__(256) void k_gemm64(
    const __hip_bfloat16* __restrict__ A0, const __hip_bfloat16* __restrict__ B0,
    const __hip_bfloat16* __restrict__ A1, const __hip_bfloat16* __restrict__ B1,
    float* __restrict__ decayOut, const float* __restrict__ tdec,
    __hip_bfloat16* __restrict__ v2Out)
{
    constexpr int K = 64;
    __shared__ __hip_bfloat16 As[128 * 32];
    __shared__ __hip_bfloat16 Bs[128 * 32];
    const int tid = threadIdx.x;
    const int op = blockIdx.x >> 10;
    const int id = blockIdx.x & 1023;
    const int xcd = id & 7, jj = id >> 3;
    const int m0 = (((xcd << 3) | (jj & 7))) * 128;
    const int n0 = (jj >> 3) * 128;
    const __hip_bfloat16* A = op ? A1 : A0;
    const __hip_bfloat16* Bt = op ? B1 : B0;
    const int wave = tid >> 6, lane = tid & 63;
    const int wm = (wave >> 1) * 64, wn = (wave & 1) * 64;
    const int fcol = lane & 15, quad = lane >> 4;

    floatx4 acc[4][4];
#pragma unroll
    for (int mi = 0; mi < 4; mi++)
#pragma unroll
        for (int ni = 0; ni < 4; ni++)
            acc[mi][ni] = (floatx4){0.f, 0.f, 0.f, 0.f};

    const int q0 = tid, q1 = tid + 256;
    const int r0 = q0 >> 2, kc0 = (q0 & 3) * 8;
    const int r1 = q1 >> 2, kc1 = (q1 & 3) * 8;
    const __hip_bfloat16* gA0 = A + (size_t)(m0 + r0) * K + kc0;
    const __hip_bfloat16* gA1 = A + (size_t)(m0 + r1) * K + kc1;
    const __hip_bfloat16* gB0 = Bt + (size_t)(n0 + r0) * K + kc0;
    const __hip_bfloat16* gB1 = Bt + (size_t)(n0 + r1) * K + kc1;
    __hip_bfloat16* lA0 = As + q0 * 8; __hip_bfloat16* lA1 = As + q1 * 8;
    __hip_bfloat16* lB0 = Bs + q0 * 8; __hip_bfloat16* lB1 = Bs + q1 * 8;

    for (int kk = 0; kk < K; kk += 32) {
        gl_lds16(gA0 + kk, lA0);
        gl_lds16(gA1 + kk, lA1);
        gl_lds16(gB0 + kk, lB0);
        gl_lds16(gB1 + kk, lB1);
        __syncthreads();
        bf16x8 aF[4], bF[4];
#pragma unroll
        for (int mi = 0; mi < 4; mi++)
            aF[mi] = *(const bf16x8*)(As + (wm + mi * 16 + fcol) * 32 + quad * 8);
#pragma unroll
        for (int ni = 0; ni < 4; ni++)
            bF[ni] = *(const bf16x8*)(Bs + (wn + ni * 16 + fcol) * 32 + quad * 8);
#pragma unroll
        for (int mi = 0; mi < 4; mi++)
#pragma unroll
            for (int ni = 0; ni < 4; ni++)
                acc[mi][ni] = __builtin_amdgcn_mfma_f32_16x16x32_bf16(
                    aF[mi], bF[ni], acc[mi][ni], 0, 0, 0);
        __syncthreads();
    }
#pragma unroll
    for (int mi = 0; mi < 4; mi++) {
#pragma unroll
        for (int ni = 0; ni < 4; ni++) {
            int rbase = m0 + wm + mi * 16 + quad * 4;
            int ccol = n0 + wn + ni * 16 + fcol;
#pragma unroll
            for (int g = 0; g < 4; g++) {
                size_t idx = (size_t)(rbase + g) * 2048 + ccol;
                float val = acc[mi][ni][g];
                if (op == 0) {
                    decayOut[idx] = expf(-expf(val + tdec[ccol]));
                } else {
                    v2Out[idx] = __float2bfloat16(__bfloat162float(v2Out[idx]) + val);
                }
            }
        }
    }
}

// ---------------- chunked WKV scan (flash-linear-attention form) ------------
// One block per (b,h); 4 waves; 32 chunks of L=64, sequential.
// k~ = k*(1-d) computed inline from raw k + dec.
// Double-buffered input staging + raw barriers + counted vmcnt (T3+T4).
__global__ __launch_bounds__(256) void k_scan_chunked(
    const __hip_bfloat16* __restrict__ r, const __hip_bfloat16* __restrict__ k,
    const __hip_bfloat16* __restrict__ v, const float* __restrict__ dec,
    const float* __restrict__ state_in,
    __hip_bfloat16* __restrict__ y, float* __restrict__ state_out)
{
    __shared__ __hip_bfloat16 Rs[2][64 * 64];   // 16 KiB
    __shared__ __hip_bfloat16 Ks[2][64 * 64];   // 16 KiB
    __shared__ __hip_bfloat16 Vs[2][64 * 64];   // 16 KiB
    __shared__ float          Dsb[2][64 * 64];  // 32 KiB
    __shared__ __hip_bfloat16 Ys[2][64 * 64];   // 16 KiB (v2 rows of chunk)
    __shared__ __hip_bfloat16 Am[64 * 72];   // a[t][i] = r*Eexc
    __shared__ __hip_bfloat16 Bm[64 * 72];   // b[s][i] = k~/Einc
    __shared__ __hip_bfloat16 VT[64 * 72];   // V^T [j][s]
    __shared__ __hip_bfloat16 CT[64 * 72];   // C^T [i][s]
    __shared__ __hip_bfloat16 ST[64 * 72];   // S^T [j][i]
    __shared__ __hip_bfloat16 Pm[64 * 72];   // masked P [t][s]
    __shared__ float part[4][64];
    __shared__ float efin[64];

    const int tid = threadIdx.x;
    const int bh = blockIdx.x, b = bh >> 5, h = bh & 31;
    const int wave = tid >> 6, lane = tid & 63;
    const int fcol = lane & 15, quad = lane >> 4;
    const int ci = tid & 63, seg = tid >> 6;

    floatx4 sfr[4];
    {
        const float* sp = state_in + (size_t)bh * 4096;
#pragma unroll
        for (int n = 0; n < 4; n++)
#pragma unroll
            for (int g = 0; g < 4; g++)
                sfr[n][g] = sp[(size_t)(16 * wave + quad * 4 + g) * 64 + 16 * n + fcol];
    }

    const size_t cbase0 = (size_t)b * T_DIM * C_DIM + (size_t)h * 64;

    // 12 global_load_lds per thread per chunk
    auto stage = [&](int cc, int buf) {
        const size_t cb = cbase0 + (size_t)cc * 64 * C_DIM;
        const int q0 = tid, q1 = tid + 256;
        const size_t o0 = (size_t)(q0 >> 3) * C_DIM + (q0 & 7) * 8;
        const size_t o1 = (size_t)(q1 >> 3) * C_DIM + (q1 & 7) * 8;
        gl_lds16(r + cb + o0, &Rs[buf][q0 * 8]);
        gl_lds16(r + cb + o1, &Rs[buf][q1 * 8]);
        gl_lds16(k + cb + o0, &Ks[buf][q0 * 8]);
        gl_lds16(k + cb + o1, &Ks[buf][q1 * 8]);
        gl_lds16(v + cb + o0, &Vs[buf][q0 * 8]);
        gl_lds16(v + cb + o1, &Vs[buf][q1 * 8]);
        gl_lds16(y + cb + o0, &Ys[buf][q0 * 8]);
        gl_lds16(y + cb + o1, &Ys[buf][q1 * 8]);
#pragma unroll
        for (int s = 0; s < 4; s++) {
            int q = tid + 256 * s;
            gl_lds16(dec + cb + (size_t)(q >> 4) * C_DIM + (q & 15) * 4,
                     &Dsb[buf][q * 4]);
        }
    };

    stage(0, 0);

    for (int c = 0; c < 32; c++) {
        const int cur = c & 1, nxt = cur ^ 1;
        const size_t cb = cbase0 + (size_t)c * 64 * C_DIM;

        // top barrier: chunk c's stage complete; prev chunk's 16 y-stores may
        // remain in flight (distinct addresses, never re-read by this kernel).
        if (c == 0) asm volatile("s_waitcnt vmcnt(0)" ::: "memory");
        else        asm volatile("s_waitcnt vmcnt(16)" ::: "memory");
        asm volatile("s_waitcnt lgkmcnt(0)" ::: "memory");
        __builtin_amdgcn_s_barrier();
        __builtin_amdgcn_sched_barrier(0);

        // prefetch next chunk into the buffer whose readers all passed the
        // barrier above (they finished with it during chunk c-1).
        if (c + 1 < 32) stage(c + 1, nxt);

        {
#pragma unroll
            for (int n = 0; n < 4; n++)
#pragma unroll
                for (int g = 0; g < 4; g++)
                    ST[(size_t)(16 * n + fcol) * 72 + 16 * wave + quad * 4 + g] =
                        __float2bfloat16(sfr[n][g]);
            float p = 1.0f;
#pragma unroll
            for (int u = 0; u < 16; u++) p *= Dsb[cur][(seg * 16 + u) * 64 + ci];
            part[seg][ci] = p;
        }
        asm volatile("s_waitcnt lgkmcnt(0)" ::: "memory");
        __builtin_amdgcn_s_barrier();   // B2 (publishes ST, part; no vm drain)
        __builtin_amdgcn_sched_barrier(0);

        {
            float p0 = part[0][ci], p1 = part[1][ci], p2 = part[2][ci], p3 = part[3][ci];
            float pre = 1.0f;
            if (seg > 0) pre *= p0;
            if (seg > 1) pre *= p1;
            if (seg > 2) pre *= p2;
            float tot = p0 * p1 * p2 * p3;
            if (seg == 0) efin[ci] = tot;
            float e = pre;
#pragma unroll
            for (int u = 0; u < 16; u++) {
                int t = seg * 16 + u;
                float d = Dsb[cur][t * 64 + ci];
                float rv = __bfloat162float(Rs[cur][t * 64 + ci]);
                float kv = __bfloat162float(Ks[cur][t * 64 + ci]) * (1.0f - d);  // k~
                Am[t * 72 + ci] = __float2bfloat16(rv * e);
                e *= d;
                float bb = kv * __builtin_amdgcn_rcpf(e);
                Bm[t * 72 + ci] = __float2bfloat16(bb);
                CT[ci * 72 + t] = __float2bfloat16(bb * tot);
            }
#pragma unroll
            for (int u = 0; u < 16; u++) {
                int t = seg * 16 + ((u + (ci & 15)) & 15);
                VT[ci * 72 + t] = Vs[cur][t * 64 + ci];
            }
        }
        asm volatile("s_waitcnt lgkmcnt(0)" ::: "memory");
        __builtin_amdgcn_s_barrier();   // B3 (publishes Am,Bm,CT,VT,efin)
        __builtin_amdgcn_sched_barrier(0);

        {
            bf16x8 af[2];
#pragma unroll
            for (int kk = 0; kk < 2; kk++)
                af[kk] = *(const bf16x8*)(Am + (16 * wave + fcol) * 72 + kk * 32 + quad * 8);
            floatx4 pfr[4], yfr[4];
#pragma unroll
            for (int n = 0; n < 4; n++) {
                pfr[n] = (floatx4){0.f, 0.f, 0.f, 0.f};
                yfr[n] = (floatx4){0.f, 0.f, 0.f, 0.f};
#pragma unroll
                for (int kk = 0; kk < 2; kk++) {
                    bf16x8 bF = *(const bf16x8*)(Bm + (16 * n + fcol) * 72 + kk * 32 + quad * 8);
                    bf16x8 sF = *(const bf16x8*)(ST + (16 * n + fcol) * 72 + kk * 32 + quad * 8);
                    pfr[n] = __builtin_amdgcn_mfma_f32_16x16x32_bf16(af[kk], bF, pfr[n], 0, 0, 0);
                    yfr[n] = __builtin_amdgcn_mfma_f32_16x16x32_bf16(af[kk], sF, yfr[n], 0, 0, 0);
                }
            }
#pragma unroll
            for (int n = 0; n < 4; n++)
#pragma unroll
                for (int g = 0; g < 4; g++) {
                    int t = 16 * wave + quad * 4 + g;
                    int s = 16 * n + fcol;
                    Pm[t * 72 + s] = (s < t) ? __float2bfloat16(pfr[n][g])
                                             : __float2bfloat16(0.0f);
                }
            float eg[4];
#pragma unroll
            for (int g = 0; g < 4; g++) eg[g] = efin[16 * wave + quad * 4 + g];
#pragma unroll
            for (int n = 0; n < 4; n++)
#pragma unroll
                for (int g = 0; g < 4; g++) sfr[n][g] *= eg[g];
            bf16x8 pf[2], cf[2];
#pragma unroll
            for (int kk = 0; kk < 2; kk++) {
                pf[kk] = *(const bf16x8*)(Pm + (16 * wave + fcol) * 72 + kk * 32 + quad * 8);
                cf[kk] = *(const bf16x8*)(CT + (16 * wave + fcol) * 72 + kk * 32 + quad * 8);
            }
#pragma unroll
            for (int n = 0; n < 4; n++) {
#pragma unroll
                for (int kk = 0; kk < 2; kk++) {
                    bf16x8 vF = *(const bf16x8*)(VT + (16 * n + fcol) * 72 + kk * 32 + quad * 8);
                    yfr[n] = __builtin_amdgcn_mfma_f32_16x16x32_bf16(pf[kk], vF, yfr[n], 0, 0, 0);
                    sfr[n] = __builtin_amdgcn_mfma_f32_16x16x32_bf16(cf[kk], vF, sfr[n], 0, 0, 0);
                }
            }
#pragma unroll
            for (int n = 0; n < 4; n++)
#pragma unroll
                for (int g = 0; g < 4; g++) {
                    int t = 16 * wave + quad * 4 + g;
                    int s = 16 * n + fcol;
                    size_t addr = cb + (size_t)t * C_DIM + s;
                    float yv = __bfloat162float(Ys[cur][t * 64 + s]) + yfr[n][g];
                    y[addr] = __float2bfloat16(yv);
                }
        }
    }
    {
        float* so = state_out + (size_t)bh * 4096;
#pragma unroll
        for (int n = 0; n < 4; n++)
#pragma unroll
            for (int g = 0; g < 4; g++)
                so[(size_t)(16 * wave + quad * 4 + g) * 64 + 16 * n + fcol] = sfr[n][g];
    }
}

// ---------------- in-place LayerNorm on bf16 rows ---------------------------
__global__ __launch_bounds__(256) void k_addln(
    __hip_bfloat16* __restrict__ y,
    const float* __restrict__ lnw, const float* __restrict__ lnb)
{
    __shared__ float ls[4], ls2[4];
    const int row = blockIdx.x;
    const size_t base = (size_t)row * C_DIM;
    const int tid = threadIdx.x;
    const int c0 = tid * 8;
    union { bf16x8 v8; __hip_bfloat16 e[8]; } uin;
    uin.v8 = *(const bf16x8*)(y + base + c0);
    float vbuf[8];
#pragma unroll
    for (int j = 0; j < 8; j++) vbuf[j] = __bfloat162float(uin.e[j]);
    float s = 0.f, s2 = 0.f;
#pragma unroll
    for (int j = 0; j < 8; j++) { s += vbuf[j]; s2 += vbuf[j] * vbuf[j]; }
#pragma unroll
    for (int off = 32; off > 0; off >>= 1) {
        s += __shfl_down(s, off, 64);
        s2 += __shfl_down(s2, off, 64);
    }
    const int w = tid >> 6;
    if ((tid & 63) == 0) { ls[w] = s; ls2[w] = s2; }
    __syncthreads();
    float S = ls[0] + ls[1] + ls[2] + ls[3];
    float S2 = ls2[0] + ls2[1] + ls2[2] + ls2[3];
    float mu = S * (1.0f / C_DIM);
    float var = S2 * (1.0f / C_DIM) - mu * mu;
    float rs = rsqrtf(var + 1e-5f);
    union { bf16x8 v8; __hip_bfloat16 e[8]; } u;
#pragma unroll
    for (int j = 0; j < 8; j++) {
        int ccc = c0 + j;
        u.e[j] = __float2bfloat16((vbuf[j] - mu) * rs * lnw[ccc] + lnb[ccc]);
    }
    *(bf16x8*)(y + base + c0) = u.v8;
}

// ---------------------------------------------------------------------------
extern "C" void kernel_launch(void* const* d_in, const int* in_sizes, int n_in,
                              void* d_out, int out_size, void* d_ws, size_t ws_size,
                              hipStream_t stream)
{
    const float* x     = (const float*)d_in[0];
    const float* shift = (const float*)d_in[1];
    const float* wkvin = (const float*)d_in[2];
    const float* tmx   = (const float*)d_in[3];
    const float* tmr   = (const float*)d_in[4];
    const float* tmk   = (const float*)d_in[5];
    const float* tmv   = (const float*)d_in[6];
    const float* tmw   = (const float*)d_in[7];
    const float* tmv2  = (const float*)d_in[8];
    const float* w1    = (const float*)d_in[9];
    const float* w2    = (const float*)d_in[10];
    const float* tdec  = (const float*)d_in[11];
    const float* dw1   = (const float*)d_in[12];
    const float* dw2   = (const float*)d_in[13];
    const float* vw1   = (const float*)d_in[14];
    const float* vw2   = (const float*)d_in[15];
    const float* Wr    = (const float*)d_in[16];
    const float* Wk    = (const float*)d_in[17];
    const float* Wv    = (const float*)d_in[18];
    const float* Wo    = (const float*)d_in[19];
    const float* lnw   = (const float*)d_in[20];
    const float* lnb   = (const float*)d_in[21];

    const size_t SZ_XBF = (size_t)M_ROWS * C_DIM * 2;
    const size_t SZ_WBF = (size_t)C_DIM * C_DIM * 2;
    char* ws = (char*)d_ws;
    size_t off = 0;
    __hip_bfloat16* S0 = (__hip_bfloat16*)(ws + off); off += SZ_XBF; // xr -> v
    __hip_bfloat16* S1 = (__hip_bfloat16*)(ws + off); off += SZ_XBF; // xk -> r
    __hip_bfloat16* S2 = (__hip_bfloat16*)(ws + off); off += SZ_XBF; // xv -> v2/y
    __hip_bfloat16* S3 = (__hip_bfloat16*)(ws + off); off += SZ_XBF; // xw -> k
    __hip_bfloat16* S4 = (__hip_bfloat16*)(ws + off); off += SZ_XBF; // xv2
    char* D = ws + off; off += (size_t)M_ROWS * C_DIM * 4;  // XX||H, then decay
    __hip_bfloat16* XX    = (__hip_bfloat16*)D;
    __hip_bfloat16* Hb    = (__hip_bfloat16*)(D + SZ_XBF); // bf16 H [8192][256]
    float*          decay = (float*)D;
    __hip_bfloat16* WrT = (__hip_bfloat16*)(ws + off); off += SZ_WBF;
    __hip_bfloat16* WkT = (__hip_bfloat16*)(ws + off); off += SZ_WBF;
    __hip_bfloat16* WvT = (__hip_bfloat16*)(ws + off); off += SZ_WBF;
    __hip_bfloat16* WoT = (__hip_bfloat16*)(ws + off); off += SZ_WBF;
    __hip_bfloat16* w1tb  = (__hip_bfloat16*)(ws + off); off += (size_t)256 * 2048 * 2;
    __hip_bfloat16* dw1t  = (__hip_bfloat16*)(ws + off); off += (size_t)64 * 2048 * 2;
    __hip_bfloat16* vw1t  = (__hip_bfloat16*)(ws + off); off += (size_t)64 * 2048 * 2;
    __hip_bfloat16* dw2t  = (__hip_bfloat16*)(ws + off); off += (size_t)2048 * 64 * 2;
    __hip_bfloat16* vw2t  = (__hip_bfloat16*)(ws + off); off += (size_t)2048 * 64 * 2;
    __hip_bfloat16* Gd    = (__hip_bfloat16*)(ws + off); off += (size_t)M_ROWS * 64 * 2;
    __hip_bfloat16* Gv    = (__hip_bfloat16*)(ws + off); off += (size_t)M_ROWS * 64 * 2;
    __hip_bfloat16* w2T   = (__hip_bfloat16*)(ws + off); off += (size_t)2048 * 160 * 2;
    if (ws_size < off) {
        fprintf(stderr, "kernel_launch: ws too small (%zu < %zu)\n", ws_size, off);
        return;
    }

    float* out_y     = (float*)d_out;
    float* out_xlast = out_y + (size_t)M_ROWS * C_DIM;
    float* out_state = out_xlast + (size_t)B_DIM * C_DIM;

    // ---- weight prep ----
    k_transpose<<<dim3(8, 64),  256, 0, stream>>>(w1,  w1tb, 2048, 160, 1);
    k_transpose<<<dim3(2, 64),  256, 0, stream>>>(dw1, dw1t, 2048, 64, 1);
    k_transpose<<<dim3(2, 64),  256, 0, stream>>>(vw1, vw1t, 2048, 64, 1);
    k_transpose<<<dim3(64, 2),  256, 0, stream>>>(dw2, dw2t, 64, 2048, 1);
    k_transpose<<<dim3(64, 2),  256, 0, stream>>>(vw2, vw2t, 64, 2048, 1);
    k_transpose<<<dim3(64, 5),  256, 0, stream>>>(w2,  w2T,  160, 2048, 1);
    k_transpose<<<dim3(64, 64), 256, 0, stream>>>(Wr, WrT, 2048, 2048, 1);
    k_transpose<<<dim3(64, 64), 256, 0, stream>>>(Wk, WkT, 2048, 2048, 1);
    k_transpose<<<dim3(64, 64), 256, 0, stream>>>(Wv, WvT, 2048, 2048, 1);
    k_transpose<<<dim3(64, 64), 256, 0, stream>>>(Wo, WoT, 2048, 2048, 1);

    // ---- mixer ----
    k_xx<<<M_ROWS, 256, 0, stream>>>(x, shift, tmx, XX, out_xlast);
    k_gemm_h<<<128, 256, 0, stream>>>(XX, w1tb, Hb);
    k_mixfused<<<2048, 256, 0, stream>>>(x, shift, Hb, w2T,
                                         tmr, tmk, tmv, tmw, tmv2,
                                         S0, S1, S2, S3, S4);
    // ---- LoRA hidden layers ----
    k_gemm_n64<<<128, 256, 0, stream>>>(S3, dw1t, Gd);   // from xw (frees S3)
    k_gemm_n64<<<128, 256, 0, stream>>>(S4, vw1t, Gv);   // from xv2
    // ---- big GEMMs (outputs recycle freed x-slots; raw k now) ----
    k_gemm256<<<256, 512, 0, stream>>>(S1, WkT, 1, nullptr, S3);   // k  (xk->S3)
    k_gemm256<<<256, 512, 0, stream>>>(S0, WrT, 1, nullptr, S1);   // r  (xr->S1)
    k_gemm256<<<256, 512, 0, stream>>>(S2, WvT, 1, nullptr, S0);   // v  (xv->S0)
    k_gemm256<<<256, 512, 0, stream>>>(S4, WvT, 1, nullptr, S2);   // v2 (xv2->S2)
    // ---- merged K=64 epilogues: decay (fp32 into D) + v2 += lora ----
    k_gemm64<<<2048, 256, 0, stream>>>(Gd, dw2t, Gv, vw2t, decay, tdec, S2);
    // ---- chunked WKV scan (k~ = k*(1-d) inline; adds v2 in-place in S2) ----
    k_scan_chunked<<<128, 256, 0, stream>>>(S1, S3, S0, decay, wkvin, S2, out_state);
    // ---- LayerNorm (in-place) + output projection ----
    k_addln<<<M_ROWS, 256, 0, stream>>>(S2, lnw, lnb);
    k_gemm256<<<256, 512, 0, stream>>>(S2, WoT, 0, out_y, nullptr);

    (void)in_sizes; (void)n_in; (void)out_size;
}

// Round 6
// 1117.309 us; speedup vs baseline: 1.1594x; 1.0180x over previous
//
#include <hip/hip_runtime.h>
#include <hip/hip_bf16.h>
#include <cstdio>

// ---------------------------------------------------------------------------
// RWKV6 TimeMix: B=4, T=2048, C=2048, H=32, N=64, DMIX=32, DDEC=64
// ---------------------------------------------------------------------------

typedef __attribute__((ext_vector_type(8))) short bf16x8;    // 8 bf16 = 4 VGPRs
typedef __attribute__((ext_vector_type(4))) float floatx4;

#define T_DIM 2048
#define C_DIM 2048
#define B_DIM 4
#define M_ROWS (B_DIM * T_DIM)   // 8192

// ---------------- global_load_lds helper (16B per lane) --------------------
typedef const unsigned int __attribute__((address_space(1)))* gas1_t;
typedef unsigned int __attribute__((address_space(3)))* las3_t;
__device__ __forceinline__ void gl_lds16(const void* g, void* l) {
    __builtin_amdgcn_global_load_lds((gas1_t)g, (las3_t)l, 16, 0, 0);
}

// ---------------- transpose + cast + zero-pad ------------------------------
__global__ __launch_bounds__(256) void k_transpose(
    const float* __restrict__ in, void* __restrict__ out,
    int R, int Cin, int to_bf16)
{
    __shared__ float tile[32][33];
    const int tx = threadIdx.x & 31, ty = threadIdx.x >> 5;
    const int cbase = blockIdx.x * 32, rbase = blockIdx.y * 32;
#pragma unroll
    for (int i = 0; i < 4; i++) {
        int r = rbase + ty + i * 8;
        int c = cbase + tx;
        tile[ty + i * 8][tx] = (c < Cin) ? in[(size_t)r * Cin + c] : 0.0f;
    }
    __syncthreads();
    if (to_bf16) {
        __hip_bfloat16* ob = (__hip_bfloat16*)out;
#pragma unroll
        for (int i = 0; i < 4; i++) {
            int c = cbase + ty + i * 8;
            ob[(size_t)c * R + rbase + tx] = __float2bfloat16(tile[tx][ty + i * 8]);
        }
    } else {
        float* of = (float*)out;
#pragma unroll
        for (int i = 0; i < 4; i++) {
            int c = cbase + ty + i * 8;
            of[(size_t)c * R + rbase + tx] = tile[tx][ty + i * 8];
        }
    }
}

// ---------------- XX = bf16(x + (prev-x)*tmx); also x_last ------------------
__global__ __launch_bounds__(256) void k_xx(
    const float* __restrict__ x, const float* __restrict__ shift,
    const float* __restrict__ tmx,
    __hip_bfloat16* __restrict__ XX, float* __restrict__ xlast)
{
    const int row = blockIdx.x;
    const int b = row >> 11, t = row & 2047;
    const int c0 = threadIdx.x * 8;
    const float* xrow = x + (size_t)row * C_DIM;
    const float* prow = (t == 0) ? (shift + (size_t)b * C_DIM) : (xrow - C_DIM);
    float4 xa = ((const float4*)(xrow + c0))[0];
    float4 xb = ((const float4*)(xrow + c0))[1];
    float4 pa = ((const float4*)(prow + c0))[0];
    float4 pb = ((const float4*)(prow + c0))[1];
    float xv8[8] = {xa.x, xa.y, xa.z, xa.w, xb.x, xb.y, xb.z, xb.w};
    float pv8[8] = {pa.x, pa.y, pa.z, pa.w, pb.x, pb.y, pb.z, pb.w};
    union { bf16x8 v8; __hip_bfloat16 e[8]; } u;
#pragma unroll
    for (int j = 0; j < 8; j++)
        u.e[j] = __float2bfloat16(fmaf(pv8[j] - xv8[j], tmx[c0 + j], xv8[j]));
    *(bf16x8*)(XX + (size_t)row * C_DIM + c0) = u.v8;
    if (t == T_DIM - 1) {
        ((float4*)(xlast + (size_t)b * C_DIM + c0))[0] = xa;
        ((float4*)(xlast + (size_t)b * C_DIM + c0))[1] = xb;
    }
}

// ---------------- H = bf16(tanh(XX @ w1)) : M=8192, N=256(pad), K=2048 ------
__global__ __launch_bounds__(256) void k_gemm_h(
    const __hip_bfloat16* __restrict__ A,
    const __hip_bfloat16* __restrict__ Bt,
    __hip_bfloat16* __restrict__ Hout)
{
    __shared__ __hip_bfloat16 As[64 * 32];
    __shared__ __hip_bfloat16 Bs[256 * 32];
    const int tid = threadIdx.x;
    const int m0 = blockIdx.x * 64;
    const int wave = tid >> 6, lane = tid & 63;
    const int fcol = lane & 15, quad = lane >> 4;
    floatx4 acc[16];
#pragma unroll
    for (int i = 0; i < 16; i++) acc[i] = (floatx4){0.f, 0.f, 0.f, 0.f};

    const int rA = tid >> 2, kcA = (tid & 3) * 8;
    const __hip_bfloat16* gA = A + (size_t)(m0 + rA) * 2048 + kcA;
    __hip_bfloat16* lA = As + tid * 8;
    const __hip_bfloat16* gB[4];
    __hip_bfloat16* lB[4];
#pragma unroll
    for (int s = 0; s < 4; s++) {
        int q = tid + 256 * s;
        gB[s] = Bt + (size_t)(q >> 2) * 2048 + (q & 3) * 8;
        lB[s] = Bs + q * 8;
    }
    for (int kk = 0; kk < 2048; kk += 32) {
        gl_lds16(gA + kk, lA);
#pragma unroll
        for (int s = 0; s < 4; s++) gl_lds16(gB[s] + kk, lB[s]);
        __syncthreads();
        bf16x8 aF = *(const bf16x8*)(As + (wave * 16 + fcol) * 32 + quad * 8);
#pragma unroll
        for (int ni = 0; ni < 16; ni++) {
            bf16x8 bF = *(const bf16x8*)(Bs + (ni * 16 + fcol) * 32 + quad * 8);
            acc[ni] = __builtin_amdgcn_mfma_f32_16x16x32_bf16(aF, bF, acc[ni], 0, 0, 0);
        }
        __syncthreads();
    }
#pragma unroll
    for (int ni = 0; ni < 16; ni++) {
        int col = ni * 16 + fcol;
#pragma unroll
        for (int g = 0; g < 4; g++) {
            int row = m0 + wave * 16 + quad * 4 + g;
            Hout[(size_t)row * 256 + col] = __float2bfloat16(tanhf(acc[ni][g]));
        }
    }
}

// ---------------- G = tanh(A @ Bt^T) : N=64, K=2048 -------------------------
__global__ __launch_bounds__(256) void k_gemm_n64(
    const __hip_bfloat16* __restrict__ A,
    const __hip_bfloat16* __restrict__ Bt,
    __hip_bfloat16* __restrict__ G)
{
    __shared__ __hip_bfloat16 As[64 * 32];
    __shared__ __hip_bfloat16 Bs[64 * 32];
    const int tid = threadIdx.x;
    const int m0 = blockIdx.x * 64;
    const int wave = tid >> 6, lane = tid & 63;
    const int fcol = lane & 15, quad = lane >> 4;
    floatx4 acc[4];
#pragma unroll
    for (int i = 0; i < 4; i++) acc[i] = (floatx4){0.f, 0.f, 0.f, 0.f};

    const int r = tid >> 2, kc = (tid & 3) * 8;
    const __hip_bfloat16* gA = A + (size_t)(m0 + r) * 2048 + kc;
    const __hip_bfloat16* gB = Bt + (size_t)r * 2048 + kc;
    __hip_bfloat16* lA = As + tid * 8;
    __hip_bfloat16* lB = Bs + tid * 8;
    for (int kk = 0; kk < 2048; kk += 32) {
        gl_lds16(gA + kk, lA);
        gl_lds16(gB + kk, lB);
        __syncthreads();
        bf16x8 aF = *(const bf16x8*)(As + (wave * 16 + fcol) * 32 + quad * 8);
#pragma unroll
        for (int ni = 0; ni < 4; ni++) {
            bf16x8 bF = *(const bf16x8*)(Bs + (ni * 16 + fcol) * 32 + quad * 8);
            acc[ni] = __builtin_amdgcn_mfma_f32_16x16x32_bf16(aF, bF, acc[ni], 0, 0, 0);
        }
        __syncthreads();
    }
#pragma unroll
    for (int ni = 0; ni < 4; ni++) {
        int col = ni * 16 + fcol;
#pragma unroll
        for (int g = 0; g < 4; g++) {
            int row = m0 + wave * 16 + quad * 4 + g;
            G[(size_t)row * 64 + col] = __float2bfloat16(tanhf(acc[ni][g]));
        }
    }
}

// ---------------- fused mix: xout_f = x + dx*(maa_f + H_f @ w2_f) -----------
__global__ __launch_bounds__(256) void k_mixfused(
    const float* __restrict__ x, const float* __restrict__ shift,
    const __hip_bfloat16* __restrict__ Hb,
    const __hip_bfloat16* __restrict__ w2T,
    const float* __restrict__ tmr, const float* __restrict__ tmk,
    const float* __restrict__ tmv, const float* __restrict__ tmw,
    const float* __restrict__ tmv2,
    __hip_bfloat16* __restrict__ xr, __hip_bfloat16* __restrict__ xk,
    __hip_bfloat16* __restrict__ xv, __hip_bfloat16* __restrict__ xw,
    __hip_bfloat16* __restrict__ xv2)
{
    __shared__ float          xp[33 * 256];     // [0]=prev/shift, [1..32]=x rows
    __shared__ __hip_bfloat16 Hs[32 * 256];     // H-slab (cols 160..255 unused)
    __shared__ __hip_bfloat16 mixS[32 * 256];   // one f's mix tile

    const int tid = threadIdx.x;
    const int bid = blockIdx.x;
    const int n0 = (bid & 7) * 256;
    const int m0 = (bid >> 3) * 32;
    const int wave = tid >> 6, lane = tid & 63;
    const int fcol = lane & 15, quad = lane >> 4;
    const int wm = (wave >> 1) * 16, wn = (wave & 1) * 128;

    // ---- stage x-slab + boundary row + H-slab ----
#pragma unroll
    for (int i = 0; i < 8; i++) {
        int row = i * 4 + wave;
        gl_lds16(x + (size_t)(m0 + row) * C_DIM + n0 + lane * 4,
                 xp + (row + 1) * 256 + lane * 4);
    }
    if (wave == 0) {
        const float* src = (m0 & 2047)
            ? (x + (size_t)(m0 - 1) * C_DIM + n0)
            : (shift + (size_t)(m0 >> 11) * C_DIM + n0);
        gl_lds16(src + lane * 4, xp + lane * 4);
    }
#pragma unroll
    for (int i = 0; i < 4; i++) {
        int q = tid + 256 * i;
        gl_lds16(Hb + (size_t)(m0 + (q >> 5)) * 256 + (q & 31) * 8,
                 Hs + (q >> 5) * 256 + (q & 31) * 8);
    }
    asm volatile("s_waitcnt vmcnt(0) lgkmcnt(0)" ::: "memory");
    __builtin_amdgcn_s_barrier();
    __builtin_amdgcn_sched_barrier(0);

    const float* maas[5] = {tmr, tmk, tmv, tmw, tmv2};
    __hip_bfloat16* outs[5] = {xr, xk, xv, xw, xv2};
    const int cc = tid & 31, c0 = cc * 8, rb = tid >> 5;

#pragma unroll
    for (int f = 0; f < 5; f++) {
        // ---- phase B: mix_f tile via MFMA (one K=32 step) ----
        {
            bf16x8 aF = *(const bf16x8*)(Hs + (wm + fcol) * 256 + f * 32 + quad * 8);
            floatx4 acc[8];
#pragma unroll
            for (int nf = 0; nf < 8; nf++) {
                bf16x8 bF = *(const bf16x8*)(
                    w2T + (size_t)(n0 + wn + nf * 16 + fcol) * 160 + f * 32 + quad * 8);
                acc[nf] = __builtin_amdgcn_mfma_f32_16x16x32_bf16(
                    aF, bF, (floatx4){0.f, 0.f, 0.f, 0.f}, 0, 0, 0);
            }
#pragma unroll
            for (int nf = 0; nf < 8; nf++)
#pragma unroll
                for (int g = 0; g < 4; g++)
                    mixS[(wm + quad * 4 + g) * 256 + wn + nf * 16 + fcol] =
                        __float2bfloat16(acc[nf][g]);
        }
        asm volatile("s_waitcnt lgkmcnt(0)" ::: "memory");
        __builtin_amdgcn_s_barrier();
        __builtin_amdgcn_sched_barrier(0);

        // ---- phase C: xout_f = x + (prev-x)*(maa_f + mix) ----
        {
            float4 ma = ((const float4*)(maas[f] + n0 + c0))[0];
            float4 mb = ((const float4*)(maas[f] + n0 + c0))[1];
            float m8[8] = {ma.x, ma.y, ma.z, ma.w, mb.x, mb.y, mb.z, mb.w};
#pragma unroll
            for (int i = 0; i < 4; i++) {
                int row = rb + 8 * i;
                float4 xa = ((const float4*)(xp + (row + 1) * 256 + c0))[0];
                float4 xb = ((const float4*)(xp + (row + 1) * 256 + c0))[1];
                float4 pa = ((const float4*)(xp + row * 256 + c0))[0];
                float4 pb = ((const float4*)(xp + row * 256 + c0))[1];
                float xv8[8] = {xa.x, xa.y, xa.z, xa.w, xb.x, xb.y, xb.z, xb.w};
                float pv8[8] = {pa.x, pa.y, pa.z, pa.w, pb.x, pb.y, pb.z, pb.w};
                union { bf16x8 v8; __hip_bfloat16 e[8]; } mu;
                mu.v8 = *(const bf16x8*)(mixS + row * 256 + c0);
                union { bf16x8 v8; __hip_bfloat16 e[8]; } u;
#pragma unroll
                for (int j = 0; j < 8; j++) {
                    float dx = pv8[j] - xv8[j];
                    float mixv = __bfloat162float(mu.e[j]);
                    u.e[j] = __float2bfloat16(fmaf(dx, m8[j] + mixv, xv8[j]));
                }
                *(bf16x8*)(outs[f] + (size_t)(m0 + row) * C_DIM + n0 + c0) = u.v8;
            }
        }
        if (f < 4) {
            asm volatile("s_waitcnt lgkmcnt(0)" ::: "memory");
            __builtin_amdgcn_s_barrier();
            __builtin_amdgcn_sched_barrier(0);
        }
    }
}

// ---------------- big MFMA GEMM: M=8192, N=2048, K=2048 ---------------------
// 256x256 tile, BK=32, 512 threads (8 waves as 2m x 4n), 4-slot LDS ring
// (128 KiB), counted vmcnt(8) deep pipeline (T3+T4). Grid 256 = 1 block/CU.
// mode 0: outF = val     mode 1: outB = bf16(val)
__global__ __launch_bounds__(512, 2) void k_gemm256(
    const __hip_bfloat16* __restrict__ A,
    const __hip_bfloat16* __restrict__ Bt,
    int mode,
    float* __restrict__ outF, __hip_bfloat16* __restrict__ outB)
{
    constexpr int K = 2048;
    constexpr int NT = K / 32;          // 64 k-tiles
    __shared__ __hip_bfloat16 LA[4][256 * 32];   // 64 KiB
    __shared__ __hip_bfloat16 LB[4][256 * 32];   // 64 KiB
    const int tid = threadIdx.x;
    const int bid = blockIdx.x;
    const int n0 = (bid & 7) * 256;     // XCD == n-tile
    const int m0 = (bid >> 3) * 256;
    const int wave = tid >> 6, lane = tid & 63;
    const int wm = (wave >> 2) * 128, wn = (wave & 3) * 64;
    const int fcol = lane & 15, quad = lane >> 4;

    floatx4 acc[8][4];
#pragma unroll
    for (int mi = 0; mi < 8; mi++)
#pragma unroll
        for (int ni = 0; ni < 4; ni++)
            acc[mi][ni] = (floatx4){0.f, 0.f, 0.f, 0.f};

    const int ch0 = wave * 2, ch1 = wave * 2 + 1;
    const int rr = lane >> 2, kc = (lane & 3) * 8;
    const __hip_bfloat16* pA0 = A  + (size_t)(m0 + ch0 * 16 + rr) * K + kc;
    const __hip_bfloat16* pA1 = A  + (size_t)(m0 + ch1 * 16 + rr) * K + kc;
    const __hip_bfloat16* pB0 = Bt + (size_t)(n0 + ch0 * 16 + rr) * K + kc;
    const __hip_bfloat16* pB1 = Bt + (size_t)(n0 + ch1 * 16 + rr) * K + kc;
    const int lo0 = ch0 * 512 + lane * 8;
    const int lo1 = ch1 * 512 + lane * 8;

    int ns = 0;
    for (; ns < 3; ++ns) {
        gl_lds16(pA0 + ns * 32, &LA[ns][lo0]);
        gl_lds16(pA1 + ns * 32, &LA[ns][lo1]);
        gl_lds16(pB0 + ns * 32, &LB[ns][lo0]);
        gl_lds16(pB1 + ns * 32, &LB[ns][lo1]);
    }
    for (int t = 0; t < NT; ++t) {
        if (t < NT - 2)       asm volatile("s_waitcnt vmcnt(8)" ::: "memory");
        else if (t == NT - 2) asm volatile("s_waitcnt vmcnt(4)" ::: "memory");
        else                  asm volatile("s_waitcnt vmcnt(0)" ::: "memory");
        asm volatile("s_barrier" ::: "memory");
        if (ns < NT) {
            const int sl = ns & 3;
            gl_lds16(pA0 + ns * 32, &LA[sl][lo0]);
            gl_lds16(pA1 + ns * 32, &LA[sl][lo1]);
            gl_lds16(pB0 + ns * 32, &LB[sl][lo0]);
            gl_lds16(pB1 + ns * 32, &LB[sl][lo1]);
            ++ns;
        }
        const int st = t & 3;
        const __hip_bfloat16* ab = &LA[st][(wm + fcol) * 32 + quad * 8];
        const __hip_bfloat16* bb = &LB[st][(wn + fcol) * 32 + quad * 8];
        bf16x8 bF[4];
#pragma unroll
        for (int ni = 0; ni < 4; ni++)
            bF[ni] = *(const bf16x8*)(bb + ni * 512);
#pragma unroll
        for (int mi = 0; mi < 8; mi++) {
            bf16x8 aF = *(const bf16x8*)(ab + mi * 512);
#pragma unroll
            for (int ni = 0; ni < 4; ni++)
                acc[mi][ni] = __builtin_amdgcn_mfma_f32_16x16x32_bf16(
                    aF, bF[ni], acc[mi][ni], 0, 0, 0);
        }
    }
#pragma unroll
    for (int mi = 0; mi < 8; mi++) {
#pragma unroll
        for (int ni = 0; ni < 4; ni++) {
            int rbase = m0 + wm + mi * 16 + quad * 4;
            int ccol = n0 + wn + ni * 16 + fcol;
#pragma unroll
            for (int g = 0; g < 4; g++) {
                size_t idx = (size_t)(rbase + g) * 2048 + ccol;
                float val = acc[mi][ni][g];
                if (mode == 0) outF[idx] = val;
                else           outB[idx] = __float2bfloat16(val);
            }
        }
    }
}

// ---------------- merged K=64 epilogue GEMMs --------------------------------
__global__ __launch_bounds__(256) void k_gemm64(
    const __hip_bfloat16* __restrict__ A0, const __hip_bfloat16* __restrict__ B0,
    const __hip_bfloat16* __restrict__ A1, const __hip_bfloat16* __restrict__ B1,
    float* __restrict__ decayOut, const float* __restrict__ tdec,
    __hip_bfloat16* __restrict__ v2Out)
{
    constexpr int K = 64;
    __shared__ __hip_bfloat16 As[128 * 32];
    __shared__ __hip_bfloat16 Bs[128 * 32];
    const int tid = threadIdx.x;
    const int op = blockIdx.x >> 10;
    const int id = blockIdx.x & 1023;
    const int xcd = id & 7, jj = id >> 3;
    const int m0 = (((xcd << 3) | (jj & 7))) * 128;
    const int n0 = (jj >> 3) * 128;
    const __hip_bfloat16* A = op ? A1 : A0;
    const __hip_bfloat16* Bt = op ? B1 : B0;
    const int wave = tid >> 6, lane = tid & 63;
    const int wm = (wave >> 1) * 64, wn = (wave & 1) * 64;
    const int fcol = lane & 15, quad = lane >> 4;

    floatx4 acc[4][4];
#pragma unroll
    for (int mi = 0; mi < 4; mi++)
#pragma unroll
        for (int ni = 0; ni < 4; ni++)
            acc[mi][ni] = (floatx4){0.f, 0.f, 0.f, 0.f};

    const int q0 = tid, q1 = tid + 256;
    const int r0 = q0 >> 2, kc0 = (q0 & 3) * 8;
    const int r1 = q1 >> 2, kc1 = (q1 & 3) * 8;
    const __hip_bfloat16* gA0 = A + (size_t)(m0 + r0) * K + kc0;
    const __hip_bfloat16* gA1 = A + (size_t)(m0 + r1) * K + kc1;
    const __hip_bfloat16* gB0 = Bt + (size_t)(n0 + r0) * K + kc0;
    const __hip_bfloat16* gB1 = Bt + (size_t)(n0 + r1) * K + kc1;
    __hip_bfloat16* lA0 = As + q0 * 8; __hip_bfloat16* lA1 = As + q1 * 8;
    __hip_bfloat16* lB0 = Bs + q0 * 8; __hip_bfloat16* lB1 = Bs + q1 * 8;

    for (int kk = 0; kk < K; kk += 32) {
        gl_lds16(gA0 + kk, lA0);
        gl_lds16(gA1 + kk, lA1);
        gl_lds16(gB0 + kk, lB0);
        gl_lds16(gB1 + kk, lB1);
        __syncthreads();
        bf16x8 aF[4], bF[4];
#pragma unroll
        for (int mi = 0; mi < 4; mi++)
            aF[mi] = *(const bf16x8*)(As + (wm + mi * 16 + fcol) * 32 + quad * 8);
#pragma unroll
        for (int ni = 0; ni < 4; ni++)
            bF[ni] = *(const bf16x8*)(Bs + (wn + ni * 16 + fcol) * 32 + quad * 8);
#pragma unroll
        for (int mi = 0; mi < 4; mi++)
#pragma unroll
            for (int ni = 0; ni < 4; ni++)
                acc[mi][ni] = __builtin_amdgcn_mfma_f32_16x16x32_bf16(
                    aF[mi], bF[ni], acc[mi][ni], 0, 0, 0);
        __syncthreads();
    }
#pragma unroll
    for (int mi = 0; mi < 4; mi++) {
#pragma unroll
        for (int ni = 0; ni < 4; ni++) {
            int rbase = m0 + wm + mi * 16 + quad * 4;
            int ccol = n0 + wn + ni * 16 + fcol;
#pragma unroll
            for (int g = 0; g < 4; g++) {
                size_t idx = (size_t)(rbase + g) * 2048 + ccol;
                float val = acc[mi][ni][g];
                if (op == 0) {
                    decayOut[idx] = expf(-expf(val + tdec[ccol]));
                } else {
                    v2Out[idx] = __float2bfloat16(__bfloat162float(v2Out[idx]) + val);
                }
            }
        }
    }
}

// ---------------- chunked WKV scan (flash-linear-attention form) ------------
// 8-wave version (512 threads): was 4 waves = 1 wave/SIMD, Occ 5.3%,
// VALUBusy 10.6% -- pure exposed latency. Wave w owns quadrant slice
// (wr=w&3 -> 16 t/i rows, wc=w>>2 -> 32 j cols): per-phase serial work
// halves, 2 waves/SIMD overlap latencies. P (QK^T analog) is computed in
// DUPLICATE by wave pairs (MfmaUtil was 2.6% -- 8 extra MFMAs are free) so
// the Pm layout shuffle stays intra-wave: duplicate writes are bit-identical
// (same inputs, same ops) -> benign race, no extra barrier. 3 barriers/chunk.
// Double-buffered staging, counted vmcnt(8) at top (8 y-stores in flight).
__global__ __launch_bounds__(512) void k_scan_chunked(
    const __hip_bfloat16* __restrict__ r, const __hip_bfloat16* __restrict__ k,
    const __hip_bfloat16* __restrict__ v, const float* __restrict__ dec,
    const float* __restrict__ state_in,
    __hip_bfloat16* __restrict__ y, float* __restrict__ state_out)
{
    __shared__ __hip_bfloat16 Rs[2][64 * 64];   // 16 KiB
    __shared__ __hip_bfloat16 Ks[2][64 * 64];   // 16 KiB
    __shared__ __hip_bfloat16 Vs[2][64 * 64];   // 16 KiB
    __shared__ float          Dsb[2][64 * 64];  // 32 KiB
    __shared__ __hip_bfloat16 Ys[2][64 * 64];   // 16 KiB (v2 rows of chunk)
    __shared__ __hip_bfloat16 Am[64 * 72];   // a[t][i] = r*Eexc
    __shared__ __hip_bfloat16 Bm[64 * 72];   // b[s][i] = k~/Einc
    __shared__ __hip_bfloat16 VT[64 * 72];   // V^T [j][s]
    __shared__ __hip_bfloat16 CT[64 * 72];   // C^T [i][s]
    __shared__ __hip_bfloat16 ST[64 * 72];   // S^T [j][i]
    __shared__ __hip_bfloat16 Pm[64 * 72];   // masked P [t][s]
    __shared__ float part[8][64];
    __shared__ float efin[64];

    const int tid = threadIdx.x;
    const int bh = blockIdx.x, b = bh >> 5, h = bh & 31;
    const int wave = tid >> 6, lane = tid & 63;
    const int fcol = lane & 15, quad = lane >> 4;
    const int wr = wave & 3, wc = wave >> 2;   // row-group / col-group
    const int ci = lane, seg = wave;           // phase A/B mapping

    floatx4 sfr[2];   // state rows 16*wr..+16, cols 32*wc..+32
    {
        const float* sp = state_in + (size_t)bh * 4096;
#pragma unroll
        for (int n = 0; n < 2; n++)
#pragma unroll
            for (int g = 0; g < 4; g++)
                sfr[n][g] = sp[(size_t)(16 * wr + quad * 4 + g) * 64
                               + 32 * wc + 16 * n + fcol];
    }

    const size_t cbase0 = (size_t)b * T_DIM * C_DIM + (size_t)h * 64;

    // 6 global_load_lds per thread per chunk (512 threads)
    auto stage = [&](int cc, int buf) {
        const size_t cb = cbase0 + (size_t)cc * 64 * C_DIM;
        const size_t o = (size_t)(tid >> 3) * C_DIM + (tid & 7) * 8;
        gl_lds16(r + cb + o, &Rs[buf][tid * 8]);
        gl_lds16(k + cb + o, &Ks[buf][tid * 8]);
        gl_lds16(v + cb + o, &Vs[buf][tid * 8]);
        gl_lds16(y + cb + o, &Ys[buf][tid * 8]);
#pragma unroll
        for (int s = 0; s < 2; s++) {
            int q = tid + 512 * s;
            gl_lds16(dec + cb + (size_t)(q >> 4) * C_DIM + (q & 15) * 4,
                     &Dsb[buf][q * 4]);
        }
    };

    stage(0, 0);

    for (int c = 0; c < 32; c++) {
        const int cur = c & 1, nxt = cur ^ 1;
        const size_t cb = cbase0 + (size_t)c * 64 * C_DIM;

        // top barrier: stage(c) complete; prev chunk's 8 y-stores (newest
        // vmem ops) may remain in flight.
        if (c == 0) asm volatile("s_waitcnt vmcnt(0)" ::: "memory");
        else        asm volatile("s_waitcnt vmcnt(8)" ::: "memory");
        asm volatile("s_waitcnt lgkmcnt(0)" ::: "memory");
        __builtin_amdgcn_s_barrier();
        __builtin_amdgcn_sched_barrier(0);

        if (c + 1 < 32) stage(c + 1, nxt);

        // ---- phase A: publish S^T; per-seg decay products (8 each) ----
        {
#pragma unroll
            for (int n = 0; n < 2; n++)
#pragma unroll
                for (int g = 0; g < 4; g++)
                    ST[(size_t)(32 * wc + 16 * n + fcol) * 72
                       + 16 * wr + quad * 4 + g] = __float2bfloat16(sfr[n][g]);
            float p = 1.0f;
#pragma unroll
            for (int u = 0; u < 8; u++) p *= Dsb[cur][(seg * 8 + u) * 64 + ci];
            part[seg][ci] = p;
        }
        asm volatile("s_waitcnt lgkmcnt(0)" ::: "memory");
        __builtin_amdgcn_s_barrier();   // B2
        __builtin_amdgcn_sched_barrier(0);

        // ---- phase B: build Am/Bm/CT/VT/efin ----
        {
            float pp[8];
#pragma unroll
            for (int s = 0; s < 8; s++) pp[s] = part[s][ci];
            float pre = 1.0f;
#pragma unroll
            for (int s = 0; s < 7; s++) pre *= (s < seg) ? pp[s] : 1.0f;
            float tot = pp[0] * pp[1] * pp[2] * pp[3]
                      * pp[4] * pp[5] * pp[6] * pp[7];
            if (seg == 0) efin[ci] = tot;
            float e = pre;
#pragma unroll
            for (int u = 0; u < 8; u++) {
                int t = seg * 8 + u;
                float d = Dsb[cur][t * 64 + ci];
                float rv = __bfloat162float(Rs[cur][t * 64 + ci]);
                float kv = __bfloat162float(Ks[cur][t * 64 + ci]) * (1.0f - d);
                Am[t * 72 + ci] = __float2bfloat16(rv * e);
                e *= d;
                float bb = kv * __builtin_amdgcn_rcpf(e);
                Bm[t * 72 + ci] = __float2bfloat16(bb);
                CT[ci * 72 + t] = __float2bfloat16(bb * tot);
            }
#pragma unroll
            for (int u = 0; u < 8; u++) {
                int t = seg * 8 + ((u + (ci & 7)) & 7);
                VT[ci * 72 + t] = Vs[cur][t * 64 + ci];
            }
        }
        asm volatile("s_waitcnt lgkmcnt(0)" ::: "memory");
        __builtin_amdgcn_s_barrier();   // B3
        __builtin_amdgcn_sched_barrier(0);

        // ---- phase C: MFMAs + y out + state update ----
        {
            bf16x8 af[2];
#pragma unroll
            for (int kk = 0; kk < 2; kk++)
                af[kk] = *(const bf16x8*)(Am + (16 * wr + fcol) * 72 + kk * 32 + quad * 8);
            // P rows (own t-range), ALL s columns (duplicated across wc pair)
            floatx4 pfr[4];
#pragma unroll
            for (int n4 = 0; n4 < 4; n4++) {
                pfr[n4] = (floatx4){0.f, 0.f, 0.f, 0.f};
#pragma unroll
                for (int kk = 0; kk < 2; kk++) {
                    bf16x8 bF = *(const bf16x8*)(Bm + (16 * n4 + fcol) * 72 + kk * 32 + quad * 8);
                    pfr[n4] = __builtin_amdgcn_mfma_f32_16x16x32_bf16(af[kk], bF, pfr[n4], 0, 0, 0);
                }
            }
            // y from entering state: own j cols
            floatx4 yfr[2];
#pragma unroll
            for (int n = 0; n < 2; n++) {
                yfr[n] = (floatx4){0.f, 0.f, 0.f, 0.f};
#pragma unroll
                for (int kk = 0; kk < 2; kk++) {
                    bf16x8 sF = *(const bf16x8*)(ST + (32 * wc + 16 * n + fcol) * 72 + kk * 32 + quad * 8);
                    yfr[n] = __builtin_amdgcn_mfma_f32_16x16x32_bf16(af[kk], sF, yfr[n], 0, 0, 0);
                }
            }
            // masked P to LDS (duplicate identical writes from wc pair: benign)
#pragma unroll
            for (int n4 = 0; n4 < 4; n4++)
#pragma unroll
                for (int g = 0; g < 4; g++) {
                    int t = 16 * wr + quad * 4 + g;
                    int s = 16 * n4 + fcol;
                    Pm[t * 72 + s] = (s < t) ? __float2bfloat16(pfr[n4][g])
                                             : __float2bfloat16(0.0f);
                }
            float eg[4];
#pragma unroll
            for (int g = 0; g < 4; g++) eg[g] = efin[16 * wr + quad * 4 + g];
#pragma unroll
            for (int n = 0; n < 2; n++)
#pragma unroll
                for (int g = 0; g < 4; g++) sfr[n][g] *= eg[g];
            bf16x8 pf[2], cf[2];
#pragma unroll
            for (int kk = 0; kk < 2; kk++) {
                pf[kk] = *(const bf16x8*)(Pm + (16 * wr + fcol) * 72 + kk * 32 + quad * 8);
                cf[kk] = *(const bf16x8*)(CT + (16 * wr + fcol) * 72 + kk * 32 + quad * 8);
            }
#pragma unroll
            for (int n = 0; n < 2; n++) {
#pragma unroll
                for (int kk = 0; kk < 2; kk++) {
                    bf16x8 vF = *(const bf16x8*)(VT + (32 * wc + 16 * n + fcol) * 72 + kk * 32 + quad * 8);
                    yfr[n] = __builtin_amdgcn_mfma_f32_16x16x32_bf16(pf[kk], vF, yfr[n], 0, 0, 0);
                    sfr[n] = __builtin_amdgcn_mfma_f32_16x16x32_bf16(cf[kk], vF, sfr[n], 0, 0, 0);
                }
            }
#pragma unroll
            for (int n = 0; n < 2; n++)
#pragma unroll
                for (int g = 0; g < 4; g++) {
                    int t = 16 * wr + quad * 4 + g;
                    int j = 32 * wc + 16 * n + fcol;
                    size_t addr = cb + (size_t)t * C_DIM + j;
                    float yv = __bfloat162float(Ys[cur][t * 64 + j]) + yfr[n][g];
                    y[addr] = __float2bfloat16(yv);
                }
        }
    }
    {
        float* so = state_out + (size_t)bh * 4096;
#pragma unroll
        for (int n = 0; n < 2; n++)
#pragma unroll
            for (int g = 0; g < 4; g++)
                so[(size_t)(16 * wr + quad * 4 + g) * 64 + 32 * wc + 16 * n + fcol]
                    = sfr[n][g];
    }
}

// ---------------- in-place LayerNorm on bf16 rows ---------------------------
__global__ __launch_bounds__(256) void k_addln(
    __hip_bfloat16* __restrict__ y,
    const float* __restrict__ lnw, const float* __restrict__ lnb)
{
    __shared__ float ls[4], ls2[4];
    const int row = blockIdx.x;
    const size_t base = (size_t)row * C_DIM;
    const int tid = threadIdx.x;
    const int c0 = tid * 8;
    union { bf16x8 v8; __hip_bfloat16 e[8]; } uin;
    uin.v8 = *(const bf16x8*)(y + base + c0);
    float vbuf[8];
#pragma unroll
    for (int j = 0; j < 8; j++) vbuf[j] = __bfloat162float(uin.e[j]);
    float s = 0.f, s2 = 0.f;
#pragma unroll
    for (int j = 0; j < 8; j++) { s += vbuf[j]; s2 += vbuf[j] * vbuf[j]; }
#pragma unroll
    for (int off = 32; off > 0; off >>= 1) {
        s += __shfl_down(s, off, 64);
        s2 += __shfl_down(s2, off, 64);
    }
    const int w = tid >> 6;
    if ((tid & 63) == 0) { ls[w] = s; ls2[w] = s2; }
    __syncthreads();
    float S = ls[0] + ls[1] + ls[2] + ls[3];
    float S2 = ls2[0] + ls2[1] + ls2[2] + ls2[3];
    float mu = S * (1.0f / C_DIM);
    float var = S2 * (1.0f / C_DIM) - mu * mu;
    float rs = rsqrtf(var + 1e-5f);
    union { bf16x8 v8; __hip_bfloat16 e[8]; } u;
#pragma unroll
    for (int j = 0; j < 8; j++) {
        int ccc = c0 + j;
        u.e[j] = __float2bfloat16((vbuf[j] - mu) * rs * lnw[ccc] + lnb[ccc]);
    }
    *(bf16x8*)(y + base + c0) = u.v8;
}

// ---------------------------------------------------------------------------
extern "C" void kernel_launch(void* const* d_in, const int* in_sizes, int n_in,
                              void* d_out, int out_size, void* d_ws, size_t ws_size,
                              hipStream_t stream)
{
    const float* x     = (const float*)d_in[0];
    const float* shift = (const float*)d_in[1];
    const float* wkvin = (const float*)d_in[2];
    const float* tmx   = (const float*)d_in[3];
    const float* tmr   = (const float*)d_in[4];
    const float* tmk   = (const float*)d_in[5];
    const float* tmv   = (const float*)d_in[6];
    const float* tmw   = (const float*)d_in[7];
    const float* tmv2  = (const float*)d_in[8];
    const float* w1    = (const float*)d_in[9];
    const float* w2    = (const float*)d_in[10];
    const float* tdec  = (const float*)d_in[11];
    const float* dw1   = (const float*)d_in[12];
    const float* dw2   = (const float*)d_in[13];
    const float* vw1   = (const float*)d_in[14];
    const float* vw2   = (const float*)d_in[15];
    const float* Wr    = (const float*)d_in[16];
    const float* Wk    = (const float*)d_in[17];
    const float* Wv    = (const float*)d_in[18];
    const float* Wo    = (const float*)d_in[19];
    const float* lnw   = (const float*)d_in[20];
    const float* lnb   = (const float*)d_in[21];

    const size_t SZ_XBF = (size_t)M_ROWS * C_DIM * 2;
    const size_t SZ_WBF = (size_t)C_DIM * C_DIM * 2;
    char* ws = (char*)d_ws;
    size_t off = 0;
    __hip_bfloat16* S0 = (__hip_bfloat16*)(ws + off); off += SZ_XBF; // xr -> v
    __hip_bfloat16* S1 = (__hip_bfloat16*)(ws + off); off += SZ_XBF; // xk -> r
    __hip_bfloat16* S2 = (__hip_bfloat16*)(ws + off); off += SZ_XBF; // xv -> v2/y
    __hip_bfloat16* S3 = (__hip_bfloat16*)(ws + off); off += SZ_XBF; // xw -> k
    __hip_bfloat16* S4 = (__hip_bfloat16*)(ws + off); off += SZ_XBF; // xv2
    char* D = ws + off; off += (size_t)M_ROWS * C_DIM * 4;  // XX||H, then decay
    __hip_bfloat16* XX    = (__hip_bfloat16*)D;
    __hip_bfloat16* Hb    = (__hip_bfloat16*)(D + SZ_XBF); // bf16 H [8192][256]
    float*          decay = (float*)D;
    __hip_bfloat16* WrT = (__hip_bfloat16*)(ws + off); off += SZ_WBF;
    __hip_bfloat16* WkT = (__hip_bfloat16*)(ws + off); off += SZ_WBF;
    __hip_bfloat16* WvT = (__hip_bfloat16*)(ws + off); off += SZ_WBF;
    __hip_bfloat16* WoT = (__hip_bfloat16*)(ws + off); off += SZ_WBF;
    __hip_bfloat16* w1tb  = (__hip_bfloat16*)(ws + off); off += (size_t)256 * 2048 * 2;
    __hip_bfloat16* dw1t  = (__hip_bfloat16*)(ws + off); off += (size_t)64 * 2048 * 2;
    __hip_bfloat16* vw1t  = (__hip_bfloat16*)(ws + off); off += (size_t)64 * 2048 * 2;
    __hip_bfloat16* dw2t  = (__hip_bfloat16*)(ws + off); off += (size_t)2048 * 64 * 2;
    __hip_bfloat16* vw2t  = (__hip_bfloat16*)(ws + off); off += (size_t)2048 * 64 * 2;
    __hip_bfloat16* Gd    = (__hip_bfloat16*)(ws + off); off += (size_t)M_ROWS * 64 * 2;
    __hip_bfloat16* Gv    = (__hip_bfloat16*)(ws + off); off += (size_t)M_ROWS * 64 * 2;
    __hip_bfloat16* w2T   = (__hip_bfloat16*)(ws + off); off += (size_t)2048 * 160 * 2;
    if (ws_size < off) {
        fprintf(stderr, "kernel_launch: ws too small (%zu < %zu)\n", ws_size, off);
        return;
    }

    float* out_y     = (float*)d_out;
    float* out_xlast = out_y + (size_t)M_ROWS * C_DIM;
    float* out_state = out_xlast + (size_t)B_DIM * C_DIM;

    // ---- weight prep ----
    k_transpose<<<dim3(8, 64),  256, 0, stream>>>(w1,  w1tb, 2048, 160, 1);
    k_transpose<<<dim3(2, 64),  256, 0, stream>>>(dw1, dw1t, 2048, 64, 1);
    k_transpose<<<dim3(2, 64),  256, 0, stream>>>(vw1, vw1t, 2048, 64, 1);
    k_transpose<<<dim3(64, 2),  256, 0, stream>>>(dw2, dw2t, 64, 2048, 1);
    k_transpose<<<dim3(64, 2),  256, 0, stream>>>(vw2, vw2t, 64, 2048, 1);
    k_transpose<<<dim3(64, 5),  256, 0, stream>>>(w2,  w2T,  160, 2048, 1);
    k_transpose<<<dim3(64, 64), 256, 0, stream>>>(Wr, WrT, 2048, 2048, 1);
    k_transpose<<<dim3(64, 64), 256, 0, stream>>>(Wk, WkT, 2048, 2048, 1);
    k_transpose<<<dim3(64, 64), 256, 0, stream>>>(Wv, WvT, 2048, 2048, 1);
    k_transpose<<<dim3(64, 64), 256, 0, stream>>>(Wo, WoT, 2048, 2048, 1);

    // ---- mixer ----
    k_xx<<<M_ROWS, 256, 0, stream>>>(x, shift, tmx, XX, out_xlast);
    k_gemm_h<<<128, 256, 0, stream>>>(XX, w1tb, Hb);
    k_mixfused<<<2048, 256, 0, stream>>>(x, shift, Hb, w2T,
                                         tmr, tmk, tmv, tmw, tmv2,
                                         S0, S1, S2, S3, S4);
    // ---- LoRA hidden layers ----
    k_gemm_n64<<<128, 256, 0, stream>>>(S3, dw1t, Gd);   // from xw (frees S3)
    k_gemm_n64<<<128, 256, 0, stream>>>(S4, vw1t, Gv);   // from xv2
    // ---- big GEMMs (outputs recycle freed x-slots; raw k now) ----
    k_gemm256<<<256, 512, 0, stream>>>(S1, WkT, 1, nullptr, S3);   // k  (xk->S3)
    k_gemm256<<<256, 512, 0, stream>>>(S0, WrT, 1, nullptr, S1);   // r  (xr->S1)
    k_gemm256<<<256, 512, 0, stream>>>(S2, WvT, 1, nullptr, S0);   // v  (xv->S0)
    k_gemm256<<<256, 512, 0, stream>>>(S4, WvT, 1, nullptr, S2);   // v2 (xv2->S2)
    // ---- merged K=64 epilogues: decay (fp32 into D) + v2 += lora ----
    k_gemm64<<<2048, 256, 0, stream>>>(Gd, dw2t, Gv, vw2t, decay, tdec, S2);
    // ---- chunked WKV scan (k~ = k*(1-d) inline; adds v2 in-place in S2) ----
    k_scan_chunked<<<128, 512, 0, stream>>>(S1, S3, S0, decay, wkvin, S2, out_state);
    // ---- LayerNorm (in-place) + output projection ----
    k_addln<<<M_ROWS, 256, 0, stream>>>(S2, lnw, lnb);
    k_gemm256<<<256, 512, 0, stream>>>(S2, WoT, 0, out_y, nullptr);

    (void)in_sizes; (void)n_in; (void)out_size;
}

// Round 7
// 1082.619 us; speedup vs baseline: 1.1965x; 1.0320x over previous
//
#include <hip/hip_runtime.h>
#include <hip/hip_bf16.h>
#include <cstdio>

// ---------------------------------------------------------------------------
// RWKV6 TimeMix: B=4, T=2048, C=2048, H=32, N=64, DMIX=32, DDEC=64
// ---------------------------------------------------------------------------

typedef __attribute__((ext_vector_type(8))) short bf16x8;    // 8 bf16 = 4 VGPRs
typedef __attribute__((ext_vector_type(4))) float floatx4;

#define T_DIM 2048
#define C_DIM 2048
#define B_DIM 4
#define M_ROWS (B_DIM * T_DIM)   // 8192

// ---------------- global_load_lds helper (16B per lane) --------------------
typedef const unsigned int __attribute__((address_space(1)))* gas1_t;
typedef unsigned int __attribute__((address_space(3)))* las3_t;
__device__ __forceinline__ void gl_lds16(const void* g, void* l) {
    __builtin_amdgcn_global_load_lds((gas1_t)g, (las3_t)l, 16, 0, 0);
}

// ---------------- transpose + cast + zero-pad ------------------------------
__global__ __launch_bounds__(256) void k_transpose(
    const float* __restrict__ in, void* __restrict__ out,
    int R, int Cin, int to_bf16)
{
    __shared__ float tile[32][33];
    const int tx = threadIdx.x & 31, ty = threadIdx.x >> 5;
    const int cbase = blockIdx.x * 32, rbase = blockIdx.y * 32;
#pragma unroll
    for (int i = 0; i < 4; i++) {
        int r = rbase + ty + i * 8;
        int c = cbase + tx;
        tile[ty + i * 8][tx] = (c < Cin) ? in[(size_t)r * Cin + c] : 0.0f;
    }
    __syncthreads();
    if (to_bf16) {
        __hip_bfloat16* ob = (__hip_bfloat16*)out;
#pragma unroll
        for (int i = 0; i < 4; i++) {
            int c = cbase + ty + i * 8;
            ob[(size_t)c * R + rbase + tx] = __float2bfloat16(tile[tx][ty + i * 8]);
        }
    } else {
        float* of = (float*)out;
#pragma unroll
        for (int i = 0; i < 4; i++) {
            int c = cbase + ty + i * 8;
            of[(size_t)c * R + rbase + tx] = tile[tx][ty + i * 8];
        }
    }
}

// ---------------- XX = bf16(x + (prev-x)*tmx); also x_last ------------------
__global__ __launch_bounds__(256) void k_xx(
    const float* __restrict__ x, const float* __restrict__ shift,
    const float* __restrict__ tmx,
    __hip_bfloat16* __restrict__ XX, float* __restrict__ xlast)
{
    const int row = blockIdx.x;
    const int b = row >> 11, t = row & 2047;
    const int c0 = threadIdx.x * 8;
    const float* xrow = x + (size_t)row * C_DIM;
    const float* prow = (t == 0) ? (shift + (size_t)b * C_DIM) : (xrow - C_DIM);
    float4 xa = ((const float4*)(xrow + c0))[0];
    float4 xb = ((const float4*)(xrow + c0))[1];
    float4 pa = ((const float4*)(prow + c0))[0];
    float4 pb = ((const float4*)(prow + c0))[1];
    float xv8[8] = {xa.x, xa.y, xa.z, xa.w, xb.x, xb.y, xb.z, xb.w};
    float pv8[8] = {pa.x, pa.y, pa.z, pa.w, pb.x, pb.y, pb.z, pb.w};
    union { bf16x8 v8; __hip_bfloat16 e[8]; } u;
#pragma unroll
    for (int j = 0; j < 8; j++)
        u.e[j] = __float2bfloat16(fmaf(pv8[j] - xv8[j], tmx[c0 + j], xv8[j]));
    *(bf16x8*)(XX + (size_t)row * C_DIM + c0) = u.v8;
    if (t == T_DIM - 1) {
        ((float4*)(xlast + (size_t)b * C_DIM + c0))[0] = xa;
        ((float4*)(xlast + (size_t)b * C_DIM + c0))[1] = xb;
    }
}

// ---------------- H = bf16(tanh(XX @ w1)) : M=8192, N=256(pad), K=2048 ------
__global__ __launch_bounds__(256) void k_gemm_h(
    const __hip_bfloat16* __restrict__ A,
    const __hip_bfloat16* __restrict__ Bt,
    __hip_bfloat16* __restrict__ Hout)
{
    __shared__ __hip_bfloat16 As[64 * 32];
    __shared__ __hip_bfloat16 Bs[256 * 32];
    const int tid = threadIdx.x;
    const int m0 = blockIdx.x * 64;
    const int wave = tid >> 6, lane = tid & 63;
    const int fcol = lane & 15, quad = lane >> 4;
    floatx4 acc[16];
#pragma unroll
    for (int i = 0; i < 16; i++) acc[i] = (floatx4){0.f, 0.f, 0.f, 0.f};

    const int rA = tid >> 2, kcA = (tid & 3) * 8;
    const __hip_bfloat16* gA = A + (size_t)(m0 + rA) * 2048 + kcA;
    __hip_bfloat16* lA = As + tid * 8;
    const __hip_bfloat16* gB[4];
    __hip_bfloat16* lB[4];
#pragma unroll
    for (int s = 0; s < 4; s++) {
        int q = tid + 256 * s;
        gB[s] = Bt + (size_t)(q >> 2) * 2048 + (q & 3) * 8;
        lB[s] = Bs + q * 8;
    }
    for (int kk = 0; kk < 2048; kk += 32) {
        gl_lds16(gA + kk, lA);
#pragma unroll
        for (int s = 0; s < 4; s++) gl_lds16(gB[s] + kk, lB[s]);
        __syncthreads();
        bf16x8 aF = *(const bf16x8*)(As + (wave * 16 + fcol) * 32 + quad * 8);
#pragma unroll
        for (int ni = 0; ni < 16; ni++) {
            bf16x8 bF = *(const bf16x8*)(Bs + (ni * 16 + fcol) * 32 + quad * 8);
            acc[ni] = __builtin_amdgcn_mfma_f32_16x16x32_bf16(aF, bF, acc[ni], 0, 0, 0);
        }
        __syncthreads();
    }
#pragma unroll
    for (int ni = 0; ni < 16; ni++) {
        int col = ni * 16 + fcol;
#pragma unroll
        for (int g = 0; g < 4; g++) {
            int row = m0 + wave * 16 + quad * 4 + g;
            Hout[(size_t)row * 256 + col] = __float2bfloat16(tanhf(acc[ni][g]));
        }
    }
}

// ---------------- G = tanh(A @ Bt^T) : N=64, K=2048 -------------------------
__global__ __launch_bounds__(256) void k_gemm_n64(
    const __hip_bfloat16* __restrict__ A,
    const __hip_bfloat16* __restrict__ Bt,
    __hip_bfloat16* __restrict__ G)
{
    __shared__ __hip_bfloat16 As[64 * 32];
    __shared__ __hip_bfloat16 Bs[64 * 32];
    const int tid = threadIdx.x;
    const int m0 = blockIdx.x * 64;
    const int wave = tid >> 6, lane = tid & 63;
    const int fcol = lane & 15, quad = lane >> 4;
    floatx4 acc[4];
#pragma unroll
    for (int i = 0; i < 4; i++) acc[i] = (floatx4){0.f, 0.f, 0.f, 0.f};

    const int r = tid >> 2, kc = (tid & 3) * 8;
    const __hip_bfloat16* gA = A + (size_t)(m0 + r) * 2048 + kc;
    const __hip_bfloat16* gB = Bt + (size_t)r * 2048 + kc;
    __hip_bfloat16* lA = As + tid * 8;
    __hip_bfloat16* lB = Bs + tid * 8;
    for (int kk = 0; kk < 2048; kk += 32) {
        gl_lds16(gA + kk, lA);
        gl_lds16(gB + kk, lB);
        __syncthreads();
        bf16x8 aF = *(const bf16x8*)(As + (wave * 16 + fcol) * 32 + quad * 8);
#pragma unroll
        for (int ni = 0; ni < 4; ni++) {
            bf16x8 bF = *(const bf16x8*)(Bs + (ni * 16 + fcol) * 32 + quad * 8);
            acc[ni] = __builtin_amdgcn_mfma_f32_16x16x32_bf16(aF, bF, acc[ni], 0, 0, 0);
        }
        __syncthreads();
    }
#pragma unroll
    for (int ni = 0; ni < 4; ni++) {
        int col = ni * 16 + fcol;
#pragma unroll
        for (int g = 0; g < 4; g++) {
            int row = m0 + wave * 16 + quad * 4 + g;
            G[(size_t)row * 64 + col] = __float2bfloat16(tanhf(acc[ni][g]));
        }
    }
}

// ---------------- fused mix: xout_f = x + dx*(maa_f + H_f @ w2_f) -----------
__global__ __launch_bounds__(256) void k_mixfused(
    const float* __restrict__ x, const float* __restrict__ shift,
    const __hip_bfloat16* __restrict__ Hb,
    const __hip_bfloat16* __restrict__ w2T,
    const float* __restrict__ tmr, const float* __restrict__ tmk,
    const float* __restrict__ tmv, const float* __restrict__ tmw,
    const float* __restrict__ tmv2,
    __hip_bfloat16* __restrict__ xr, __hip_bfloat16* __restrict__ xk,
    __hip_bfloat16* __restrict__ xv, __hip_bfloat16* __restrict__ xw,
    __hip_bfloat16* __restrict__ xv2)
{
    __shared__ float          xp[33 * 256];     // [0]=prev/shift, [1..32]=x rows
    __shared__ __hip_bfloat16 Hs[32 * 256];     // H-slab (cols 160..255 unused)
    __shared__ __hip_bfloat16 mixS[32 * 256];   // one f's mix tile

    const int tid = threadIdx.x;
    const int bid = blockIdx.x;
    const int n0 = (bid & 7) * 256;
    const int m0 = (bid >> 3) * 32;
    const int wave = tid >> 6, lane = tid & 63;
    const int fcol = lane & 15, quad = lane >> 4;
    const int wm = (wave >> 1) * 16, wn = (wave & 1) * 128;

    // ---- stage x-slab + boundary row + H-slab ----
#pragma unroll
    for (int i = 0; i < 8; i++) {
        int row = i * 4 + wave;
        gl_lds16(x + (size_t)(m0 + row) * C_DIM + n0 + lane * 4,
                 xp + (row + 1) * 256 + lane * 4);
    }
    if (wave == 0) {
        const float* src = (m0 & 2047)
            ? (x + (size_t)(m0 - 1) * C_DIM + n0)
            : (shift + (size_t)(m0 >> 11) * C_DIM + n0);
        gl_lds16(src + lane * 4, xp + lane * 4);
    }
#pragma unroll
    for (int i = 0; i < 4; i++) {
        int q = tid + 256 * i;
        gl_lds16(Hb + (size_t)(m0 + (q >> 5)) * 256 + (q & 31) * 8,
                 Hs + (q >> 5) * 256 + (q & 31) * 8);
    }
    asm volatile("s_waitcnt vmcnt(0) lgkmcnt(0)" ::: "memory");
    __builtin_amdgcn_s_barrier();
    __builtin_amdgcn_sched_barrier(0);

    const float* maas[5] = {tmr, tmk, tmv, tmw, tmv2};
    __hip_bfloat16* outs[5] = {xr, xk, xv, xw, xv2};
    const int cc = tid & 31, c0 = cc * 8, rb = tid >> 5;

#pragma unroll
    for (int f = 0; f < 5; f++) {
        // ---- phase B: mix_f tile via MFMA (one K=32 step) ----
        {
            bf16x8 aF = *(const bf16x8*)(Hs + (wm + fcol) * 256 + f * 32 + quad * 8);
            floatx4 acc[8];
#pragma unroll
            for (int nf = 0; nf < 8; nf++) {
                bf16x8 bF = *(const bf16x8*)(
                    w2T + (size_t)(n0 + wn + nf * 16 + fcol) * 160 + f * 32 + quad * 8);
                acc[nf] = __builtin_amdgcn_mfma_f32_16x16x32_bf16(
                    aF, bF, (floatx4){0.f, 0.f, 0.f, 0.f}, 0, 0, 0);
            }
#pragma unroll
            for (int nf = 0; nf < 8; nf++)
#pragma unroll
                for (int g = 0; g < 4; g++)
                    mixS[(wm + quad * 4 + g) * 256 + wn + nf * 16 + fcol] =
                        __float2bfloat16(acc[nf][g]);
        }
        asm volatile("s_waitcnt lgkmcnt(0)" ::: "memory");
        __builtin_amdgcn_s_barrier();
        __builtin_amdgcn_sched_barrier(0);

        // ---- phase C: xout_f = x + (prev-x)*(maa_f + mix) ----
        {
            float4 ma = ((const float4*)(maas[f] + n0 + c0))[0];
            float4 mb = ((const float4*)(maas[f] + n0 + c0))[1];
            float m8[8] = {ma.x, ma.y, ma.z, ma.w, mb.x, mb.y, mb.z, mb.w};
#pragma unroll
            for (int i = 0; i < 4; i++) {
                int row = rb + 8 * i;
                float4 xa = ((const float4*)(xp + (row + 1) * 256 + c0))[0];
                float4 xb = ((const float4*)(xp + (row + 1) * 256 + c0))[1];
                float4 pa = ((const float4*)(xp + row * 256 + c0))[0];
                float4 pb = ((const float4*)(xp + row * 256 + c0))[1];
                float xv8[8] = {xa.x, xa.y, xa.z, xa.w, xb.x, xb.y, xb.z, xb.w};
                float pv8[8] = {pa.x, pa.y, pa.z, pa.w, pb.x, pb.y, pb.z, pb.w};
                union { bf16x8 v8; __hip_bfloat16 e[8]; } mu;
                mu.v8 = *(const bf16x8*)(mixS + row * 256 + c0);
                union { bf16x8 v8; __hip_bfloat16 e[8]; } u;
#pragma unroll
                for (int j = 0; j < 8; j++) {
                    float dx = pv8[j] - xv8[j];
                    float mixv = __bfloat162float(mu.e[j]);
                    u.e[j] = __float2bfloat16(fmaf(dx, m8[j] + mixv, xv8[j]));
                }
                *(bf16x8*)(outs[f] + (size_t)(m0 + row) * C_DIM + n0 + c0) = u.v8;
            }
        }
        if (f < 4) {
            asm volatile("s_waitcnt lgkmcnt(0)" ::: "memory");
            __builtin_amdgcn_s_barrier();
            __builtin_amdgcn_sched_barrier(0);
        }
    }
}

// ---------------- big MFMA GEMM: M=8192, N=2048, K=2048 ---------------------
// 8-phase port (T2+T3+T4+T5): 256x256 tile, BK=64, 512 thr (8 waves 2Mx4N),
// 2 LDS dbufs of [2 half][128][64] for A and B (128 KiB). Per K-tile: 4
// C-quadrant phases {barrier; ds_read subtile; issue half-tile stage; setprio1
// 16 MFMA setprio0}; ONE counted vmcnt(4) gate per K-tile (never 0 until
// epilogue) so stages span >=4 phases. Bank-conflict fix per rule 21: LDS
// dest linear, global source col-group pre-swizzled kq=(tid&7)^((tid>>3)&7),
// reader XORs the same involution -> 2 lanes/bank (free). Stage rotation
// B-lo(t+1)@Ph1, B-hi(t+1)@Ph2, A(t+2)@Ph4 places every write >=1 phase after
// the region's last reader crossed a barrier (ledger-verified, incl.
// prologue/epilogue vmcnt counts). Fragment content & C-map unchanged.
// mode 0: outF = val     mode 1: outB = bf16(val)
__global__ __launch_bounds__(512, 2) void k_gemm256(
    const __hip_bfloat16* __restrict__ A,
    const __hip_bfloat16* __restrict__ Bt,
    int mode,
    float* __restrict__ outF, __hip_bfloat16* __restrict__ outB)
{
    constexpr int K = 2048;
    constexpr int NT = K / 64;                 // 32 K-tiles of BK=64
    __shared__ __hip_bfloat16 LA[2][16384];    // [dbuf][half*8192 + row*64 + col]
    __shared__ __hip_bfloat16 LB[2][16384];
    const int tid = threadIdx.x;
    const int bid = blockIdx.x;
    const int n0 = (bid & 7) * 256;            // XCD == n-tile
    const int m0 = (bid >> 3) * 256;
    const int wave = tid >> 6, lane = tid & 63;
    const int wm = (wave >> 2) * 128, wn = (wave & 3) * 64;
    const int fcol = lane & 15, quad = lane >> 4;

    floatx4 acc[8][4];
#pragma unroll
    for (int mi = 0; mi < 8; mi++)
#pragma unroll
        for (int ni = 0; ni < 4; ni++)
            acc[mi][ni] = (floatx4){0.f, 0.f, 0.f, 0.f};

    // ---- staging: pre-swizzled global source, linear LDS dest ----
    const int srow = tid >> 3;                           // 0..63
    const int kqe  = ((tid & 7) ^ (srow & 7)) * 8;       // swizzled col elem
    const __hip_bfloat16* gA = A  + (size_t)(m0 + srow) * K + kqe;
    const __hip_bfloat16* gB = Bt + (size_t)(n0 + srow) * K + kqe;

    auto stageA = [&](int tau) {      // both halves, 4 loads/thread
        __hip_bfloat16* l = &LA[tau & 1][0] + tid * 8;
        const __hip_bfloat16* g = gA + tau * 64;
        gl_lds16(g,                  l);
        gl_lds16(g + (size_t)64*K,   l + 4096);
        gl_lds16(g + (size_t)128*K,  l + 8192);
        gl_lds16(g + (size_t)192*K,  l + 12288);
    };
    auto stageBlo = [&](int tau) {    // 2 loads/thread
        __hip_bfloat16* l = &LB[tau & 1][0] + tid * 8;
        const __hip_bfloat16* g = gB + tau * 64;
        gl_lds16(g,                 l);
        gl_lds16(g + (size_t)64*K,  l + 4096);
    };
    auto stageBhi = [&](int tau) {    // 2 loads/thread
        __hip_bfloat16* l = &LB[tau & 1][0] + 8192 + tid * 8;
        const __hip_bfloat16* g = gB + (size_t)128*K + tau * 64;
        gl_lds16(g,                 l);
        gl_lds16(g + (size_t)64*K,  l + 4096);
    };

    // ---- fragment read addressing (reader-side swizzle) ----
    const int swz0 = (quad ^ (fcol & 7)) * 8;   // kf=0 slot
    const int swz1 = swz0 ^ 32;                 // kf=1 slot ((4+quad)^f7)*8
    const int aOff = (wm >> 7) * 8192 + fcol * 64;
    const int bOff = (wn >> 7) * 8192 + (wn & 127) * 64 + fcol * 64;

    // ---- prologue: tiles 0 and 1 (ledger: A0=4,Blo0=2,Bhi0=2,A1=4) ----
    stageA(0); stageBlo(0); stageBhi(0); stageA(1);
    asm volatile("s_waitcnt vmcnt(4)" ::: "memory");   // tile0 resident; A1 in flight

    bf16x8 a[4][2], b0[2][2], b1[2][2];
    for (int t = 0; t < NT; ++t) {
        const int d = t & 1;
        const __hip_bfloat16* ab = &LA[d][0] + aOff;
        const __hip_bfloat16* bb = &LB[d][0] + bOff;

        // ---- Ph1: Q(mi0-3, ni0-1) ----
        __builtin_amdgcn_s_barrier();
        __builtin_amdgcn_sched_barrier(0);
#pragma unroll
        for (int mi = 0; mi < 4; mi++) {
            a[mi][0] = *(const bf16x8*)(ab + mi * 1024 + swz0);
            a[mi][1] = *(const bf16x8*)(ab + mi * 1024 + swz1);
        }
#pragma unroll
        for (int ni = 0; ni < 2; ni++) {
            b0[ni][0] = *(const bf16x8*)(bb + ni * 1024 + swz0);
            b0[ni][1] = *(const bf16x8*)(bb + ni * 1024 + swz1);
        }
        if (t + 1 < NT) stageBlo(t + 1);
        __builtin_amdgcn_s_setprio(1);
#pragma unroll
        for (int mi = 0; mi < 4; mi++)
#pragma unroll
            for (int ni = 0; ni < 2; ni++) {
                acc[mi][ni] = __builtin_amdgcn_mfma_f32_16x16x32_bf16(a[mi][0], b0[ni][0], acc[mi][ni], 0, 0, 0);
                acc[mi][ni] = __builtin_amdgcn_mfma_f32_16x16x32_bf16(a[mi][1], b0[ni][1], acc[mi][ni], 0, 0, 0);
            }
        __builtin_amdgcn_s_setprio(0);

        // ---- Ph2: Q(mi0-3, ni2-3) ----
        __builtin_amdgcn_s_barrier();
        __builtin_amdgcn_sched_barrier(0);
#pragma unroll
        for (int ni = 0; ni < 2; ni++) {
            b1[ni][0] = *(const bf16x8*)(bb + (2 + ni) * 1024 + swz0);
            b1[ni][1] = *(const bf16x8*)(bb + (2 + ni) * 1024 + swz1);
        }
        if (t + 1 < NT) stageBhi(t + 1);
        __builtin_amdgcn_s_setprio(1);
#pragma unroll
        for (int mi = 0; mi < 4; mi++)
#pragma unroll
            for (int ni = 0; ni < 2; ni++) {
                acc[mi][2 + ni] = __builtin_amdgcn_mfma_f32_16x16x32_bf16(a[mi][0], b1[ni][0], acc[mi][2 + ni], 0, 0, 0);
                acc[mi][2 + ni] = __builtin_amdgcn_mfma_f32_16x16x32_bf16(a[mi][1], b1[ni][1], acc[mi][2 + ni], 0, 0, 0);
            }
        __builtin_amdgcn_s_setprio(0);

        // ---- Ph3: Q(mi4-7, ni2-3) ----
        __builtin_amdgcn_s_barrier();
        __builtin_amdgcn_sched_barrier(0);
#pragma unroll
        for (int mi = 0; mi < 4; mi++) {
            a[mi][0] = *(const bf16x8*)(ab + (4 + mi) * 1024 + swz0);
            a[mi][1] = *(const bf16x8*)(ab + (4 + mi) * 1024 + swz1);
        }
        __builtin_amdgcn_s_setprio(1);
#pragma unroll
        for (int mi = 0; mi < 4; mi++)
#pragma unroll
            for (int ni = 0; ni < 2; ni++) {
                acc[4 + mi][2 + ni] = __builtin_amdgcn_mfma_f32_16x16x32_bf16(a[mi][0], b1[ni][0], acc[4 + mi][2 + ni], 0, 0, 0);
                acc[4 + mi][2 + ni] = __builtin_amdgcn_mfma_f32_16x16x32_bf16(a[mi][1], b1[ni][1], acc[4 + mi][2 + ni], 0, 0, 0);
            }
        __builtin_amdgcn_s_setprio(0);

        // ---- Ph4: Q(mi4-7, ni0-1) ----
        __builtin_amdgcn_s_barrier();
        __builtin_amdgcn_sched_barrier(0);
#pragma unroll
        for (int ni = 0; ni < 2; ni++) {
            b0[ni][0] = *(const bf16x8*)(bb + ni * 1024 + swz0);
            b0[ni][1] = *(const bf16x8*)(bb + ni * 1024 + swz1);
        }
        if (t + 2 < NT) stageA(t + 2);
        __builtin_amdgcn_s_setprio(1);
#pragma unroll
        for (int mi = 0; mi < 4; mi++)
#pragma unroll
            for (int ni = 0; ni < 2; ni++) {
                acc[4 + mi][ni] = __builtin_amdgcn_mfma_f32_16x16x32_bf16(a[mi][0], b0[ni][0], acc[4 + mi][ni], 0, 0, 0);
                acc[4 + mi][ni] = __builtin_amdgcn_mfma_f32_16x16x32_bf16(a[mi][1], b0[ni][1], acc[4 + mi][ni], 0, 0, 0);
            }
        __builtin_amdgcn_s_setprio(0);

        // ---- per-tile gate: next tile's newest region (B-hi) staged @Ph2;
        //      newer outstanding = this Ph4's A-stage (4 loads) -> vmcnt(4).
        if (t < NT - 2)       asm volatile("s_waitcnt vmcnt(4)" ::: "memory");
        else if (t == NT - 2) asm volatile("s_waitcnt vmcnt(0)" ::: "memory");
    }

#pragma unroll
    for (int mi = 0; mi < 8; mi++) {
#pragma unroll
        for (int ni = 0; ni < 4; ni++) {
            int rbase = m0 + wm + mi * 16 + quad * 4;
            int ccol = n0 + wn + ni * 16 + fcol;
#pragma unroll
            for (int g = 0; g < 4; g++) {
                size_t idx = (size_t)(rbase + g) * 2048 + ccol;
                float val = acc[mi][ni][g];
                if (mode == 0) outF[idx] = val;
                else           outB[idx] = __float2bfloat16(val);
            }
        }
    }
}

// ---------------- merged K=64 epilogue GEMMs --------------------------------
__global__ __launch_bounds__(256) void k_gemm64(
    const __hip_bfloat16* __restrict__ A0, const __hip_bfloat16* __restrict__ B0,
    const __hip_bfloat16* __restrict__ A1, const __hip_bfloat16* __restrict__ B1,
    float* __restrict__ decayOut, const float* __restrict__ tdec,
    __hip_bfloat16* __restrict__ v2Out)
{
    constexpr int K = 64;
    __shared__ __hip_bfloat16 As[128 * 32];
    __shared__ __hip_bfloat16 Bs[128 * 32];
    const int tid = threadIdx.x;
    const int op = blockIdx.x >> 10;
    const int id = blockIdx.x & 1023;
    const int xcd = id & 7, jj = id >> 3;
    const int m0 = (((xcd << 3) | (jj & 7))) * 128;
    const int n0 = (jj >> 3) * 128;
    const __hip_bfloat16* A = op ? A1 : A0;
    const __hip_bfloat16* Bt = op ? B1 : B0;
    const int wave = tid >> 6, lane = tid & 63;
    const int wm = (wave >> 1) * 64, wn = (wave & 1) * 64;
    const int fcol = lane & 15, quad = lane >> 4;

    floatx4 acc[4][4];
#pragma unroll
    for (int mi = 0; mi < 4; mi++)
#pragma unroll
        for (int ni = 0; ni < 4; ni++)
            acc[mi][ni] = (floatx4){0.f, 0.f, 0.f, 0.f};

    const int q0 = tid, q1 = tid + 256;
    const int r0 = q0 >> 2, kc0 = (q0 & 3) * 8;
    const int r1 = q1 >> 2, kc1 = (q1 & 3) * 8;
    const __hip_bfloat16* gA0 = A + (size_t)(m0 + r0) * K + kc0;
    const __hip_bfloat16* gA1 = A + (size_t)(m0 + r1) * K + kc1;
    const __hip_bfloat16* gB0 = Bt + (size_t)(n0 + r0) * K + kc0;
    const __hip_bfloat16* gB1 = Bt + (size_t)(n0 + r1) * K + kc1;
    __hip_bfloat16* lA0 = As + q0 * 8; __hip_bfloat16* lA1 = As + q1 * 8;
    __hip_bfloat16* lB0 = Bs + q0 * 8; __hip_bfloat16* lB1 = Bs + q1 * 8;

    for (int kk = 0; kk < K; kk += 32) {
        gl_lds16(gA0 + kk, lA0);
        gl_lds16(gA1 + kk, lA1);
        gl_lds16(gB0 + kk, lB0);
        gl_lds16(gB1 + kk, lB1);
        __syncthreads();
        bf16x8 aF[4], bF[4];
#pragma unroll
        for (int mi = 0; mi < 4; mi++)
            aF[mi] = *(const bf16x8*)(As + (wm + mi * 16 + fcol) * 32 + quad * 8);
#pragma unroll
        for (int ni = 0; ni < 4; ni++)
            bF[ni] = *(const bf16x8*)(Bs + (wn + ni * 16 + fcol) * 32 + quad * 8);
#pragma unroll
        for (int mi = 0; mi < 4; mi++)
#pragma unroll
            for (int ni = 0; ni < 4; ni++)
                acc[mi][ni] = __builtin_amdgcn_mfma_f32_16x16x32_bf16(
                    aF[mi], bF[ni], acc[mi][ni], 0, 0, 0);
        __syncthreads();
    }
#pragma unroll
    for (int mi = 0; mi < 4; mi++) {
#pragma unroll
        for (int ni = 0; ni < 4; ni++) {
            int rbase = m0 + wm + mi * 16 + quad * 4;
            int ccol = n0 + wn + ni * 16 + fcol;
#pragma unroll
            for (int g = 0; g < 4; g++) {
                size_t idx = (size_t)(rbase + g) * 2048 + ccol;
                float val = acc[mi][ni][g];
                if (op == 0) {
                    decayOut[idx] = expf(-expf(val + tdec[ccol]));
                } else {
                    v2Out[idx] = __float2bfloat16(__bfloat162float(v2Out[idx]) + val);
                }
            }
        }
    }
}

// ---------------- chunked WKV scan (flash-linear-attention form) ------------
// 8-wave (512 thr), quadrant split (wr,wc), duplicated-P benign race,
// double-buffered staging, counted vmcnt(8), 3 barriers/chunk.
__global__ __launch_bounds__(512) void k_scan_chunked(
    const __hip_bfloat16* __restrict__ r, const __hip_bfloat16* __restrict__ k,
    const __hip_bfloat16* __restrict__ v, const float* __restrict__ dec,
    const float* __restrict__ state_in,
    __hip_bfloat16* __restrict__ y, float* __restrict__ state_out)
{
    __shared__ __hip_bfloat16 Rs[2][64 * 64];   // 16 KiB
    __shared__ __hip_bfloat16 Ks[2][64 * 64];   // 16 KiB
    __shared__ __hip_bfloat16 Vs[2][64 * 64];   // 16 KiB
    __shared__ float          Dsb[2][64 * 64];  // 32 KiB
    __shared__ __hip_bfloat16 Ys[2][64 * 64];   // 16 KiB (v2 rows of chunk)
    __shared__ __hip_bfloat16 Am[64 * 72];   // a[t][i] = r*Eexc
    __shared__ __hip_bfloat16 Bm[64 * 72];   // b[s][i] = k~/Einc
    __shared__ __hip_bfloat16 VT[64 * 72];   // V^T [j][s]
    __shared__ __hip_bfloat16 CT[64 * 72];   // C^T [i][s]
    __shared__ __hip_bfloat16 ST[64 * 72];   // S^T [j][i]
    __shared__ __hip_bfloat16 Pm[64 * 72];   // masked P [t][s]
    __shared__ float part[8][64];
    __shared__ float efin[64];

    const int tid = threadIdx.x;
    const int bh = blockIdx.x, b = bh >> 5, h = bh & 31;
    const int wave = tid >> 6, lane = tid & 63;
    const int fcol = lane & 15, quad = lane >> 4;
    const int wr = wave & 3, wc = wave >> 2;   // row-group / col-group
    const int ci = lane, seg = wave;           // phase A/B mapping

    floatx4 sfr[2];   // state rows 16*wr..+16, cols 32*wc..+32
    {
        const float* sp = state_in + (size_t)bh * 4096;
#pragma unroll
        for (int n = 0; n < 2; n++)
#pragma unroll
            for (int g = 0; g < 4; g++)
                sfr[n][g] = sp[(size_t)(16 * wr + quad * 4 + g) * 64
                               + 32 * wc + 16 * n + fcol];
    }

    const size_t cbase0 = (size_t)b * T_DIM * C_DIM + (size_t)h * 64;

    // 6 global_load_lds per thread per chunk (512 threads)
    auto stage = [&](int cc, int buf) {
        const size_t cb = cbase0 + (size_t)cc * 64 * C_DIM;
        const size_t o = (size_t)(tid >> 3) * C_DIM + (tid & 7) * 8;
        gl_lds16(r + cb + o, &Rs[buf][tid * 8]);
        gl_lds16(k + cb + o, &Ks[buf][tid * 8]);
        gl_lds16(v + cb + o, &Vs[buf][tid * 8]);
        gl_lds16(y + cb + o, &Ys[buf][tid * 8]);
#pragma unroll
        for (int s = 0; s < 2; s++) {
            int q = tid + 512 * s;
            gl_lds16(dec + cb + (size_t)(q >> 4) * C_DIM + (q & 15) * 4,
                     &Dsb[buf][q * 4]);
        }
    };

    stage(0, 0);

    for (int c = 0; c < 32; c++) {
        const int cur = c & 1, nxt = cur ^ 1;
        const size_t cb = cbase0 + (size_t)c * 64 * C_DIM;

        if (c == 0) asm volatile("s_waitcnt vmcnt(0)" ::: "memory");
        else        asm volatile("s_waitcnt vmcnt(8)" ::: "memory");
        asm volatile("s_waitcnt lgkmcnt(0)" ::: "memory");
        __builtin_amdgcn_s_barrier();
        __builtin_amdgcn_sched_barrier(0);

        if (c + 1 < 32) stage(c + 1, nxt);

        // ---- phase A: publish S^T; per-seg decay products (8 each) ----
        {
#pragma unroll
            for (int n = 0; n < 2; n++)
#pragma unroll
                for (int g = 0; g < 4; g++)
                    ST[(size_t)(32 * wc + 16 * n + fcol) * 72
                       + 16 * wr + quad * 4 + g] = __float2bfloat16(sfr[n][g]);
            float p = 1.0f;
#pragma unroll
            for (int u = 0; u < 8; u++) p *= Dsb[cur][(seg * 8 + u) * 64 + ci];
            part[seg][ci] = p;
        }
        asm volatile("s_waitcnt lgkmcnt(0)" ::: "memory");
        __builtin_amdgcn_s_barrier();   // B2
        __builtin_amdgcn_sched_barrier(0);

        // ---- phase B: build Am/Bm/CT/VT/efin ----
        {
            float pp[8];
#pragma unroll
            for (int s = 0; s < 8; s++) pp[s] = part[s][ci];
            float pre = 1.0f;
#pragma unroll
            for (int s = 0; s < 7; s++) pre *= (s < seg) ? pp[s] : 1.0f;
            float tot = pp[0] * pp[1] * pp[2] * pp[3]
                      * pp[4] * pp[5] * pp[6] * pp[7];
            if (seg == 0) efin[ci] = tot;
            float e = pre;
#pragma unroll
            for (int u = 0; u < 8; u++) {
                int t = seg * 8 + u;
                float d = Dsb[cur][t * 64 + ci];
                float rv = __bfloat162float(Rs[cur][t * 64 + ci]);
                float kv = __bfloat162float(Ks[cur][t * 64 + ci]) * (1.0f - d);
                Am[t * 72 + ci] = __float2bfloat16(rv * e);
                e *= d;
                float bb = kv * __builtin_amdgcn_rcpf(e);
                Bm[t * 72 + ci] = __float2bfloat16(bb);
                CT[ci * 72 + t] = __float2bfloat16(bb * tot);
            }
#pragma unroll
            for (int u = 0; u < 8; u++) {
                int t = seg * 8 + ((u + (ci & 7)) & 7);
                VT[ci * 72 + t] = Vs[cur][t * 64 + ci];
            }
        }
        asm volatile("s_waitcnt lgkmcnt(0)" ::: "memory");
        __builtin_amdgcn_s_barrier();   // B3
        __builtin_amdgcn_sched_barrier(0);

        // ---- phase C: MFMAs + y out + state update ----
        {
            bf16x8 af[2];
#pragma unroll
            for (int kk = 0; kk < 2; kk++)
                af[kk] = *(const bf16x8*)(Am + (16 * wr + fcol) * 72 + kk * 32 + quad * 8);
            floatx4 pfr[4];
#pragma unroll
            for (int n4 = 0; n4 < 4; n4++) {
                pfr[n4] = (floatx4){0.f, 0.f, 0.f, 0.f};
#pragma unroll
                for (int kk = 0; kk < 2; kk++) {
                    bf16x8 bF = *(const bf16x8*)(Bm + (16 * n4 + fcol) * 72 + kk * 32 + quad * 8);
                    pfr[n4] = __builtin_amdgcn_mfma_f32_16x16x32_bf16(af[kk], bF, pfr[n4], 0, 0, 0);
                }
            }
            floatx4 yfr[2];
#pragma unroll
            for (int n = 0; n < 2; n++) {
                yfr[n] = (floatx4){0.f, 0.f, 0.f, 0.f};
#pragma unroll
                for (int kk = 0; kk < 2; kk++) {
                    bf16x8 sF = *(const bf16x8*)(ST + (32 * wc + 16 * n + fcol) * 72 + kk * 32 + quad * 8);
                    yfr[n] = __builtin_amdgcn_mfma_f32_16x16x32_bf16(af[kk], sF, yfr[n], 0, 0, 0);
                }
            }
#pragma unroll
            for (int n4 = 0; n4 < 4; n4++)
#pragma unroll
                for (int g = 0; g < 4; g++) {
                    int t = 16 * wr + quad * 4 + g;
                    int s = 16 * n4 + fcol;
                    Pm[t * 72 + s] = (s < t) ? __float2bfloat16(pfr[n4][g])
                                             : __float2bfloat16(0.0f);
                }
            float eg[4];
#pragma unroll
            for (int g = 0; g < 4; g++) eg[g] = efin[16 * wr + quad * 4 + g];
#pragma unroll
            for (int n = 0; n < 2; n++)
#pragma unroll
                for (int g = 0; g < 4; g++) sfr[n][g] *= eg[g];
            bf16x8 pf[2], cf[2];
#pragma unroll
            for (int kk = 0; kk < 2; kk++) {
                pf[kk] = *(const bf16x8*)(Pm + (16 * wr + fcol) * 72 + kk * 32 + quad * 8);
                cf[kk] = *(const bf16x8*)(CT + (16 * wr + fcol) * 72 + kk * 32 + quad * 8);
            }
#pragma unroll
            for (int n = 0; n < 2; n++) {
#pragma unroll
                for (int kk = 0; kk < 2; kk++) {
                    bf16x8 vF = *(const bf16x8*)(VT + (32 * wc + 16 * n + fcol) * 72 + kk * 32 + quad * 8);
                    yfr[n] = __builtin_amdgcn_mfma_f32_16x16x32_bf16(pf[kk], vF, yfr[n], 0, 0, 0);
                    sfr[n] = __builtin_amdgcn_mfma_f32_16x16x32_bf16(cf[kk], vF, sfr[n], 0, 0, 0);
                }
            }
#pragma unroll
            for (int n = 0; n < 2; n++)
#pragma unroll
                for (int g = 0; g < 4; g++) {
                    int t = 16 * wr + quad * 4 + g;
                    int j = 32 * wc + 16 * n + fcol;
                    size_t addr = cb + (size_t)t * C_DIM + j;
                    float yv = __bfloat162float(Ys[cur][t * 64 + j]) + yfr[n][g];
                    y[addr] = __float2bfloat16(yv);
                }
        }
    }
    {
        float* so = state_out + (size_t)bh * 4096;
#pragma unroll
        for (int n = 0; n < 2; n++)
#pragma unroll
            for (int g = 0; g < 4; g++)
                so[(size_t)(16 * wr + quad * 4 + g) * 64 + 32 * wc + 16 * n + fcol]
                    = sfr[n][g];
    }
}

// ---------------- in-place LayerNorm on bf16 rows ---------------------------
__global__ __launch_bounds__(256) void k_addln(
    __hip_bfloat16* __restrict__ y,
    const float* __restrict__ lnw, const float* __restrict__ lnb)
{
    __shared__ float ls[4], ls2[4];
    const int row = blockIdx.x;
    const size_t base = (size_t)row * C_DIM;
    const int tid = threadIdx.x;
    const int c0 = tid * 8;
    union { bf16x8 v8; __hip_bfloat16 e[8]; } uin;
    uin.v8 = *(const bf16x8*)(y + base + c0);
    float vbuf[8];
#pragma unroll
    for (int j = 0; j < 8; j++) vbuf[j] = __bfloat162float(uin.e[j]);
    float s = 0.f, s2 = 0.f;
#pragma unroll
    for (int j = 0; j < 8; j++) { s += vbuf[j]; s2 += vbuf[j] * vbuf[j]; }
#pragma unroll
    for (int off = 32; off > 0; off >>= 1) {
        s += __shfl_down(s, off, 64);
        s2 += __shfl_down(s2, off, 64);
    }
    const int w = tid >> 6;
    if ((tid & 63) == 0) { ls[w] = s; ls2[w] = s2; }
    __syncthreads();
    float S = ls[0] + ls[1] + ls[2] + ls[3];
    float S2 = ls2[0] + ls2[1] + ls2[2] + ls2[3];
    float mu = S * (1.0f / C_DIM);
    float var = S2 * (1.0f / C_DIM) - mu * mu;
    float rs = rsqrtf(var + 1e-5f);
    union { bf16x8 v8; __hip_bfloat16 e[8]; } u;
#pragma unroll
    for (int j = 0; j < 8; j++) {
        int ccc = c0 + j;
        u.e[j] = __float2bfloat16((vbuf[j] - mu) * rs * lnw[ccc] + lnb[ccc]);
    }
    *(bf16x8*)(y + base + c0) = u.v8;
}

// ---------------------------------------------------------------------------
extern "C" void kernel_launch(void* const* d_in, const int* in_sizes, int n_in,
                              void* d_out, int out_size, void* d_ws, size_t ws_size,
                              hipStream_t stream)
{
    const float* x     = (const float*)d_in[0];
    const float* shift = (const float*)d_in[1];
    const float* wkvin = (const float*)d_in[2];
    const float* tmx   = (const float*)d_in[3];
    const float* tmr   = (const float*)d_in[4];
    const float* tmk   = (const float*)d_in[5];
    const float* tmv   = (const float*)d_in[6];
    const float* tmw   = (const float*)d_in[7];
    const float* tmv2  = (const float*)d_in[8];
    const float* w1    = (const float*)d_in[9];
    const float* w2    = (const float*)d_in[10];
    const float* tdec  = (const float*)d_in[11];
    const float* dw1   = (const float*)d_in[12];
    const float* dw2   = (const float*)d_in[13];
    const float* vw1   = (const float*)d_in[14];
    const float* vw2   = (const float*)d_in[15];
    const float* Wr    = (const float*)d_in[16];
    const float* Wk    = (const float*)d_in[17];
    const float* Wv    = (const float*)d_in[18];
    const float* Wo    = (const float*)d_in[19];
    const float* lnw   = (const float*)d_in[20];
    const float* lnb   = (const float*)d_in[21];

    const size_t SZ_XBF = (size_t)M_ROWS * C_DIM * 2;
    const size_t SZ_WBF = (size_t)C_DIM * C_DIM * 2;
    char* ws = (char*)d_ws;
    size_t off = 0;
    __hip_bfloat16* S0 = (__hip_bfloat16*)(ws + off); off += SZ_XBF; // xr -> v
    __hip_bfloat16* S1 = (__hip_bfloat16*)(ws + off); off += SZ_XBF; // xk -> r
    __hip_bfloat16* S2 = (__hip_bfloat16*)(ws + off); off += SZ_XBF; // xv -> v2/y
    __hip_bfloat16* S3 = (__hip_bfloat16*)(ws + off); off += SZ_XBF; // xw -> k
    __hip_bfloat16* S4 = (__hip_bfloat16*)(ws + off); off += SZ_XBF; // xv2
    char* D = ws + off; off += (size_t)M_ROWS * C_DIM * 4;  // XX||H, then decay
    __hip_bfloat16* XX    = (__hip_bfloat16*)D;
    __hip_bfloat16* Hb    = (__hip_bfloat16*)(D + SZ_XBF); // bf16 H [8192][256]
    float*          decay = (float*)D;
    __hip_bfloat16* WrT = (__hip_bfloat16*)(ws + off); off += SZ_WBF;
    __hip_bfloat16* WkT = (__hip_bfloat16*)(ws + off); off += SZ_WBF;
    __hip_bfloat16* WvT = (__hip_bfloat16*)(ws + off); off += SZ_WBF;
    __hip_bfloat16* WoT = (__hip_bfloat16*)(ws + off); off += SZ_WBF;
    __hip_bfloat16* w1tb  = (__hip_bfloat16*)(ws + off); off += (size_t)256 * 2048 * 2;
    __hip_bfloat16* dw1t  = (__hip_bfloat16*)(ws + off); off += (size_t)64 * 2048 * 2;
    __hip_bfloat16* vw1t  = (__hip_bfloat16*)(ws + off); off += (size_t)64 * 2048 * 2;
    __hip_bfloat16* dw2t  = (__hip_bfloat16*)(ws + off); off += (size_t)2048 * 64 * 2;
    __hip_bfloat16* vw2t  = (__hip_bfloat16*)(ws + off); off += (size_t)2048 * 64 * 2;
    __hip_bfloat16* Gd    = (__hip_bfloat16*)(ws + off); off += (size_t)M_ROWS * 64 * 2;
    __hip_bfloat16* Gv    = (__hip_bfloat16*)(ws + off); off += (size_t)M_ROWS * 64 * 2;
    __hip_bfloat16* w2T   = (__hip_bfloat16*)(ws + off); off += (size_t)2048 * 160 * 2;
    if (ws_size < off) {
        fprintf(stderr, "kernel_launch: ws too small (%zu < %zu)\n", ws_size, off);
        return;
    }

    float* out_y     = (float*)d_out;
    float* out_xlast = out_y + (size_t)M_ROWS * C_DIM;
    float* out_state = out_xlast + (size_t)B_DIM * C_DIM;

    // ---- weight prep ----
    k_transpose<<<dim3(8, 64),  256, 0, stream>>>(w1,  w1tb, 2048, 160, 1);
    k_transpose<<<dim3(2, 64),  256, 0, stream>>>(dw1, dw1t, 2048, 64, 1);
    k_transpose<<<dim3(2, 64),  256, 0, stream>>>(vw1, vw1t, 2048, 64, 1);
    k_transpose<<<dim3(64, 2),  256, 0, stream>>>(dw2, dw2t, 64, 2048, 1);
    k_transpose<<<dim3(64, 2),  256, 0, stream>>>(vw2, vw2t, 64, 2048, 1);
    k_transpose<<<dim3(64, 5),  256, 0, stream>>>(w2,  w2T,  160, 2048, 1);
    k_transpose<<<dim3(64, 64), 256, 0, stream>>>(Wr, WrT, 2048, 2048, 1);
    k_transpose<<<dim3(64, 64), 256, 0, stream>>>(Wk, WkT, 2048, 2048, 1);
    k_transpose<<<dim3(64, 64), 256, 0, stream>>>(Wv, WvT, 2048, 2048, 1);
    k_transpose<<<dim3(64, 64), 256, 0, stream>>>(Wo, WoT, 2048, 2048, 1);

    // ---- mixer ----
    k_xx<<<M_ROWS, 256, 0, stream>>>(x, shift, tmx, XX, out_xlast);
    k_gemm_h<<<128, 256, 0, stream>>>(XX, w1tb, Hb);
    k_mixfused<<<2048, 256, 0, stream>>>(x, shift, Hb, w2T,
                                         tmr, tmk, tmv, tmw, tmv2,
                                         S0, S1, S2, S3, S4);
    // ---- LoRA hidden layers ----
    k_gemm_n64<<<128, 256, 0, stream>>>(S3, dw1t, Gd);   // from xw (frees S3)
    k_gemm_n64<<<128, 256, 0, stream>>>(S4, vw1t, Gv);   // from xv2
    // ---- big GEMMs (outputs recycle freed x-slots; raw k now) ----
    k_gemm256<<<256, 512, 0, stream>>>(S1, WkT, 1, nullptr, S3);   // k  (xk->S3)
    k_gemm256<<<256, 512, 0, stream>>>(S0, WrT, 1, nullptr, S1);   // r  (xr->S1)
    k_gemm256<<<256, 512, 0, stream>>>(S2, WvT, 1, nullptr, S0);   // v  (xv->S0)
    k_gemm256<<<256, 512, 0, stream>>>(S4, WvT, 1, nullptr, S2);   // v2 (xv2->S2)
    // ---- merged K=64 epilogues: decay (fp32 into D) + v2 += lora ----
    k_gemm64<<<2048, 256, 0, stream>>>(Gd, dw2t, Gv, vw2t, decay, tdec, S2);
    // ---- chunked WKV scan (k~ = k*(1-d) inline; adds v2 in-place in S2) ----
    k_scan_chunked<<<128, 512, 0, stream>>>(S1, S3, S0, decay, wkvin, S2, out_state);
    // ---- LayerNorm (in-place) + output projection ----
    k_addln<<<M_ROWS, 256, 0, stream>>>(S2, lnw, lnb);
    k_gemm256<<<256, 512, 0, stream>>>(S2, WoT, 0, out_y, nullptr);

    (void)in_sizes; (void)n_in; (void)out_size;
}